// Round 5
// baseline (701.706 us; speedup 1.0000x reference)
//
#include <hip/hip_runtime.h>

#define NV 100000
#define NE 50000
#define NNZ_C 800000
#define CAP_E 64        // slots per edge   (Poisson(16), +12 sigma)
#define CAP_V 48        // slots per vertex (Poisson(8),  +14 sigma)
#define NB_E 391        // ceil(NE/128) buckets of 128 edges
#define NB_V 782        // ceil(NV/128) buckets of 128 vertices
#define CAPB_E 2560     // Poisson(2048) + 11 sigma
#define CAPB_V 1408     // Poisson(1024) + 12 sigma

typedef unsigned int uint32;
typedef unsigned short u16;
typedef u16 u16x8 __attribute__((ext_vector_type(8)));
typedef short short8 __attribute__((ext_vector_type(8)));
typedef float floatx4 __attribute__((ext_vector_type(4)));

__device__ __forceinline__ float bf2f(u16 h) {
  return __uint_as_float(((uint32)h) << 16);
}
__device__ __forceinline__ u16 f2bf(float f) {
  uint32 u = __float_as_uint(f);
  u += 0x7FFF + ((u >> 16) & 1);   // RNE
  return (u16)(u >> 16);
}

// ---------------- CSR build: bucketed two-phase ----------------
// bcur: one cursor per 64B line; [0,NB_E) edge buckets, [NB_E,NB_E+NB_V) vertex buckets

__global__ void zero_bcur(int* p, int n) {
  int i = blockIdx.x * blockDim.x + threadIdx.x;
  if (i < n) p[i] = 0;
}

__global__ void bucket_scatter(const int* __restrict__ vertex, const int* __restrict__ edges,
                               int* __restrict__ bcur,
                               uint32* __restrict__ pairE, uint32* __restrict__ pairV) {
  int stride = gridDim.x * blockDim.x;
  for (int k = blockIdx.x * blockDim.x + threadIdx.x; k < NNZ_C; k += stride) {
    uint32 e = (uint32)edges[k], v = (uint32)vertex[k];
    uint32 be = e >> 7, bv = v >> 7;
    int pe = atomicAdd(&bcur[be << 4], 1);
    if (pe < CAPB_E) pairE[be * CAPB_E + pe] = ((e & 127u) << 25) | v;   // v < 2^17
    int pv = atomicAdd(&bcur[(NB_E + bv) << 4], 1);
    if (pv < CAPB_V) pairV[bv * CAPB_V + pv] = ((v & 127u) << 25) | e;   // e < 2^16
  }
}

// one block per bucket: rank via LDS atomics, write items into a 32KB L2 window
__global__ __launch_bounds__(256) void expand(const uint32* __restrict__ pairs,
                                              const int* __restrict__ bcur, int curOff,
                                              int capb, int* __restrict__ items, int cap,
                                              int* __restrict__ cnt, int nKeys) {
  __shared__ int lcnt[128];
  int b = blockIdx.x, t = threadIdx.x;
  if (t < 128) lcnt[t] = 0;
  __syncthreads();
  int n = min(bcur[(curOff + b) << 4], capb);
  const uint32* p = pairs + (size_t)b * capb;
  for (int i = t; i < n; i += 256) {
    uint32 w = p[i];
    int loc = w >> 25;
    int val = (int)(w & 0x1FFFFFFu);
    int r = atomicAdd(&lcnt[loc], 1);
    int key = (b << 7) + loc;
    if (r < cap) items[(size_t)key * cap + r] = val;
  }
  __syncthreads();
  if (t < 128) {
    int key = (b << 7) + t;
    if (key < nKeys) cnt[key] = lcnt[t];
  }
}

// ---------------- weight prep ----------------
// WT layout: [0,16384) = W0T[n][k]; then 4x WeffT[i][n][k], Weff=(1-b)I+b*Ws[i]

__global__ void prep_weights(const float* __restrict__ W0, const float* __restrict__ Ws,
                             u16* __restrict__ WT) {
  int idx = blockIdx.x * blockDim.x + threadIdx.x;
  if (idx >= 5 * 16384) return;
  const float betas[4] = {0.4054651081f, 0.2231435513f, 0.1541506798f, 0.1177830357f};
  int sec = idx >> 14;
  int rc = idx & 16383;
  int n = rc >> 7, k = rc & 127;
  float v;
  if (sec == 0) {
    v = W0[k * 128 + n];
  } else {
    int i = sec - 1;
    float b = betas[i];
    v = b * Ws[i * 16384 + k * 128 + n];
    if (k == n) v += 1.0f - b;
  }
  WT[idx] = f2bf(v);
}

// ---------------- edge aggregation (bf16, 16 lanes/row, MLP-4) ----------------

__global__ __launch_bounds__(256) void edge_agg(const u16* __restrict__ Xh,
                                                const int* __restrict__ cntE,
                                                const int* __restrict__ itemsE,
                                                u16* __restrict__ Xeh) {
  int g = threadIdx.x >> 4;
  int lane = threadIdx.x & 15;
  int e = blockIdx.x * 16 + g;
  int cnt = cntE[e];
  int n = min(cnt, CAP_E);
  const int* it = itemsE + (size_t)e * CAP_E;
  float acc[8] = {0.f, 0.f, 0.f, 0.f, 0.f, 0.f, 0.f, 0.f};
  int j = 0;
  for (; j + 4 <= n; j += 4) {
    int4 vs = *(const int4*)(it + j);
    u16x8 a = *(const u16x8*)(Xh + (size_t)vs.x * 128 + lane * 8);
    u16x8 b = *(const u16x8*)(Xh + (size_t)vs.y * 128 + lane * 8);
    u16x8 c = *(const u16x8*)(Xh + (size_t)vs.z * 128 + lane * 8);
    u16x8 d = *(const u16x8*)(Xh + (size_t)vs.w * 128 + lane * 8);
    #pragma unroll
    for (int q = 0; q < 8; q++)
      acc[q] += (bf2f(a[q]) + bf2f(b[q])) + (bf2f(c[q]) + bf2f(d[q]));
  }
  for (; j < n; j++) {
    int v = it[j];
    u16x8 xv = *(const u16x8*)(Xh + (size_t)v * 128 + lane * 8);
    #pragma unroll
    for (int q = 0; q < 8; q++) acc[q] += bf2f(xv[q]);
  }
  float inv = 1.f / fmaxf((float)cnt, 1.f);
  u16x8 o;
  #pragma unroll
  for (int q = 0; q < 8; q++) o[q] = f2bf(acc[q] * inv);
  *(u16x8*)(Xeh + (size_t)e * 128 + lane * 8) = o;
}

// ---------------- fused vertex_agg + MFMA GEMM (depth layers) ----------------
// Yh = relu( blend(vertex_agg(Xe)) @ Weff ), block owns rows [row0,row0+128)

__global__ __launch_bounds__(256) void gemm_fused(const u16* __restrict__ Xeh,
                                                  const int* __restrict__ cntV,
                                                  const int* __restrict__ itemsV,
                                                  const u16* __restrict__ x0h,
                                                  const u16* __restrict__ WT,
                                                  u16* __restrict__ Yh, int nrows) {
  __shared__ u16 As[128 * 136];
  __shared__ u16 Bs[128 * 136];
  int t = threadIdx.x;
  int row0 = blockIdx.x * 128;
  #pragma unroll
  for (int i = 0; i < 8; i++) {
    int idx = t + 256 * i;
    int r = idx >> 4, c8 = idx & 15;
    *(u16x8*)&Bs[r * 136 + c8 * 8] = *(const u16x8*)(WT + (size_t)r * 128 + c8 * 8);
  }
  int g = t >> 4, lane = t & 15;
  for (int pass = 0; pass < 8; pass++) {
    int r = pass * 16 + g;
    int v = row0 + r;
    float acc[8] = {0.f, 0.f, 0.f, 0.f, 0.f, 0.f, 0.f, 0.f};
    int cnt = 0;
    if (v < nrows) {
      cnt = cntV[v];
      int n = min(cnt, CAP_V);
      const int* it = itemsV + (size_t)v * CAP_V;
      int j = 0;
      for (; j + 4 <= n; j += 4) {
        int4 es = *(const int4*)(it + j);
        u16x8 a = *(const u16x8*)(Xeh + (size_t)es.x * 128 + lane * 8);
        u16x8 b = *(const u16x8*)(Xeh + (size_t)es.y * 128 + lane * 8);
        u16x8 c = *(const u16x8*)(Xeh + (size_t)es.z * 128 + lane * 8);
        u16x8 d = *(const u16x8*)(Xeh + (size_t)es.w * 128 + lane * 8);
        #pragma unroll
        for (int q = 0; q < 8; q++)
          acc[q] += (bf2f(a[q]) + bf2f(b[q])) + (bf2f(c[q]) + bf2f(d[q]));
      }
      for (; j < n; j++) {
        int e = it[j];
        u16x8 xv = *(const u16x8*)(Xeh + (size_t)e * 128 + lane * 8);
        #pragma unroll
        for (int q = 0; q < 8; q++) acc[q] += bf2f(xv[q]);
      }
    }
    float inv = 1.f / fmaxf((float)cnt, 1.f);
    float sq = 0.f;
    #pragma unroll
    for (int q = 0; q < 8; q++) { acc[q] *= inv; sq += acc[q] * acc[q]; }
    sq += __shfl_xor(sq, 1, 64);
    sq += __shfl_xor(sq, 2, 64);
    sq += __shfl_xor(sq, 4, 64);
    sq += __shfl_xor(sq, 8, 64);
    float scale = (sq > 0.f) ? rsqrtf(sq) : 0.f;
    u16x8 o = {0, 0, 0, 0, 0, 0, 0, 0};
    if (v < nrows) {
      u16x8 x0v = *(const u16x8*)(x0h + (size_t)v * 128 + lane * 8);
      #pragma unroll
      for (int q = 0; q < 8; q++)
        o[q] = f2bf(0.9f * acc[q] * scale + 0.1f * bf2f(x0v[q]));
    }
    *(u16x8*)&As[r * 136 + lane * 8] = o;
  }
  __syncthreads();

  int w = t >> 6;
  int lane64 = t & 63;
  int lo16 = lane64 & 15, hi = lane64 >> 4;
  floatx4 acc[2][8];
  #pragma unroll
  for (int rt = 0; rt < 2; rt++)
    #pragma unroll
    for (int ct = 0; ct < 8; ct++) acc[rt][ct] = (floatx4){0.f, 0.f, 0.f, 0.f};

  #pragma unroll
  for (int kc = 0; kc < 4; kc++) {
    int koff = kc * 32 + hi * 8;
    short8 a0 = *(const short8*)&As[(w * 32 + lo16) * 136 + koff];
    short8 a1 = *(const short8*)&As[(w * 32 + 16 + lo16) * 136 + koff];
    #pragma unroll
    for (int ct = 0; ct < 8; ct++) {
      short8 b = *(const short8*)&Bs[(ct * 16 + lo16) * 136 + koff];
      acc[0][ct] = __builtin_amdgcn_mfma_f32_16x16x32_bf16(a0, b, acc[0][ct], 0, 0, 0);
      acc[1][ct] = __builtin_amdgcn_mfma_f32_16x16x32_bf16(a1, b, acc[1][ct], 0, 0, 0);
    }
  }
  __syncthreads();

  #pragma unroll
  for (int rt = 0; rt < 2; rt++) {
    #pragma unroll
    for (int ct = 0; ct < 8; ct++) {
      int col = ct * 16 + lo16;
      #pragma unroll
      for (int reg = 0; reg < 4; reg++) {
        int row = w * 32 + rt * 16 + hi * 4 + reg;
        As[row * 136 + col] = f2bf(fmaxf(acc[rt][ct][reg], 0.f));
      }
    }
  }
  __syncthreads();
  #pragma unroll
  for (int i = 0; i < 8; i++) {
    int idx = t + 256 * i;
    int r = idx >> 4, c8 = idx & 15;
    if (row0 + r < nrows)
      *(u16x8*)(Yh + (size_t)(row0 + r) * 128 + c8 * 8) =
          *(const u16x8*)&As[r * 136 + c8 * 8];
  }
}

// ---------------- first GEMM: fp32 A in, bf16 out (+copy), relu+bias ----------------

__global__ __launch_bounds__(256) void gemm_first(const float* __restrict__ A,
                                                  const u16* __restrict__ WT,
                                                  const float* __restrict__ bias,
                                                  u16* __restrict__ Yh,
                                                  u16* __restrict__ Y2h, int nrows) {
  __shared__ u16 As[128 * 136];
  __shared__ u16 Bs[128 * 136];
  int t = threadIdx.x;
  int row0 = blockIdx.x * 128;
  #pragma unroll
  for (int i = 0; i < 8; i++) {
    int idx = t + 256 * i;
    int r = idx >> 4, c8 = idx & 15;
    u16x8 v = {0, 0, 0, 0, 0, 0, 0, 0};
    if (row0 + r < nrows) {
      const float* p = A + (size_t)(row0 + r) * 128 + c8 * 8;
      float4 a = *(const float4*)p;
      float4 b = *(const float4*)(p + 4);
      v[0] = f2bf(a.x); v[1] = f2bf(a.y); v[2] = f2bf(a.z); v[3] = f2bf(a.w);
      v[4] = f2bf(b.x); v[5] = f2bf(b.y); v[6] = f2bf(b.z); v[7] = f2bf(b.w);
    }
    *(u16x8*)&As[r * 136 + c8 * 8] = v;
    *(u16x8*)&Bs[r * 136 + c8 * 8] = *(const u16x8*)(WT + (size_t)r * 128 + c8 * 8);
  }
  __syncthreads();

  int w = t >> 6;
  int lane = t & 63;
  int lo16 = lane & 15, hi = lane >> 4;
  floatx4 acc[2][8];
  #pragma unroll
  for (int rt = 0; rt < 2; rt++)
    #pragma unroll
    for (int ct = 0; ct < 8; ct++) acc[rt][ct] = (floatx4){0.f, 0.f, 0.f, 0.f};

  #pragma unroll
  for (int kc = 0; kc < 4; kc++) {
    int koff = kc * 32 + hi * 8;
    short8 a0 = *(const short8*)&As[(w * 32 + lo16) * 136 + koff];
    short8 a1 = *(const short8*)&As[(w * 32 + 16 + lo16) * 136 + koff];
    #pragma unroll
    for (int ct = 0; ct < 8; ct++) {
      short8 b = *(const short8*)&Bs[(ct * 16 + lo16) * 136 + koff];
      acc[0][ct] = __builtin_amdgcn_mfma_f32_16x16x32_bf16(a0, b, acc[0][ct], 0, 0, 0);
      acc[1][ct] = __builtin_amdgcn_mfma_f32_16x16x32_bf16(a1, b, acc[1][ct], 0, 0, 0);
    }
  }
  __syncthreads();

  #pragma unroll
  for (int rt = 0; rt < 2; rt++) {
    #pragma unroll
    for (int ct = 0; ct < 8; ct++) {
      int col = ct * 16 + lo16;
      float bv = bias[col];
      #pragma unroll
      for (int reg = 0; reg < 4; reg++) {
        int row = w * 32 + rt * 16 + hi * 4 + reg;
        As[row * 136 + col] = f2bf(fmaxf(acc[rt][ct][reg] + bv, 0.f));
      }
    }
  }
  __syncthreads();
  #pragma unroll
  for (int i = 0; i < 8; i++) {
    int idx = t + 256 * i;
    int r = idx >> 4, c8 = idx & 15;
    if (row0 + r < nrows) {
      u16x8 v = *(const u16x8*)&As[r * 136 + c8 * 8];
      *(u16x8*)(Yh + (size_t)(row0 + r) * 128 + c8 * 8) = v;
      *(u16x8*)(Y2h + (size_t)(row0 + r) * 128 + c8 * 8) = v;
    }
  }
}

// ---------------- output GEMM: out[nrows,40] = Xh @ Wout + bout ----------------

__global__ __launch_bounds__(256) void gemm_out(const u16* __restrict__ Xh,
                                                const float* __restrict__ W,
                                                const float* __restrict__ bias,
                                                float* __restrict__ Y, int nrows) {
  __shared__ float xs[128][36];
  __shared__ float ws[32][44];
  int t = threadIdx.x;
  int tr = t >> 3;
  int tc = t & 7;
  int row0 = blockIdx.x * 128;
  float acc[4][5];
  #pragma unroll
  for (int i = 0; i < 4; i++)
    #pragma unroll
    for (int j = 0; j < 5; j++) acc[i][j] = 0.f;

  for (int k0 = 0; k0 < 128; k0 += 32) {
    #pragma unroll
    for (int i = 0; i < 2; i++) {
      int idx = t + 256 * i;
      int r = idx >> 2, c8 = idx & 3;
      int gr = row0 + r;
      u16x8 v = {0, 0, 0, 0, 0, 0, 0, 0};
      if (gr < nrows) v = *(const u16x8*)(Xh + (size_t)gr * 128 + k0 + c8 * 8);
      #pragma unroll
      for (int q = 0; q < 8; q++) xs[r][c8 * 8 + q] = bf2f(v[q]);
    }
    #pragma unroll
    for (int i = 0; i < 5; i++) {
      int idx = t + 256 * i;
      int r = idx / 40, c = idx % 40;
      ws[r][c] = W[(k0 + r) * 40 + c];
    }
    __syncthreads();
    #pragma unroll
    for (int kk4 = 0; kk4 < 8; kk4++) {
      float4 xv[4];
      #pragma unroll
      for (int i = 0; i < 4; i++) xv[i] = *(const float4*)&xs[tr + 32 * i][kk4 * 4];
      #pragma unroll
      for (int q = 0; q < 4; q++) {
        int kk = kk4 * 4 + q;
        float w[5];
        #pragma unroll
        for (int j = 0; j < 5; j++) w[j] = ws[kk][tc * 5 + j];
        #pragma unroll
        for (int i = 0; i < 4; i++) {
          float xq = ((const float*)&xv[i])[q];
          #pragma unroll
          for (int j = 0; j < 5; j++) acc[i][j] += xq * w[j];
        }
      }
    }
    __syncthreads();
  }
  #pragma unroll
  for (int i = 0; i < 4; i++) {
    int gr = row0 + tr + 32 * i;
    if (gr >= nrows) continue;
    #pragma unroll
    for (int j = 0; j < 5; j++) {
      int c = tc * 5 + j;
      Y[(long)gr * 40 + c] = acc[i][j] + bias[c];
    }
  }
}

// ---------------- launch ----------------

extern "C" void kernel_launch(void* const* d_in, const int* in_sizes, int n_in,
                              void* d_out, int out_size, void* d_ws, size_t ws_size,
                              hipStream_t stream) {
  const float* x    = (const float*)d_in[0];
  const float* W0   = (const float*)d_in[1];
  const float* b0   = (const float*)d_in[2];
  const float* Ws   = (const float*)d_in[3];
  const float* Wout = (const float*)d_in[4];
  const float* bout = (const float*)d_in[5];
  const int* vertex = (const int*)d_in[6];
  const int* edges  = (const int*)d_in[7];
  float* out = (float*)d_out;

  char* base = (char*)d_ws;
  size_t o = 0;
  auto alloc = [&](size_t bytes) -> char* {
    char* r = base + o;
    o += (bytes + 255) & ~(size_t)255;
    return r;
  };
  u16* x_curh = (u16*)alloc((size_t)NV * 128 * 2);
  u16* x0h    = (u16*)alloc((size_t)NV * 128 * 2);
  u16* Xeh    = (u16*)alloc((size_t)NE * 128 * 2);
  u16* WT     = (u16*)alloc((size_t)5 * 16384 * 2);
  int* cntE   = (int*)alloc((size_t)NE * 4);
  int* cntV   = (int*)alloc((size_t)NV * 4);
  int* itemsE = (int*)alloc((size_t)NE * CAP_E * 4);
  int* itemsV = (int*)alloc((size_t)NV * CAP_V * 4);
  uint32* pairE = (uint32*)alloc((size_t)NB_E * CAPB_E * 4);
  uint32* pairV = (uint32*)alloc((size_t)NB_V * CAPB_V * 4);
  int* bcur   = (int*)alloc((size_t)(NB_E + NB_V) * 16 * 4);

  int nb = (NB_E + NB_V) * 16;
  zero_bcur<<<(nb + 255) / 256, 256, 0, stream>>>(bcur, nb);
  bucket_scatter<<<1024, 256, 0, stream>>>(vertex, edges, bcur, pairE, pairV);
  expand<<<NB_E, 256, 0, stream>>>(pairE, bcur, 0, CAPB_E, itemsE, CAP_E, cntE, NE);
  expand<<<NB_V, 256, 0, stream>>>(pairV, bcur, NB_E, CAPB_V, itemsV, CAP_V, cntV, NV);
  prep_weights<<<(5 * 16384 + 255) / 256, 256, 0, stream>>>(W0, Ws, WT);

  int gblocks = (NV + 127) / 128;
  gemm_first<<<gblocks, 256, 0, stream>>>(x, WT, b0, x_curh, x0h, NV);

  for (int i = 0; i < 4; i++) {
    edge_agg<<<NE / 16, 256, 0, stream>>>(x_curh, cntE, itemsE, Xeh);
    gemm_fused<<<gblocks, 256, 0, stream>>>(Xeh, cntV, itemsV, x0h,
                                            WT + (size_t)(1 + i) * 16384, x_curh, NV);
  }
  gemm_out<<<gblocks, 256, 0, stream>>>(x_curh, Wout, bout, out, NV);
}

// Round 6
// 583.442 us; speedup vs baseline: 1.2027x; 1.2027x over previous
//
#include <hip/hip_runtime.h>

#define NV 100000
#define NE 50000
#define NNZ_C 800000
#define CAP_E 64        // slots per edge   (Poisson(16), +12 sigma)
#define CAP_V 48        // slots per vertex (Poisson(8),  +14 sigma)
#define NB_E 391        // ceil(NE/128) buckets of 128 edges
#define NB_V 782        // ceil(NV/128) buckets of 128 vertices
#define CAPB_E 2560     // Poisson(2048) + 11 sigma
#define CAPB_V 1408     // Poisson(1024) + 12 sigma

typedef unsigned int uint32;
typedef unsigned short u16;
typedef u16 u16x8 __attribute__((ext_vector_type(8)));
typedef short short8 __attribute__((ext_vector_type(8)));
typedef float floatx16 __attribute__((ext_vector_type(16)));

__device__ __forceinline__ float bf2f(u16 h) {
  return __uint_as_float(((uint32)h) << 16);
}
__device__ __forceinline__ u16 f2bf(float f) {
  uint32 u = __float_as_uint(f);
  u += 0x7FFF + ((u >> 16) & 1);   // RNE
  return (u16)(u >> 16);
}

// ---------------- CSR build: bucketed two-phase ----------------

__global__ void zero_bcur(int* p, int n) {
  int i = blockIdx.x * blockDim.x + threadIdx.x;
  if (i < n) p[i] = 0;
}

__global__ void bucket_scatter(const int* __restrict__ vertex, const int* __restrict__ edges,
                               int* __restrict__ bcur,
                               uint32* __restrict__ pairE, uint32* __restrict__ pairV) {
  int stride = gridDim.x * blockDim.x;
  for (int k = blockIdx.x * blockDim.x + threadIdx.x; k < NNZ_C; k += stride) {
    uint32 e = (uint32)edges[k], v = (uint32)vertex[k];
    uint32 be = e >> 7, bv = v >> 7;
    int pe = atomicAdd(&bcur[be << 4], 1);
    if (pe < CAPB_E) pairE[be * CAPB_E + pe] = ((e & 127u) << 25) | v;
    int pv = atomicAdd(&bcur[(NB_E + bv) << 4], 1);
    if (pv < CAPB_V) pairV[bv * CAPB_V + pv] = ((v & 127u) << 25) | e;
  }
}

__global__ __launch_bounds__(256) void expand(const uint32* __restrict__ pairs,
                                              const int* __restrict__ bcur, int curOff,
                                              int capb, int* __restrict__ items, int cap,
                                              int* __restrict__ cnt, int nKeys) {
  __shared__ int lcnt[128];
  int b = blockIdx.x, t = threadIdx.x;
  if (t < 128) lcnt[t] = 0;
  __syncthreads();
  int n = min(bcur[(curOff + b) << 4], capb);
  const uint32* p = pairs + (size_t)b * capb;
  for (int i = t; i < n; i += 256) {
    uint32 w = p[i];
    int loc = w >> 25;
    int val = (int)(w & 0x1FFFFFFu);
    int r = atomicAdd(&lcnt[loc], 1);
    int key = (b << 7) + loc;
    if (r < cap) items[(size_t)key * cap + r] = val;
  }
  __syncthreads();
  if (t < 128) {
    int key = (b << 7) + t;
    if (key < nKeys) cnt[key] = lcnt[t];
  }
}

// ---------------- weight prep ----------------
// WT: [0,16384) = W0T[n][k]; then 4x WeffT[i][n][k], Weff=(1-b)I+b*Ws[i]

__global__ void prep_weights(const float* __restrict__ W0, const float* __restrict__ Ws,
                             u16* __restrict__ WT) {
  int idx = blockIdx.x * blockDim.x + threadIdx.x;
  if (idx >= 5 * 16384) return;
  const float betas[4] = {0.4054651081f, 0.2231435513f, 0.1541506798f, 0.1177830357f};
  int sec = idx >> 14;
  int rc = idx & 16383;
  int n = rc >> 7, k = rc & 127;
  float v;
  if (sec == 0) {
    v = W0[k * 128 + n];
  } else {
    int i = sec - 1;
    float b = betas[i];
    v = b * Ws[i * 16384 + k * 128 + n];
    if (k == n) v += 1.0f - b;
  }
  WT[idx] = f2bf(v);
}

// ---------------- aggregations (bf16, 16 lanes/row, MLP-4) ----------------

__global__ __launch_bounds__(256) void edge_agg(const u16* __restrict__ Xh,
                                                const int* __restrict__ cntE,
                                                const int* __restrict__ itemsE,
                                                u16* __restrict__ Xeh) {
  int g = threadIdx.x >> 4;
  int lane = threadIdx.x & 15;
  int e = blockIdx.x * 16 + g;
  int cnt = cntE[e];
  int n = min(cnt, CAP_E);
  const int* it = itemsE + (size_t)e * CAP_E;
  float acc[8] = {0.f, 0.f, 0.f, 0.f, 0.f, 0.f, 0.f, 0.f};
  int j = 0;
  for (; j + 4 <= n; j += 4) {
    int4 vs = *(const int4*)(it + j);
    u16x8 a = *(const u16x8*)(Xh + (size_t)vs.x * 128 + lane * 8);
    u16x8 b = *(const u16x8*)(Xh + (size_t)vs.y * 128 + lane * 8);
    u16x8 c = *(const u16x8*)(Xh + (size_t)vs.z * 128 + lane * 8);
    u16x8 d = *(const u16x8*)(Xh + (size_t)vs.w * 128 + lane * 8);
    #pragma unroll
    for (int q = 0; q < 8; q++)
      acc[q] += (bf2f(a[q]) + bf2f(b[q])) + (bf2f(c[q]) + bf2f(d[q]));
  }
  for (; j < n; j++) {
    int v = it[j];
    u16x8 xv = *(const u16x8*)(Xh + (size_t)v * 128 + lane * 8);
    #pragma unroll
    for (int q = 0; q < 8; q++) acc[q] += bf2f(xv[q]);
  }
  float inv = 1.f / fmaxf((float)cnt, 1.f);
  u16x8 o;
  #pragma unroll
  for (int q = 0; q < 8; q++) o[q] = f2bf(acc[q] * inv);
  *(u16x8*)(Xeh + (size_t)e * 128 + lane * 8) = o;
}

__global__ __launch_bounds__(256) void vertex_agg(const u16* __restrict__ Xeh,
                                                  const int* __restrict__ cntV,
                                                  const int* __restrict__ itemsV,
                                                  const u16* __restrict__ x0h,
                                                  u16* __restrict__ Xih) {
  int g = threadIdx.x >> 4;
  int lane = threadIdx.x & 15;
  int v = blockIdx.x * 16 + g;
  int cnt = cntV[v];
  int n = min(cnt, CAP_V);
  const int* it = itemsV + (size_t)v * CAP_V;
  float acc[8] = {0.f, 0.f, 0.f, 0.f, 0.f, 0.f, 0.f, 0.f};
  int j = 0;
  for (; j + 4 <= n; j += 4) {
    int4 es = *(const int4*)(it + j);
    u16x8 a = *(const u16x8*)(Xeh + (size_t)es.x * 128 + lane * 8);
    u16x8 b = *(const u16x8*)(Xeh + (size_t)es.y * 128 + lane * 8);
    u16x8 c = *(const u16x8*)(Xeh + (size_t)es.z * 128 + lane * 8);
    u16x8 d = *(const u16x8*)(Xeh + (size_t)es.w * 128 + lane * 8);
    #pragma unroll
    for (int q = 0; q < 8; q++)
      acc[q] += (bf2f(a[q]) + bf2f(b[q])) + (bf2f(c[q]) + bf2f(d[q]));
  }
  for (; j < n; j++) {
    int e = it[j];
    u16x8 xv = *(const u16x8*)(Xeh + (size_t)e * 128 + lane * 8);
    #pragma unroll
    for (int q = 0; q < 8; q++) acc[q] += bf2f(xv[q]);
  }
  float inv = 1.f / fmaxf((float)cnt, 1.f);
  float sq = 0.f;
  #pragma unroll
  for (int q = 0; q < 8; q++) { acc[q] *= inv; sq += acc[q] * acc[q]; }
  sq += __shfl_xor(sq, 1, 64);
  sq += __shfl_xor(sq, 2, 64);
  sq += __shfl_xor(sq, 4, 64);
  sq += __shfl_xor(sq, 8, 64);
  float scale = (sq > 0.f) ? rsqrtf(sq) : 0.f;
  u16x8 x0v = *(const u16x8*)(x0h + (size_t)v * 128 + lane * 8);
  u16x8 o;
  #pragma unroll
  for (int q = 0; q < 8; q++)
    o[q] = f2bf(0.9f * acc[q] * scale + 0.1f * bf2f(x0v[q]));
  *(u16x8*)(Xih + (size_t)v * 128 + lane * 8) = o;
}

// ---------------- MFMA GEMM (32x32x16, 2x2 wave grid, 2x2 reg tile) ----------------
// A frag: row = lane&31, k = (lane>>5)*8 + j.  C/D: col = lane&31,
// row = (reg&3) + 8*(reg>>2) + 4*(lane>>5)  [m74/m101-verified]

__global__ __launch_bounds__(256) void gemm_mfma(const u16* __restrict__ Ah,
                                                 const u16* __restrict__ WT,
                                                 u16* __restrict__ Yh, int nrows) {
  __shared__ u16 As[128 * 136];
  __shared__ u16 Bs[128 * 136];
  int t = threadIdx.x;
  int row0 = blockIdx.x * 128;
  #pragma unroll
  for (int i = 0; i < 8; i++) {
    int idx = t + 256 * i;
    int r = idx >> 4, c8 = idx & 15;
    u16x8 v = {0, 0, 0, 0, 0, 0, 0, 0};
    if (row0 + r < nrows) v = *(const u16x8*)(Ah + (size_t)(row0 + r) * 128 + c8 * 8);
    *(u16x8*)&As[r * 136 + c8 * 8] = v;
    *(u16x8*)&Bs[r * 136 + c8 * 8] = *(const u16x8*)(WT + (size_t)r * 128 + c8 * 8);
  }
  __syncthreads();

  int w = t >> 6, lane = t & 63;
  int l31 = lane & 31, kh = lane >> 5;
  int wr = w >> 1, wc = w & 1;
  floatx16 acc[2][2];
  #pragma unroll
  for (int rt = 0; rt < 2; rt++)
    #pragma unroll
    for (int ct = 0; ct < 2; ct++)
      #pragma unroll
      for (int q = 0; q < 16; q++) acc[rt][ct][q] = 0.f;

  #pragma unroll
  for (int ks = 0; ks < 8; ks++) {
    int koff = ks * 16 + kh * 8;
    short8 a0 = *(const short8*)&As[(wr * 64 + l31) * 136 + koff];
    short8 a1 = *(const short8*)&As[(wr * 64 + 32 + l31) * 136 + koff];
    short8 b0 = *(const short8*)&Bs[(wc * 64 + l31) * 136 + koff];
    short8 b1 = *(const short8*)&Bs[(wc * 64 + 32 + l31) * 136 + koff];
    acc[0][0] = __builtin_amdgcn_mfma_f32_32x32x16_bf16(a0, b0, acc[0][0], 0, 0, 0);
    acc[0][1] = __builtin_amdgcn_mfma_f32_32x32x16_bf16(a0, b1, acc[0][1], 0, 0, 0);
    acc[1][0] = __builtin_amdgcn_mfma_f32_32x32x16_bf16(a1, b0, acc[1][0], 0, 0, 0);
    acc[1][1] = __builtin_amdgcn_mfma_f32_32x32x16_bf16(a1, b1, acc[1][1], 0, 0, 0);
  }
  __syncthreads();

  #pragma unroll
  for (int rt = 0; rt < 2; rt++)
    #pragma unroll
    for (int ct = 0; ct < 2; ct++) {
      int col = wc * 64 + ct * 32 + l31;
      #pragma unroll
      for (int reg = 0; reg < 16; reg++) {
        int row = wr * 64 + rt * 32 + (reg & 3) + 8 * (reg >> 2) + 4 * kh;
        As[row * 136 + col] = f2bf(fmaxf(acc[rt][ct][reg], 0.f));
      }
    }
  __syncthreads();
  #pragma unroll
  for (int i = 0; i < 8; i++) {
    int idx = t + 256 * i;
    int r = idx >> 4, c8 = idx & 15;
    if (row0 + r < nrows)
      *(u16x8*)(Yh + (size_t)(row0 + r) * 128 + c8 * 8) =
          *(const u16x8*)&As[r * 136 + c8 * 8];
  }
}

// first GEMM: fp32 A in, +bias, relu, dual bf16 outputs
__global__ __launch_bounds__(256) void gemm_first(const float* __restrict__ A,
                                                  const u16* __restrict__ WT,
                                                  const float* __restrict__ bias,
                                                  u16* __restrict__ Yh,
                                                  u16* __restrict__ Y2h, int nrows) {
  __shared__ u16 As[128 * 136];
  __shared__ u16 Bs[128 * 136];
  int t = threadIdx.x;
  int row0 = blockIdx.x * 128;
  #pragma unroll
  for (int i = 0; i < 8; i++) {
    int idx = t + 256 * i;
    int r = idx >> 4, c8 = idx & 15;
    u16x8 v = {0, 0, 0, 0, 0, 0, 0, 0};
    if (row0 + r < nrows) {
      const float* p = A + (size_t)(row0 + r) * 128 + c8 * 8;
      float4 a = *(const float4*)p;
      float4 b = *(const float4*)(p + 4);
      v[0] = f2bf(a.x); v[1] = f2bf(a.y); v[2] = f2bf(a.z); v[3] = f2bf(a.w);
      v[4] = f2bf(b.x); v[5] = f2bf(b.y); v[6] = f2bf(b.z); v[7] = f2bf(b.w);
    }
    *(u16x8*)&As[r * 136 + c8 * 8] = v;
    *(u16x8*)&Bs[r * 136 + c8 * 8] = *(const u16x8*)(WT + (size_t)r * 128 + c8 * 8);
  }
  __syncthreads();

  int w = t >> 6, lane = t & 63;
  int l31 = lane & 31, kh = lane >> 5;
  int wr = w >> 1, wc = w & 1;
  floatx16 acc[2][2];
  #pragma unroll
  for (int rt = 0; rt < 2; rt++)
    #pragma unroll
    for (int ct = 0; ct < 2; ct++)
      #pragma unroll
      for (int q = 0; q < 16; q++) acc[rt][ct][q] = 0.f;

  #pragma unroll
  for (int ks = 0; ks < 8; ks++) {
    int koff = ks * 16 + kh * 8;
    short8 a0 = *(const short8*)&As[(wr * 64 + l31) * 136 + koff];
    short8 a1 = *(const short8*)&As[(wr * 64 + 32 + l31) * 136 + koff];
    short8 b0 = *(const short8*)&Bs[(wc * 64 + l31) * 136 + koff];
    short8 b1 = *(const short8*)&Bs[(wc * 64 + 32 + l31) * 136 + koff];
    acc[0][0] = __builtin_amdgcn_mfma_f32_32x32x16_bf16(a0, b0, acc[0][0], 0, 0, 0);
    acc[0][1] = __builtin_amdgcn_mfma_f32_32x32x16_bf16(a0, b1, acc[0][1], 0, 0, 0);
    acc[1][0] = __builtin_amdgcn_mfma_f32_32x32x16_bf16(a1, b0, acc[1][0], 0, 0, 0);
    acc[1][1] = __builtin_amdgcn_mfma_f32_32x32x16_bf16(a1, b1, acc[1][1], 0, 0, 0);
  }
  __syncthreads();

  #pragma unroll
  for (int rt = 0; rt < 2; rt++)
    #pragma unroll
    for (int ct = 0; ct < 2; ct++) {
      int col = wc * 64 + ct * 32 + l31;
      float bv = bias[col];
      #pragma unroll
      for (int reg = 0; reg < 16; reg++) {
        int row = wr * 64 + rt * 32 + (reg & 3) + 8 * (reg >> 2) + 4 * kh;
        As[row * 136 + col] = f2bf(fmaxf(acc[rt][ct][reg] + bv, 0.f));
      }
    }
  __syncthreads();
  #pragma unroll
  for (int i = 0; i < 8; i++) {
    int idx = t + 256 * i;
    int r = idx >> 4, c8 = idx & 15;
    if (row0 + r < nrows) {
      u16x8 v = *(const u16x8*)&As[r * 136 + c8 * 8];
      *(u16x8*)(Yh + (size_t)(row0 + r) * 128 + c8 * 8) = v;
      *(u16x8*)(Y2h + (size_t)(row0 + r) * 128 + c8 * 8) = v;
    }
  }
}

// ---------------- output GEMM: out[nrows,40] = Xh @ Wout + bout ----------------

__global__ __launch_bounds__(256) void gemm_out(const u16* __restrict__ Xh,
                                                const float* __restrict__ W,
                                                const float* __restrict__ bias,
                                                float* __restrict__ Y, int nrows) {
  __shared__ float xs[128][36];
  __shared__ float ws[32][44];
  int t = threadIdx.x;
  int tr = t >> 3;
  int tc = t & 7;
  int row0 = blockIdx.x * 128;
  float acc[4][5];
  #pragma unroll
  for (int i = 0; i < 4; i++)
    #pragma unroll
    for (int j = 0; j < 5; j++) acc[i][j] = 0.f;

  for (int k0 = 0; k0 < 128; k0 += 32) {
    #pragma unroll
    for (int i = 0; i < 2; i++) {
      int idx = t + 256 * i;
      int r = idx >> 2, c8 = idx & 3;
      int gr = row0 + r;
      u16x8 v = {0, 0, 0, 0, 0, 0, 0, 0};
      if (gr < nrows) v = *(const u16x8*)(Xh + (size_t)gr * 128 + k0 + c8 * 8);
      #pragma unroll
      for (int q = 0; q < 8; q++) xs[r][c8 * 8 + q] = bf2f(v[q]);
    }
    #pragma unroll
    for (int i = 0; i < 5; i++) {
      int idx = t + 256 * i;
      int r = idx / 40, c = idx % 40;
      ws[r][c] = W[(k0 + r) * 40 + c];
    }
    __syncthreads();
    #pragma unroll
    for (int kk4 = 0; kk4 < 8; kk4++) {
      float4 xv[4];
      #pragma unroll
      for (int i = 0; i < 4; i++) xv[i] = *(const float4*)&xs[tr + 32 * i][kk4 * 4];
      #pragma unroll
      for (int q = 0; q < 4; q++) {
        int kk = kk4 * 4 + q;
        float wv[5];
        #pragma unroll
        for (int j = 0; j < 5; j++) wv[j] = ws[kk][tc * 5 + j];
        #pragma unroll
        for (int i = 0; i < 4; i++) {
          float xq = ((const float*)&xv[i])[q];
          #pragma unroll
          for (int j = 0; j < 5; j++) acc[i][j] += xq * wv[j];
        }
      }
    }
    __syncthreads();
  }
  #pragma unroll
  for (int i = 0; i < 4; i++) {
    int gr = row0 + tr + 32 * i;
    if (gr >= nrows) continue;
    #pragma unroll
    for (int j = 0; j < 5; j++) {
      int c = tc * 5 + j;
      Y[(long)gr * 40 + c] = acc[i][j] + bias[c];
    }
  }
}

// ---------------- launch ----------------

extern "C" void kernel_launch(void* const* d_in, const int* in_sizes, int n_in,
                              void* d_out, int out_size, void* d_ws, size_t ws_size,
                              hipStream_t stream) {
  const float* x    = (const float*)d_in[0];
  const float* W0   = (const float*)d_in[1];
  const float* b0   = (const float*)d_in[2];
  const float* Ws   = (const float*)d_in[3];
  const float* Wout = (const float*)d_in[4];
  const float* bout = (const float*)d_in[5];
  const int* vertex = (const int*)d_in[6];
  const int* edges  = (const int*)d_in[7];
  float* out = (float*)d_out;

  char* base = (char*)d_ws;
  size_t o = 0;
  auto alloc = [&](size_t bytes) -> char* {
    char* r = base + o;
    o += (bytes + 255) & ~(size_t)255;
    return r;
  };
  u16* x_curh = (u16*)alloc((size_t)NV * 128 * 2);
  u16* x0h    = (u16*)alloc((size_t)NV * 128 * 2);
  u16* Xeh    = (u16*)alloc((size_t)NE * 128 * 2);
  u16* WT     = (u16*)alloc((size_t)5 * 16384 * 2);
  int* cntE   = (int*)alloc((size_t)NE * 4);
  int* cntV   = (int*)alloc((size_t)NV * 4);
  int* itemsE = (int*)alloc((size_t)NE * CAP_E * 4);
  int* itemsV = (int*)alloc((size_t)NV * CAP_V * 4);
  uint32* pairE = (uint32*)alloc((size_t)NB_E * CAPB_E * 4);
  uint32* pairV = (uint32*)alloc((size_t)NB_V * CAPB_V * 4);
  int* bcur   = (int*)alloc((size_t)(NB_E + NB_V) * 16 * 4);

  int nb = (NB_E + NB_V) * 16;
  zero_bcur<<<(nb + 255) / 256, 256, 0, stream>>>(bcur, nb);
  bucket_scatter<<<1024, 256, 0, stream>>>(vertex, edges, bcur, pairE, pairV);
  expand<<<NB_E, 256, 0, stream>>>(pairE, bcur, 0, CAPB_E, itemsE, CAP_E, cntE, NE);
  expand<<<NB_V, 256, 0, stream>>>(pairV, bcur, NB_E, CAPB_V, itemsV, CAP_V, cntV, NV);
  prep_weights<<<(5 * 16384 + 255) / 256, 256, 0, stream>>>(W0, Ws, WT);

  int gblocks = (NV + 127) / 128;
  gemm_first<<<gblocks, 256, 0, stream>>>(x, WT, b0, x_curh, x0h, NV);

  for (int i = 0; i < 4; i++) {
    edge_agg<<<NE / 16, 256, 0, stream>>>(x_curh, cntE, itemsE, Xeh);
    vertex_agg<<<NV / 16, 256, 0, stream>>>(Xeh, cntV, itemsV, x0h, x_curh);
    gemm_mfma<<<gblocks, 256, 0, stream>>>(x_curh, WT + (size_t)(1 + i) * 16384,
                                           x_curh, NV);
  }
  gemm_out<<<gblocks, 256, 0, stream>>>(x_curh, Wout, bout, out, NV);
}

// Round 7
// 579.548 us; speedup vs baseline: 1.2108x; 1.0067x over previous
//
#include <hip/hip_runtime.h>

#define NV 100000
#define NE 50000
#define NNZ_C 800000
#define CAP_E 64        // slots per edge   (Poisson(16), +12 sigma)
#define CAP_V 48        // slots per vertex (Poisson(8),  +14 sigma)
#define NB_E 391        // ceil(NE/128) buckets of 128 edges
#define NB_V 782        // ceil(NV/128) buckets of 128 vertices
#define CAPB_E8 512     // per-XCD sub-stream cap (balanced mean 256, +16 sigma)
#define CAPB_V8 256     // per-XCD sub-stream cap (balanced mean 128, +11 sigma)
#define OVF_CAP 810000  // overflow list covers worst case fully -> always correct
#define NCUR ((NB_E + NB_V) * 8)
#define OVCNT_E NCUR
#define OVCNT_V (NCUR + 1)

typedef unsigned int uint32;
typedef unsigned short u16;
typedef u16 u16x8 __attribute__((ext_vector_type(8)));
typedef short short8 __attribute__((ext_vector_type(8)));
typedef float floatx16 __attribute__((ext_vector_type(16)));

__device__ __forceinline__ float bf2f(u16 h) {
  return __uint_as_float(((uint32)h) << 16);
}
__device__ __forceinline__ u16 f2bf(float f) {
  uint32 u = __float_as_uint(f);
  u += 0x7FFF + ((u >> 16) & 1);   // RNE
  return (u16)(u >> 16);
}
__device__ __forceinline__ int xcc_id() {
  int x;
  asm("s_getreg_b32 %0, hwreg(HW_REG_XCC_ID)" : "=s"(x));
  return x & 7;
}

// ---------------- CSR build: bucketed two-phase, XCD-local streams ----------------

__global__ void zero_bcur(int* p, int n) {
  int i = blockIdx.x * blockDim.x + threadIdx.x;
  if (i < n) p[i] = 0;
}

__global__ void bucket_scatter(const int* __restrict__ vertex, const int* __restrict__ edges,
                               int* __restrict__ bcur,
                               uint32* __restrict__ pairE, uint32* __restrict__ pairV,
                               uint2* __restrict__ ovfE, uint2* __restrict__ ovfV) {
  int xcd = xcc_id();
  int stride = gridDim.x * blockDim.x;
  for (int k = blockIdx.x * blockDim.x + threadIdx.x; k < NNZ_C; k += stride) {
    uint32 e = (uint32)edges[k], v = (uint32)vertex[k];
    uint32 be = e >> 7, bv = v >> 7;
    uint32 pkE = ((e & 127u) << 25) | v;
    uint32 pkV = ((v & 127u) << 25) | e;
    int ce = (int)(be * 8) + xcd;
    int pe = atomicAdd(&bcur[ce << 4], 1);
    if (pe < CAPB_E8) pairE[(size_t)ce * CAPB_E8 + pe] = pkE;
    else {
      int op = atomicAdd(&bcur[OVCNT_E << 4], 1);
      if (op < OVF_CAP) ovfE[op] = make_uint2(be, pkE);
    }
    int cv = (int)((NB_E + bv) * 8) + xcd;
    int pv = atomicAdd(&bcur[cv << 4], 1);
    if (pv < CAPB_V8) pairV[(size_t)((size_t)bv * 8 + xcd) * CAPB_V8 + pv] = pkV;
    else {
      int op = atomicAdd(&bcur[OVCNT_V << 4], 1);
      if (op < OVF_CAP) ovfV[op] = make_uint2(bv, pkV);
    }
  }
}

// one block per bucket: rank via LDS atomics into dense per-key lists
__global__ __launch_bounds__(256) void expand(const uint32* __restrict__ pairs,
                                              const int* __restrict__ bcur, int subOff,
                                              int capb, const uint2* __restrict__ ovf,
                                              int ovfIdx, int* __restrict__ items, int cap,
                                              int* __restrict__ cnt, int nKeys) {
  __shared__ int lcnt[128];
  int b = blockIdx.x, t = threadIdx.x;
  if (t < 128) lcnt[t] = 0;
  __syncthreads();
  #pragma unroll
  for (int x = 0; x < 8; x++) {
    int c = subOff + b * 8 + x;
    int n = min(bcur[c << 4], capb);
    const uint32* p = pairs + (size_t)(b * 8 + x) * capb;
    for (int i = t; i < n; i += 256) {
      uint32 w = p[i];
      int loc = w >> 25;
      int val = (int)(w & 0x1FFFFFFu);
      int r = atomicAdd(&lcnt[loc], 1);
      if (r < cap) items[(size_t)((b << 7) + loc) * cap + r] = val;
    }
  }
  int novf = min(bcur[ovfIdx << 4], OVF_CAP);
  for (int i = t; i < novf; i += 256) {
    uint2 w = ovf[i];
    if ((int)w.x == b) {
      int loc = w.y >> 25;
      int val = (int)(w.y & 0x1FFFFFFu);
      int r = atomicAdd(&lcnt[loc], 1);
      if (r < cap) items[(size_t)((b << 7) + loc) * cap + r] = val;
    }
  }
  __syncthreads();
  if (t < 128) {
    int key = (b << 7) + t;
    if (key < nKeys) cnt[key] = lcnt[t];
  }
}

// ---------------- weight prep ----------------
// WT: [0,16384) = W0T[n][k]; then 4x WeffT[i][n][k], Weff=(1-b)I+b*Ws[i]

__global__ void prep_weights(const float* __restrict__ W0, const float* __restrict__ Ws,
                             u16* __restrict__ WT) {
  int idx = blockIdx.x * blockDim.x + threadIdx.x;
  if (idx >= 5 * 16384) return;
  const float betas[4] = {0.4054651081f, 0.2231435513f, 0.1541506798f, 0.1177830357f};
  int sec = idx >> 14;
  int rc = idx & 16383;
  int n = rc >> 7, k = rc & 127;
  float v;
  if (sec == 0) {
    v = W0[k * 128 + n];
  } else {
    int i = sec - 1;
    float b = betas[i];
    v = b * Ws[i * 16384 + k * 128 + n];
    if (k == n) v += 1.0f - b;
  }
  WT[idx] = f2bf(v);
}

// ---------------- aggregations (bf16, 16 lanes/row, MLP-8/4/1) ----------------

__global__ __launch_bounds__(256) void edge_agg(const u16* __restrict__ Xh,
                                                const int* __restrict__ cntE,
                                                const int* __restrict__ itemsE,
                                                u16* __restrict__ Xeh) {
  int g = threadIdx.x >> 4;
  int lane = threadIdx.x & 15;
  int e = blockIdx.x * 16 + g;
  int cnt = cntE[e];
  int n = min(cnt, CAP_E);
  const int* it = itemsE + (size_t)e * CAP_E;
  float acc[8] = {0.f, 0.f, 0.f, 0.f, 0.f, 0.f, 0.f, 0.f};
  int j = 0;
  for (; j + 8 <= n; j += 8) {
    int4 v0 = *(const int4*)(it + j);
    int4 v1 = *(const int4*)(it + j + 4);
    u16x8 r0 = *(const u16x8*)(Xh + (size_t)v0.x * 128 + lane * 8);
    u16x8 r1 = *(const u16x8*)(Xh + (size_t)v0.y * 128 + lane * 8);
    u16x8 r2 = *(const u16x8*)(Xh + (size_t)v0.z * 128 + lane * 8);
    u16x8 r3 = *(const u16x8*)(Xh + (size_t)v0.w * 128 + lane * 8);
    u16x8 r4 = *(const u16x8*)(Xh + (size_t)v1.x * 128 + lane * 8);
    u16x8 r5 = *(const u16x8*)(Xh + (size_t)v1.y * 128 + lane * 8);
    u16x8 r6 = *(const u16x8*)(Xh + (size_t)v1.z * 128 + lane * 8);
    u16x8 r7 = *(const u16x8*)(Xh + (size_t)v1.w * 128 + lane * 8);
    #pragma unroll
    for (int q = 0; q < 8; q++)
      acc[q] += ((bf2f(r0[q]) + bf2f(r1[q])) + (bf2f(r2[q]) + bf2f(r3[q]))) +
                ((bf2f(r4[q]) + bf2f(r5[q])) + (bf2f(r6[q]) + bf2f(r7[q])));
  }
  for (; j + 4 <= n; j += 4) {
    int4 vs = *(const int4*)(it + j);
    u16x8 a = *(const u16x8*)(Xh + (size_t)vs.x * 128 + lane * 8);
    u16x8 b = *(const u16x8*)(Xh + (size_t)vs.y * 128 + lane * 8);
    u16x8 c = *(const u16x8*)(Xh + (size_t)vs.z * 128 + lane * 8);
    u16x8 d = *(const u16x8*)(Xh + (size_t)vs.w * 128 + lane * 8);
    #pragma unroll
    for (int q = 0; q < 8; q++)
      acc[q] += (bf2f(a[q]) + bf2f(b[q])) + (bf2f(c[q]) + bf2f(d[q]));
  }
  for (; j < n; j++) {
    int v = it[j];
    u16x8 xv = *(const u16x8*)(Xh + (size_t)v * 128 + lane * 8);
    #pragma unroll
    for (int q = 0; q < 8; q++) acc[q] += bf2f(xv[q]);
  }
  float inv = 1.f / fmaxf((float)cnt, 1.f);
  u16x8 o;
  #pragma unroll
  for (int q = 0; q < 8; q++) o[q] = f2bf(acc[q] * inv);
  *(u16x8*)(Xeh + (size_t)e * 128 + lane * 8) = o;
}

__global__ __launch_bounds__(256) void vertex_agg(const u16* __restrict__ Xeh,
                                                  const int* __restrict__ cntV,
                                                  const int* __restrict__ itemsV,
                                                  const u16* __restrict__ x0h,
                                                  u16* __restrict__ Xih) {
  int g = threadIdx.x >> 4;
  int lane = threadIdx.x & 15;
  int v = blockIdx.x * 16 + g;
  int cnt = cntV[v];
  int n = min(cnt, CAP_V);
  const int* it = itemsV + (size_t)v * CAP_V;
  float acc[8] = {0.f, 0.f, 0.f, 0.f, 0.f, 0.f, 0.f, 0.f};
  int j = 0;
  for (; j + 8 <= n; j += 8) {
    int4 e0 = *(const int4*)(it + j);
    int4 e1 = *(const int4*)(it + j + 4);
    u16x8 r0 = *(const u16x8*)(Xeh + (size_t)e0.x * 128 + lane * 8);
    u16x8 r1 = *(const u16x8*)(Xeh + (size_t)e0.y * 128 + lane * 8);
    u16x8 r2 = *(const u16x8*)(Xeh + (size_t)e0.z * 128 + lane * 8);
    u16x8 r3 = *(const u16x8*)(Xeh + (size_t)e0.w * 128 + lane * 8);
    u16x8 r4 = *(const u16x8*)(Xeh + (size_t)e1.x * 128 + lane * 8);
    u16x8 r5 = *(const u16x8*)(Xeh + (size_t)e1.y * 128 + lane * 8);
    u16x8 r6 = *(const u16x8*)(Xeh + (size_t)e1.z * 128 + lane * 8);
    u16x8 r7 = *(const u16x8*)(Xeh + (size_t)e1.w * 128 + lane * 8);
    #pragma unroll
    for (int q = 0; q < 8; q++)
      acc[q] += ((bf2f(r0[q]) + bf2f(r1[q])) + (bf2f(r2[q]) + bf2f(r3[q]))) +
                ((bf2f(r4[q]) + bf2f(r5[q])) + (bf2f(r6[q]) + bf2f(r7[q])));
  }
  for (; j + 4 <= n; j += 4) {
    int4 es = *(const int4*)(it + j);
    u16x8 a = *(const u16x8*)(Xeh + (size_t)es.x * 128 + lane * 8);
    u16x8 b = *(const u16x8*)(Xeh + (size_t)es.y * 128 + lane * 8);
    u16x8 c = *(const u16x8*)(Xeh + (size_t)es.z * 128 + lane * 8);
    u16x8 d = *(const u16x8*)(Xeh + (size_t)es.w * 128 + lane * 8);
    #pragma unroll
    for (int q = 0; q < 8; q++)
      acc[q] += (bf2f(a[q]) + bf2f(b[q])) + (bf2f(c[q]) + bf2f(d[q]));
  }
  for (; j < n; j++) {
    int e = it[j];
    u16x8 xv = *(const u16x8*)(Xeh + (size_t)e * 128 + lane * 8);
    #pragma unroll
    for (int q = 0; q < 8; q++) acc[q] += bf2f(xv[q]);
  }
  float inv = 1.f / fmaxf((float)cnt, 1.f);
  float sq = 0.f;
  #pragma unroll
  for (int q = 0; q < 8; q++) { acc[q] *= inv; sq += acc[q] * acc[q]; }
  sq += __shfl_xor(sq, 1, 64);
  sq += __shfl_xor(sq, 2, 64);
  sq += __shfl_xor(sq, 4, 64);
  sq += __shfl_xor(sq, 8, 64);
  float scale = (sq > 0.f) ? rsqrtf(sq) : 0.f;
  u16x8 x0v = *(const u16x8*)(x0h + (size_t)v * 128 + lane * 8);
  u16x8 o;
  #pragma unroll
  for (int q = 0; q < 8; q++)
    o[q] = f2bf(0.9f * acc[q] * scale + 0.1f * bf2f(x0v[q]));
  *(u16x8*)(Xih + (size_t)v * 128 + lane * 8) = o;
}

// ---------------- MFMA GEMM (32x32x16, 2x2 wave grid, 2x2 reg tile) ----------------
// A frag: row = lane&31, k = (lane>>5)*8 + j.  C/D: col = lane&31,
// row = (reg&3) + 8*(reg>>2) + 4*(lane>>5)  [m74/m101-verified]

__global__ __launch_bounds__(256) void gemm_mfma(const u16* __restrict__ Ah,
                                                 const u16* __restrict__ WT,
                                                 u16* __restrict__ Yh, int nrows) {
  __shared__ u16 As[128 * 136];
  __shared__ u16 Bs[128 * 136];
  int t = threadIdx.x;
  int row0 = blockIdx.x * 128;
  #pragma unroll
  for (int i = 0; i < 8; i++) {
    int idx = t + 256 * i;
    int r = idx >> 4, c8 = idx & 15;
    u16x8 v = {0, 0, 0, 0, 0, 0, 0, 0};
    if (row0 + r < nrows) v = *(const u16x8*)(Ah + (size_t)(row0 + r) * 128 + c8 * 8);
    *(u16x8*)&As[r * 136 + c8 * 8] = v;
    *(u16x8*)&Bs[r * 136 + c8 * 8] = *(const u16x8*)(WT + (size_t)r * 128 + c8 * 8);
  }
  __syncthreads();

  int w = t >> 6, lane = t & 63;
  int l31 = lane & 31, kh = lane >> 5;
  int wr = w >> 1, wc = w & 1;
  floatx16 acc[2][2];
  #pragma unroll
  for (int rt = 0; rt < 2; rt++)
    #pragma unroll
    for (int ct = 0; ct < 2; ct++)
      #pragma unroll
      for (int q = 0; q < 16; q++) acc[rt][ct][q] = 0.f;

  #pragma unroll
  for (int ks = 0; ks < 8; ks++) {
    int koff = ks * 16 + kh * 8;
    short8 a0 = *(const short8*)&As[(wr * 64 + l31) * 136 + koff];
    short8 a1 = *(const short8*)&As[(wr * 64 + 32 + l31) * 136 + koff];
    short8 b0 = *(const short8*)&Bs[(wc * 64 + l31) * 136 + koff];
    short8 b1 = *(const short8*)&Bs[(wc * 64 + 32 + l31) * 136 + koff];
    acc[0][0] = __builtin_amdgcn_mfma_f32_32x32x16_bf16(a0, b0, acc[0][0], 0, 0, 0);
    acc[0][1] = __builtin_amdgcn_mfma_f32_32x32x16_bf16(a0, b1, acc[0][1], 0, 0, 0);
    acc[1][0] = __builtin_amdgcn_mfma_f32_32x32x16_bf16(a1, b0, acc[1][0], 0, 0, 0);
    acc[1][1] = __builtin_amdgcn_mfma_f32_32x32x16_bf16(a1, b1, acc[1][1], 0, 0, 0);
  }
  __syncthreads();

  #pragma unroll
  for (int rt = 0; rt < 2; rt++)
    #pragma unroll
    for (int ct = 0; ct < 2; ct++) {
      int col = wc * 64 + ct * 32 + l31;
      #pragma unroll
      for (int reg = 0; reg < 16; reg++) {
        int row = wr * 64 + rt * 32 + (reg & 3) + 8 * (reg >> 2) + 4 * kh;
        As[row * 136 + col] = f2bf(fmaxf(acc[rt][ct][reg], 0.f));
      }
    }
  __syncthreads();
  #pragma unroll
  for (int i = 0; i < 8; i++) {
    int idx = t + 256 * i;
    int r = idx >> 4, c8 = idx & 15;
    if (row0 + r < nrows)
      *(u16x8*)(Yh + (size_t)(row0 + r) * 128 + c8 * 8) =
          *(const u16x8*)&As[r * 136 + c8 * 8];
  }
}

// first GEMM: fp32 A in, +bias, relu, dual bf16 outputs
__global__ __launch_bounds__(256) void gemm_first(const float* __restrict__ A,
                                                  const u16* __restrict__ WT,
                                                  const float* __restrict__ bias,
                                                  u16* __restrict__ Yh,
                                                  u16* __restrict__ Y2h, int nrows) {
  __shared__ u16 As[128 * 136];
  __shared__ u16 Bs[128 * 136];
  int t = threadIdx.x;
  int row0 = blockIdx.x * 128;
  #pragma unroll
  for (int i = 0; i < 8; i++) {
    int idx = t + 256 * i;
    int r = idx >> 4, c8 = idx & 15;
    u16x8 v = {0, 0, 0, 0, 0, 0, 0, 0};
    if (row0 + r < nrows) {
      const float* p = A + (size_t)(row0 + r) * 128 + c8 * 8;
      float4 a = *(const float4*)p;
      float4 b = *(const float4*)(p + 4);
      v[0] = f2bf(a.x); v[1] = f2bf(a.y); v[2] = f2bf(a.z); v[3] = f2bf(a.w);
      v[4] = f2bf(b.x); v[5] = f2bf(b.y); v[6] = f2bf(b.z); v[7] = f2bf(b.w);
    }
    *(u16x8*)&As[r * 136 + c8 * 8] = v;
    *(u16x8*)&Bs[r * 136 + c8 * 8] = *(const u16x8*)(WT + (size_t)r * 128 + c8 * 8);
  }
  __syncthreads();

  int w = t >> 6, lane = t & 63;
  int l31 = lane & 31, kh = lane >> 5;
  int wr = w >> 1, wc = w & 1;
  floatx16 acc[2][2];
  #pragma unroll
  for (int rt = 0; rt < 2; rt++)
    #pragma unroll
    for (int ct = 0; ct < 2; ct++)
      #pragma unroll
      for (int q = 0; q < 16; q++) acc[rt][ct][q] = 0.f;

  #pragma unroll
  for (int ks = 0; ks < 8; ks++) {
    int koff = ks * 16 + kh * 8;
    short8 a0 = *(const short8*)&As[(wr * 64 + l31) * 136 + koff];
    short8 a1 = *(const short8*)&As[(wr * 64 + 32 + l31) * 136 + koff];
    short8 b0 = *(const short8*)&Bs[(wc * 64 + l31) * 136 + koff];
    short8 b1 = *(const short8*)&Bs[(wc * 64 + 32 + l31) * 136 + koff];
    acc[0][0] = __builtin_amdgcn_mfma_f32_32x32x16_bf16(a0, b0, acc[0][0], 0, 0, 0);
    acc[0][1] = __builtin_amdgcn_mfma_f32_32x32x16_bf16(a0, b1, acc[0][1], 0, 0, 0);
    acc[1][0] = __builtin_amdgcn_mfma_f32_32x32x16_bf16(a1, b0, acc[1][0], 0, 0, 0);
    acc[1][1] = __builtin_amdgcn_mfma_f32_32x32x16_bf16(a1, b1, acc[1][1], 0, 0, 0);
  }
  __syncthreads();

  #pragma unroll
  for (int rt = 0; rt < 2; rt++)
    #pragma unroll
    for (int ct = 0; ct < 2; ct++) {
      int col = wc * 64 + ct * 32 + l31;
      float bv = bias[col];
      #pragma unroll
      for (int reg = 0; reg < 16; reg++) {
        int row = wr * 64 + rt * 32 + (reg & 3) + 8 * (reg >> 2) + 4 * kh;
        As[row * 136 + col] = f2bf(fmaxf(acc[rt][ct][reg] + bv, 0.f));
      }
    }
  __syncthreads();
  #pragma unroll
  for (int i = 0; i < 8; i++) {
    int idx = t + 256 * i;
    int r = idx >> 4, c8 = idx & 15;
    if (row0 + r < nrows) {
      u16x8 v = *(const u16x8*)&As[r * 136 + c8 * 8];
      *(u16x8*)(Yh + (size_t)(row0 + r) * 128 + c8 * 8) = v;
      *(u16x8*)(Y2h + (size_t)(row0 + r) * 128 + c8 * 8) = v;
    }
  }
}

// ---------------- output GEMM: out[nrows,40] = Xh @ Wout + bout ----------------

__global__ __launch_bounds__(256) void gemm_out(const u16* __restrict__ Xh,
                                                const float* __restrict__ W,
                                                const float* __restrict__ bias,
                                                float* __restrict__ Y, int nrows) {
  __shared__ float xs[128][36];
  __shared__ float ws[32][44];
  int t = threadIdx.x;
  int tr = t >> 3;
  int tc = t & 7;
  int row0 = blockIdx.x * 128;
  float acc[4][5];
  #pragma unroll
  for (int i = 0; i < 4; i++)
    #pragma unroll
    for (int j = 0; j < 5; j++) acc[i][j] = 0.f;

  for (int k0 = 0; k0 < 128; k0 += 32) {
    #pragma unroll
    for (int i = 0; i < 2; i++) {
      int idx = t + 256 * i;
      int r = idx >> 2, c8 = idx & 3;
      int gr = row0 + r;
      u16x8 v = {0, 0, 0, 0, 0, 0, 0, 0};
      if (gr < nrows) v = *(const u16x8*)(Xh + (size_t)gr * 128 + k0 + c8 * 8);
      #pragma unroll
      for (int q = 0; q < 8; q++) xs[r][c8 * 8 + q] = bf2f(v[q]);
    }
    #pragma unroll
    for (int i = 0; i < 5; i++) {
      int idx = t + 256 * i;
      int r = idx / 40, c = idx % 40;
      ws[r][c] = W[(k0 + r) * 40 + c];
    }
    __syncthreads();
    #pragma unroll
    for (int kk4 = 0; kk4 < 8; kk4++) {
      float4 xv[4];
      #pragma unroll
      for (int i = 0; i < 4; i++) xv[i] = *(const float4*)&xs[tr + 32 * i][kk4 * 4];
      #pragma unroll
      for (int q = 0; q < 4; q++) {
        int kk = kk4 * 4 + q;
        float wv[5];
        #pragma unroll
        for (int j = 0; j < 5; j++) wv[j] = ws[kk][tc * 5 + j];
        #pragma unroll
        for (int i = 0; i < 4; i++) {
          float xq = ((const float*)&xv[i])[q];
          #pragma unroll
          for (int j = 0; j < 5; j++) acc[i][j] += xq * wv[j];
        }
      }
    }
    __syncthreads();
  }
  #pragma unroll
  for (int i = 0; i < 4; i++) {
    int gr = row0 + tr + 32 * i;
    if (gr >= nrows) continue;
    #pragma unroll
    for (int j = 0; j < 5; j++) {
      int c = tc * 5 + j;
      Y[(long)gr * 40 + c] = acc[i][j] + bias[c];
    }
  }
}

// ---------------- launch ----------------

extern "C" void kernel_launch(void* const* d_in, const int* in_sizes, int n_in,
                              void* d_out, int out_size, void* d_ws, size_t ws_size,
                              hipStream_t stream) {
  const float* x    = (const float*)d_in[0];
  const float* W0   = (const float*)d_in[1];
  const float* b0   = (const float*)d_in[2];
  const float* Ws   = (const float*)d_in[3];
  const float* Wout = (const float*)d_in[4];
  const float* bout = (const float*)d_in[5];
  const int* vertex = (const int*)d_in[6];
  const int* edges  = (const int*)d_in[7];
  float* out = (float*)d_out;

  char* base = (char*)d_ws;
  size_t o = 0;
  auto alloc = [&](size_t bytes) -> char* {
    char* r = base + o;
    o += (bytes + 255) & ~(size_t)255;
    return r;
  };
  u16* x_curh = (u16*)alloc((size_t)NV * 128 * 2);
  u16* x0h    = (u16*)alloc((size_t)NV * 128 * 2);
  u16* Xeh    = (u16*)alloc((size_t)NE * 128 * 2);
  u16* WT     = (u16*)alloc((size_t)5 * 16384 * 2);
  int* cntE   = (int*)alloc((size_t)NE * 4);
  int* cntV   = (int*)alloc((size_t)NV * 4);
  int* itemsE = (int*)alloc((size_t)NE * CAP_E * 4);
  int* itemsV = (int*)alloc((size_t)NV * CAP_V * 4);
  uint32* pairE = (uint32*)alloc((size_t)NB_E * 8 * CAPB_E8 * 4);
  uint32* pairV = (uint32*)alloc((size_t)NB_V * 8 * CAPB_V8 * 4);
  uint2* ovfE  = (uint2*)alloc((size_t)OVF_CAP * 8);
  uint2* ovfV  = (uint2*)alloc((size_t)OVF_CAP * 8);
  int* bcur   = (int*)alloc((size_t)(NCUR + 2) * 16 * 4);

  int nb = (NCUR + 2) * 16;
  zero_bcur<<<(nb + 255) / 256, 256, 0, stream>>>(bcur, nb);
  bucket_scatter<<<1024, 256, 0, stream>>>(vertex, edges, bcur, pairE, pairV, ovfE, ovfV);
  expand<<<NB_E, 256, 0, stream>>>(pairE, bcur, 0, CAPB_E8, ovfE, OVCNT_E,
                                   itemsE, CAP_E, cntE, NE);
  expand<<<NB_V, 256, 0, stream>>>(pairV, bcur, NB_E * 8, CAPB_V8, ovfV, OVCNT_V,
                                   itemsV, CAP_V, cntV, NV);
  prep_weights<<<(5 * 16384 + 255) / 256, 256, 0, stream>>>(W0, Ws, WT);

  int gblocks = (NV + 127) / 128;
  gemm_first<<<gblocks, 256, 0, stream>>>(x, WT, b0, x_curh, x0h, NV);

  for (int i = 0; i < 4; i++) {
    edge_agg<<<NE / 16, 256, 0, stream>>>(x_curh, cntE, itemsE, Xeh);
    vertex_agg<<<NV / 16, 256, 0, stream>>>(Xeh, cntV, itemsV, x0h, x_curh);
    gemm_mfma<<<gblocks, 256, 0, stream>>>(x_curh, WT + (size_t)(1 + i) * 16384,
                                           x_curh, NV);
  }
  gemm_out<<<gblocks, 256, 0, stream>>>(x_curh, Wout, bout, out, NV);
}

// Round 8
// 555.193 us; speedup vs baseline: 1.2639x; 1.0439x over previous
//
#include <hip/hip_runtime.h>

#define NV 100000
#define NE 50000
#define NNZ_C 800000
#define CAP_E 64        // slots per edge   (multiple of 16)
#define CAP_V 48        // slots per vertex (multiple of 8)
#define NB_E 391        // ceil(NE/128)
#define NB_V 782        // ceil(NV/128)
#define CAPB_E8 512     // per-XCD sub-stream cap
#define CAPB_V8 256
#define OVF_CAP 810000  // overflow covers worst case -> always correct
#define NCUR ((NB_E + NB_V) * 8)
#define OVCNT_E NCUR
#define OVCNT_V (NCUR + 1)

typedef unsigned int uint32;
typedef unsigned short u16;
typedef u16 u16x8 __attribute__((ext_vector_type(8)));
typedef short short8 __attribute__((ext_vector_type(8)));
typedef float floatx16 __attribute__((ext_vector_type(16)));

__device__ __forceinline__ float bf2f(u16 h) {
  return __uint_as_float(((uint32)h) << 16);
}
__device__ __forceinline__ u16 f2bf(float f) {
  uint32 u = __float_as_uint(f);
  u += 0x7FFF + ((u >> 16) & 1);   // RNE
  return (u16)(u >> 16);
}
__device__ __forceinline__ int xcc_id() {
  int x;
  asm("s_getreg_b32 %0, hwreg(HW_REG_XCC_ID)" : "=s"(x));
  return x & 7;
}

// ---------------- zero cursors + dummy gather rows ----------------

__global__ void zero_misc(int* __restrict__ bcur, int nb,
                          u16* __restrict__ dummyX, u16* __restrict__ dummyXe) {
  int i = blockIdx.x * blockDim.x + threadIdx.x;
  if (i < nb) bcur[i] = 0;
  if (i < 128) { dummyX[i] = 0; dummyXe[i] = 0; }
}

// ---------------- bucket scatter: 2-way unroll, hoisted atomics ----------------

__global__ void bucket_scatter(const int* __restrict__ vertex, const int* __restrict__ edges,
                               int* __restrict__ bcur,
                               uint32* __restrict__ pairE, uint32* __restrict__ pairV,
                               uint2* __restrict__ ovfE, uint2* __restrict__ ovfV) {
  int xcd = xcc_id();
  int stride = gridDim.x * blockDim.x;
  const int half = NNZ_C / 2;
  for (int k = blockIdx.x * blockDim.x + threadIdx.x; k < half; k += stride) {
    uint32 e0 = (uint32)edges[k],        v0 = (uint32)vertex[k];
    uint32 e1 = (uint32)edges[k + half], v1 = (uint32)vertex[k + half];
    uint32 be0 = e0 >> 7, bv0 = v0 >> 7, be1 = e1 >> 7, bv1 = v1 >> 7;
    int se0 = (int)(be0 * 8) + xcd, sv0 = (int)(bv0 * 8) + xcd;
    int se1 = (int)(be1 * 8) + xcd, sv1 = (int)(bv1 * 8) + xcd;
    // 4 independent atomic chains in flight
    int pe0 = atomicAdd(&bcur[se0 << 4], 1);
    int pv0 = atomicAdd(&bcur[(NB_E * 8 + sv0) << 4], 1);
    int pe1 = atomicAdd(&bcur[se1 << 4], 1);
    int pv1 = atomicAdd(&bcur[(NB_E * 8 + sv1) << 4], 1);
    uint32 pkE0 = ((e0 & 127u) << 25) | v0, pkV0 = ((v0 & 127u) << 25) | e0;
    uint32 pkE1 = ((e1 & 127u) << 25) | v1, pkV1 = ((v1 & 127u) << 25) | e1;
    if (pe0 < CAPB_E8) pairE[(size_t)se0 * CAPB_E8 + pe0] = pkE0;
    else { int op = atomicAdd(&bcur[OVCNT_E << 4], 1); if (op < OVF_CAP) ovfE[op] = make_uint2(be0, pkE0); }
    if (pv0 < CAPB_V8) pairV[(size_t)sv0 * CAPB_V8 + pv0] = pkV0;
    else { int op = atomicAdd(&bcur[OVCNT_V << 4], 1); if (op < OVF_CAP) ovfV[op] = make_uint2(bv0, pkV0); }
    if (pe1 < CAPB_E8) pairE[(size_t)se1 * CAPB_E8 + pe1] = pkE1;
    else { int op = atomicAdd(&bcur[OVCNT_E << 4], 1); if (op < OVF_CAP) ovfE[op] = make_uint2(be1, pkE1); }
    if (pv1 < CAPB_V8) pairV[(size_t)sv1 * CAPB_V8 + pv1] = pkV1;
    else { int op = atomicAdd(&bcur[OVCNT_V << 4], 1); if (op < OVF_CAP) ovfV[op] = make_uint2(bv1, pkV1); }
  }
}

// one block per bucket: rank via LDS atomics; pad each key list to multiple of P
// with `dummy` index (points at an always-zero row -> exact under mean)
__global__ __launch_bounds__(256) void expand(const uint32* __restrict__ pairs,
                                              const int* __restrict__ bcur, int subOff,
                                              int capb, const uint2* __restrict__ ovf,
                                              int ovfIdx, int* __restrict__ items, int cap,
                                              int* __restrict__ cnt, int nKeys,
                                              int P, int dummy) {
  __shared__ int lcnt[128];
  int b = blockIdx.x, t = threadIdx.x;
  if (t < 128) lcnt[t] = 0;
  __syncthreads();
  #pragma unroll
  for (int x = 0; x < 8; x++) {
    int c = subOff + b * 8 + x;
    int n = min(bcur[c << 4], capb);
    const uint32* p = pairs + (size_t)(b * 8 + x) * capb;
    for (int i = t; i < n; i += 256) {
      uint32 w = p[i];
      int loc = w >> 25;
      int val = (int)(w & 0x1FFFFFFu);
      int r = atomicAdd(&lcnt[loc], 1);
      if (r < cap) items[(size_t)((b << 7) + loc) * cap + r] = val;
    }
  }
  int novf = min(bcur[ovfIdx << 4], OVF_CAP);
  for (int i = t; i < novf; i += 256) {
    uint2 w = ovf[i];
    if ((int)w.x == b) {
      int loc = w.y >> 25;
      int val = (int)(w.y & 0x1FFFFFFu);
      int r = atomicAdd(&lcnt[loc], 1);
      if (r < cap) items[(size_t)((b << 7) + loc) * cap + r] = val;
    }
  }
  __syncthreads();
  if (t < 128) {
    int key = (b << 7) + t;
    if (key < nKeys) {
      int c = lcnt[t];
      cnt[key] = c;
      int cc = min(c, cap);
      int padded = min((cc + P - 1) & ~(P - 1), cap);
      for (int r = cc; r < padded; r++)
        items[(size_t)key * cap + r] = dummy;
    }
  }
}

// ---------------- weight prep ----------------
// WT: [0,16384) = W0T[n][k]; then 4x WeffT[i][n][k], Weff=(1-b)I+b*Ws[i]

__global__ void prep_weights(const float* __restrict__ W0, const float* __restrict__ Ws,
                             u16* __restrict__ WT) {
  int idx = blockIdx.x * blockDim.x + threadIdx.x;
  if (idx >= 5 * 16384) return;
  const float betas[4] = {0.4054651081f, 0.2231435513f, 0.1541506798f, 0.1177830357f};
  int sec = idx >> 14;
  int rc = idx & 16383;
  int n = rc >> 7, k = rc & 127;
  float v;
  if (sec == 0) {
    v = W0[k * 128 + n];
  } else {
    int i = sec - 1;
    float b = betas[i];
    v = b * Ws[i * 16384 + k * 128 + n];
    if (k == n) v += 1.0f - b;
  }
  WT[idx] = f2bf(v);
}

// ---------------- aggregations (bf16, 16 lanes/row, guard-free batches) ----------------

__global__ __launch_bounds__(256) void edge_agg(const u16* __restrict__ Xh,
                                                const int* __restrict__ cntE,
                                                const int* __restrict__ itemsE,
                                                u16* __restrict__ Xeh) {
  int g = threadIdx.x >> 4;
  int lane = threadIdx.x & 15;
  int e = blockIdx.x * 16 + g;
  int cnt = cntE[e];
  int n16 = (min(cnt, CAP_E) + 15) & ~15;
  const int* it = itemsE + (size_t)e * CAP_E;
  float acc[8] = {0.f, 0.f, 0.f, 0.f, 0.f, 0.f, 0.f, 0.f};
  for (int j = 0; j < n16; j += 16) {
    int4 i0 = *(const int4*)(it + j);
    int4 i1 = *(const int4*)(it + j + 4);
    int4 i2 = *(const int4*)(it + j + 8);
    int4 i3 = *(const int4*)(it + j + 12);
    u16x8 r0 = *(const u16x8*)(Xh + (size_t)i0.x * 128 + lane * 8);
    u16x8 r1 = *(const u16x8*)(Xh + (size_t)i0.y * 128 + lane * 8);
    u16x8 r2 = *(const u16x8*)(Xh + (size_t)i0.z * 128 + lane * 8);
    u16x8 r3 = *(const u16x8*)(Xh + (size_t)i0.w * 128 + lane * 8);
    u16x8 r4 = *(const u16x8*)(Xh + (size_t)i1.x * 128 + lane * 8);
    u16x8 r5 = *(const u16x8*)(Xh + (size_t)i1.y * 128 + lane * 8);
    u16x8 r6 = *(const u16x8*)(Xh + (size_t)i1.z * 128 + lane * 8);
    u16x8 r7 = *(const u16x8*)(Xh + (size_t)i1.w * 128 + lane * 8);
    u16x8 r8 = *(const u16x8*)(Xh + (size_t)i2.x * 128 + lane * 8);
    u16x8 r9 = *(const u16x8*)(Xh + (size_t)i2.y * 128 + lane * 8);
    u16x8 rA = *(const u16x8*)(Xh + (size_t)i2.z * 128 + lane * 8);
    u16x8 rB = *(const u16x8*)(Xh + (size_t)i2.w * 128 + lane * 8);
    u16x8 rC = *(const u16x8*)(Xh + (size_t)i3.x * 128 + lane * 8);
    u16x8 rD = *(const u16x8*)(Xh + (size_t)i3.y * 128 + lane * 8);
    u16x8 rE = *(const u16x8*)(Xh + (size_t)i3.z * 128 + lane * 8);
    u16x8 rF = *(const u16x8*)(Xh + (size_t)i3.w * 128 + lane * 8);
    #pragma unroll
    for (int q = 0; q < 8; q++) {
      float s0 = (bf2f(r0[q]) + bf2f(r1[q])) + (bf2f(r2[q]) + bf2f(r3[q]));
      float s1 = (bf2f(r4[q]) + bf2f(r5[q])) + (bf2f(r6[q]) + bf2f(r7[q]));
      float s2 = (bf2f(r8[q]) + bf2f(r9[q])) + (bf2f(rA[q]) + bf2f(rB[q]));
      float s3 = (bf2f(rC[q]) + bf2f(rD[q])) + (bf2f(rE[q]) + bf2f(rF[q]));
      acc[q] += (s0 + s1) + (s2 + s3);
    }
  }
  float inv = 1.f / fmaxf((float)cnt, 1.f);
  u16x8 o;
  #pragma unroll
  for (int q = 0; q < 8; q++) o[q] = f2bf(acc[q] * inv);
  *(u16x8*)(Xeh + (size_t)e * 128 + lane * 8) = o;
}

__global__ __launch_bounds__(256) void vertex_agg(const u16* __restrict__ Xeh,
                                                  const int* __restrict__ cntV,
                                                  const int* __restrict__ itemsV,
                                                  const u16* __restrict__ x0h,
                                                  u16* __restrict__ Xih) {
  int g = threadIdx.x >> 4;
  int lane = threadIdx.x & 15;
  int v = blockIdx.x * 16 + g;
  int cnt = cntV[v];
  int n8 = (min(cnt, CAP_V) + 7) & ~7;
  const int* it = itemsV + (size_t)v * CAP_V;
  float acc[8] = {0.f, 0.f, 0.f, 0.f, 0.f, 0.f, 0.f, 0.f};
  for (int j = 0; j < n8; j += 8) {
    int4 e0 = *(const int4*)(it + j);
    int4 e1 = *(const int4*)(it + j + 4);
    u16x8 r0 = *(const u16x8*)(Xeh + (size_t)e0.x * 128 + lane * 8);
    u16x8 r1 = *(const u16x8*)(Xeh + (size_t)e0.y * 128 + lane * 8);
    u16x8 r2 = *(const u16x8*)(Xeh + (size_t)e0.z * 128 + lane * 8);
    u16x8 r3 = *(const u16x8*)(Xeh + (size_t)e0.w * 128 + lane * 8);
    u16x8 r4 = *(const u16x8*)(Xeh + (size_t)e1.x * 128 + lane * 8);
    u16x8 r5 = *(const u16x8*)(Xeh + (size_t)e1.y * 128 + lane * 8);
    u16x8 r6 = *(const u16x8*)(Xeh + (size_t)e1.z * 128 + lane * 8);
    u16x8 r7 = *(const u16x8*)(Xeh + (size_t)e1.w * 128 + lane * 8);
    #pragma unroll
    for (int q = 0; q < 8; q++)
      acc[q] += ((bf2f(r0[q]) + bf2f(r1[q])) + (bf2f(r2[q]) + bf2f(r3[q]))) +
                ((bf2f(r4[q]) + bf2f(r5[q])) + (bf2f(r6[q]) + bf2f(r7[q])));
  }
  float inv = 1.f / fmaxf((float)cnt, 1.f);
  float sq = 0.f;
  #pragma unroll
  for (int q = 0; q < 8; q++) { acc[q] *= inv; sq += acc[q] * acc[q]; }
  sq += __shfl_xor(sq, 1, 64);
  sq += __shfl_xor(sq, 2, 64);
  sq += __shfl_xor(sq, 4, 64);
  sq += __shfl_xor(sq, 8, 64);
  float scale = (sq > 0.f) ? rsqrtf(sq) : 0.f;
  u16x8 x0v = *(const u16x8*)(x0h + (size_t)v * 128 + lane * 8);
  u16x8 o;
  #pragma unroll
  for (int q = 0; q < 8; q++)
    o[q] = f2bf(0.9f * acc[q] * scale + 0.1f * bf2f(x0v[q]));
  *(u16x8*)(Xih + (size_t)v * 128 + lane * 8) = o;
}

// ---------------- MFMA GEMM (32x32x16, 2x2 wave grid, 2x2 reg tile) ----------------
// A frag: row = lane&31, k = (lane>>5)*8 + j.  C/D: col = lane&31,
// row = (reg&3) + 8*(reg>>2) + 4*(lane>>5)  [m74/m101-verified]

__global__ __launch_bounds__(256) void gemm_mfma(const u16* __restrict__ Ah,
                                                 const u16* __restrict__ WT,
                                                 u16* __restrict__ Yh, int nrows) {
  __shared__ u16 As[128 * 136];
  __shared__ u16 Bs[128 * 136];
  int t = threadIdx.x;
  int row0 = blockIdx.x * 128;
  #pragma unroll
  for (int i = 0; i < 8; i++) {
    int idx = t + 256 * i;
    int r = idx >> 4, c8 = idx & 15;
    u16x8 v = {0, 0, 0, 0, 0, 0, 0, 0};
    if (row0 + r < nrows) v = *(const u16x8*)(Ah + (size_t)(row0 + r) * 128 + c8 * 8);
    *(u16x8*)&As[r * 136 + c8 * 8] = v;
    *(u16x8*)&Bs[r * 136 + c8 * 8] = *(const u16x8*)(WT + (size_t)r * 128 + c8 * 8);
  }
  __syncthreads();

  int w = t >> 6, lane = t & 63;
  int l31 = lane & 31, kh = lane >> 5;
  int wr = w >> 1, wc = w & 1;
  floatx16 acc[2][2];
  #pragma unroll
  for (int rt = 0; rt < 2; rt++)
    #pragma unroll
    for (int ct = 0; ct < 2; ct++)
      #pragma unroll
      for (int q = 0; q < 16; q++) acc[rt][ct][q] = 0.f;

  #pragma unroll
  for (int ks = 0; ks < 8; ks++) {
    int koff = ks * 16 + kh * 8;
    short8 a0 = *(const short8*)&As[(wr * 64 + l31) * 136 + koff];
    short8 a1 = *(const short8*)&As[(wr * 64 + 32 + l31) * 136 + koff];
    short8 b0 = *(const short8*)&Bs[(wc * 64 + l31) * 136 + koff];
    short8 b1 = *(const short8*)&Bs[(wc * 64 + 32 + l31) * 136 + koff];
    acc[0][0] = __builtin_amdgcn_mfma_f32_32x32x16_bf16(a0, b0, acc[0][0], 0, 0, 0);
    acc[0][1] = __builtin_amdgcn_mfma_f32_32x32x16_bf16(a0, b1, acc[0][1], 0, 0, 0);
    acc[1][0] = __builtin_amdgcn_mfma_f32_32x32x16_bf16(a1, b0, acc[1][0], 0, 0, 0);
    acc[1][1] = __builtin_amdgcn_mfma_f32_32x32x16_bf16(a1, b1, acc[1][1], 0, 0, 0);
  }
  __syncthreads();

  #pragma unroll
  for (int rt = 0; rt < 2; rt++)
    #pragma unroll
    for (int ct = 0; ct < 2; ct++) {
      int col = wc * 64 + ct * 32 + l31;
      #pragma unroll
      for (int reg = 0; reg < 16; reg++) {
        int row = wr * 64 + rt * 32 + (reg & 3) + 8 * (reg >> 2) + 4 * kh;
        As[row * 136 + col] = f2bf(fmaxf(acc[rt][ct][reg], 0.f));
      }
    }
  __syncthreads();
  #pragma unroll
  for (int i = 0; i < 8; i++) {
    int idx = t + 256 * i;
    int r = idx >> 4, c8 = idx & 15;
    if (row0 + r < nrows)
      *(u16x8*)(Yh + (size_t)(row0 + r) * 128 + c8 * 8) =
          *(const u16x8*)&As[r * 136 + c8 * 8];
  }
}

// first GEMM: fp32 A in, +bias, relu, dual bf16 outputs
__global__ __launch_bounds__(256) void gemm_first(const float* __restrict__ A,
                                                  const u16* __restrict__ WT,
                                                  const float* __restrict__ bias,
                                                  u16* __restrict__ Yh,
                                                  u16* __restrict__ Y2h, int nrows) {
  __shared__ u16 As[128 * 136];
  __shared__ u16 Bs[128 * 136];
  int t = threadIdx.x;
  int row0 = blockIdx.x * 128;
  #pragma unroll
  for (int i = 0; i < 8; i++) {
    int idx = t + 256 * i;
    int r = idx >> 4, c8 = idx & 15;
    u16x8 v = {0, 0, 0, 0, 0, 0, 0, 0};
    if (row0 + r < nrows) {
      const float* p = A + (size_t)(row0 + r) * 128 + c8 * 8;
      float4 a = *(const float4*)p;
      float4 b = *(const float4*)(p + 4);
      v[0] = f2bf(a.x); v[1] = f2bf(a.y); v[2] = f2bf(a.z); v[3] = f2bf(a.w);
      v[4] = f2bf(b.x); v[5] = f2bf(b.y); v[6] = f2bf(b.z); v[7] = f2bf(b.w);
    }
    *(u16x8*)&As[r * 136 + c8 * 8] = v;
    *(u16x8*)&Bs[r * 136 + c8 * 8] = *(const u16x8*)(WT + (size_t)r * 128 + c8 * 8);
  }
  __syncthreads();

  int w = t >> 6, lane = t & 63;
  int l31 = lane & 31, kh = lane >> 5;
  int wr = w >> 1, wc = w & 1;
  floatx16 acc[2][2];
  #pragma unroll
  for (int rt = 0; rt < 2; rt++)
    #pragma unroll
    for (int ct = 0; ct < 2; ct++)
      #pragma unroll
      for (int q = 0; q < 16; q++) acc[rt][ct][q] = 0.f;

  #pragma unroll
  for (int ks = 0; ks < 8; ks++) {
    int koff = ks * 16 + kh * 8;
    short8 a0 = *(const short8*)&As[(wr * 64 + l31) * 136 + koff];
    short8 a1 = *(const short8*)&As[(wr * 64 + 32 + l31) * 136 + koff];
    short8 b0 = *(const short8*)&Bs[(wc * 64 + l31) * 136 + koff];
    short8 b1 = *(const short8*)&Bs[(wc * 64 + 32 + l31) * 136 + koff];
    acc[0][0] = __builtin_amdgcn_mfma_f32_32x32x16_bf16(a0, b0, acc[0][0], 0, 0, 0);
    acc[0][1] = __builtin_amdgcn_mfma_f32_32x32x16_bf16(a0, b1, acc[0][1], 0, 0, 0);
    acc[1][0] = __builtin_amdgcn_mfma_f32_32x32x16_bf16(a1, b0, acc[1][0], 0, 0, 0);
    acc[1][1] = __builtin_amdgcn_mfma_f32_32x32x16_bf16(a1, b1, acc[1][1], 0, 0, 0);
  }
  __syncthreads();

  #pragma unroll
  for (int rt = 0; rt < 2; rt++)
    #pragma unroll
    for (int ct = 0; ct < 2; ct++) {
      int col = wc * 64 + ct * 32 + l31;
      float bv = bias[col];
      #pragma unroll
      for (int reg = 0; reg < 16; reg++) {
        int row = wr * 64 + rt * 32 + (reg & 3) + 8 * (reg >> 2) + 4 * kh;
        As[row * 136 + col] = f2bf(fmaxf(acc[rt][ct][reg] + bv, 0.f));
      }
    }
  __syncthreads();
  #pragma unroll
  for (int i = 0; i < 8; i++) {
    int idx = t + 256 * i;
    int r = idx >> 4, c8 = idx & 15;
    if (row0 + r < nrows) {
      u16x8 v = *(const u16x8*)&As[r * 136 + c8 * 8];
      *(u16x8*)(Yh + (size_t)(row0 + r) * 128 + c8 * 8) = v;
      *(u16x8*)(Y2h + (size_t)(row0 + r) * 128 + c8 * 8) = v;
    }
  }
}

// ---------------- output GEMM: out[nrows,40] = Xh @ Wout + bout ----------------

__global__ __launch_bounds__(256) void gemm_out(const u16* __restrict__ Xh,
                                                const float* __restrict__ W,
                                                const float* __restrict__ bias,
                                                float* __restrict__ Y, int nrows) {
  __shared__ float xs[128][36];
  __shared__ float ws[32][44];
  int t = threadIdx.x;
  int tr = t >> 3;
  int tc = t & 7;
  int row0 = blockIdx.x * 128;
  float acc[4][5];
  #pragma unroll
  for (int i = 0; i < 4; i++)
    #pragma unroll
    for (int j = 0; j < 5; j++) acc[i][j] = 0.f;

  for (int k0 = 0; k0 < 128; k0 += 32) {
    #pragma unroll
    for (int i = 0; i < 2; i++) {
      int idx = t + 256 * i;
      int r = idx >> 2, c8 = idx & 3;
      int gr = row0 + r;
      u16x8 v = {0, 0, 0, 0, 0, 0, 0, 0};
      if (gr < nrows) v = *(const u16x8*)(Xh + (size_t)gr * 128 + k0 + c8 * 8);
      #pragma unroll
      for (int q = 0; q < 8; q++) xs[r][c8 * 8 + q] = bf2f(v[q]);
    }
    #pragma unroll
    for (int i = 0; i < 5; i++) {
      int idx = t + 256 * i;
      int r = idx / 40, c = idx % 40;
      ws[r][c] = W[(k0 + r) * 40 + c];
    }
    __syncthreads();
    #pragma unroll
    for (int kk4 = 0; kk4 < 8; kk4++) {
      float4 xv[4];
      #pragma unroll
      for (int i = 0; i < 4; i++) xv[i] = *(const float4*)&xs[tr + 32 * i][kk4 * 4];
      #pragma unroll
      for (int q = 0; q < 4; q++) {
        int kk = kk4 * 4 + q;
        float wv[5];
        #pragma unroll
        for (int j = 0; j < 5; j++) wv[j] = ws[kk][tc * 5 + j];
        #pragma unroll
        for (int i = 0; i < 4; i++) {
          float xq = ((const float*)&xv[i])[q];
          #pragma unroll
          for (int j = 0; j < 5; j++) acc[i][j] += xq * wv[j];
        }
      }
    }
    __syncthreads();
  }
  #pragma unroll
  for (int i = 0; i < 4; i++) {
    int gr = row0 + tr + 32 * i;
    if (gr >= nrows) continue;
    #pragma unroll
    for (int j = 0; j < 5; j++) {
      int c = tc * 5 + j;
      Y[(long)gr * 40 + c] = acc[i][j] + bias[c];
    }
  }
}

// ---------------- launch ----------------

extern "C" void kernel_launch(void* const* d_in, const int* in_sizes, int n_in,
                              void* d_out, int out_size, void* d_ws, size_t ws_size,
                              hipStream_t stream) {
  const float* x    = (const float*)d_in[0];
  const float* W0   = (const float*)d_in[1];
  const float* b0   = (const float*)d_in[2];
  const float* Ws   = (const float*)d_in[3];
  const float* Wout = (const float*)d_in[4];
  const float* bout = (const float*)d_in[5];
  const int* vertex = (const int*)d_in[6];
  const int* edges  = (const int*)d_in[7];
  float* out = (float*)d_out;

  char* base = (char*)d_ws;
  size_t o = 0;
  auto alloc = [&](size_t bytes) -> char* {
    char* r = base + o;
    o += (bytes + 255) & ~(size_t)255;
    return r;
  };
  u16* x_curh = (u16*)alloc((size_t)(NV + 1) * 128 * 2);  // +1 dummy zero row
  u16* x0h    = (u16*)alloc((size_t)NV * 128 * 2);
  u16* Xeh    = (u16*)alloc((size_t)(NE + 1) * 128 * 2);  // +1 dummy zero row
  u16* WT     = (u16*)alloc((size_t)5 * 16384 * 2);
  int* cntE   = (int*)alloc((size_t)NE * 4);
  int* cntV   = (int*)alloc((size_t)NV * 4);
  int* itemsE = (int*)alloc((size_t)NE * CAP_E * 4);
  int* itemsV = (int*)alloc((size_t)NV * CAP_V * 4);
  uint32* pairE = (uint32*)alloc((size_t)NB_E * 8 * CAPB_E8 * 4);
  uint32* pairV = (uint32*)alloc((size_t)NB_V * 8 * CAPB_V8 * 4);
  uint2* ovfE  = (uint2*)alloc((size_t)OVF_CAP * 8);
  uint2* ovfV  = (uint2*)alloc((size_t)OVF_CAP * 8);
  int* bcur   = (int*)alloc((size_t)(NCUR + 2) * 16 * 4);

  int nb = (NCUR + 2) * 16;
  zero_misc<<<(nb + 255) / 256, 256, 0, stream>>>(bcur, nb,
                                                  x_curh + (size_t)NV * 128,
                                                  Xeh + (size_t)NE * 128);
  bucket_scatter<<<1024, 256, 0, stream>>>(vertex, edges, bcur, pairE, pairV, ovfE, ovfV);
  expand<<<NB_E, 256, 0, stream>>>(pairE, bcur, 0, CAPB_E8, ovfE, OVCNT_E,
                                   itemsE, CAP_E, cntE, NE, 16, NV);
  expand<<<NB_V, 256, 0, stream>>>(pairV, bcur, NB_E * 8, CAPB_V8, ovfV, OVCNT_V,
                                   itemsV, CAP_V, cntV, NV, 8, NE);
  prep_weights<<<(5 * 16384 + 255) / 256, 256, 0, stream>>>(W0, Ws, WT);

  int gblocks = (NV + 127) / 128;
  gemm_first<<<gblocks, 256, 0, stream>>>(x, WT, b0, x_curh, x0h, NV);

  for (int i = 0; i < 4; i++) {
    edge_agg<<<NE / 16, 256, 0, stream>>>(x_curh, cntE, itemsE, Xeh);
    vertex_agg<<<NV / 16, 256, 0, stream>>>(Xeh, cntV, itemsV, x0h, x_curh);
    gemm_mfma<<<gblocks, 256, 0, stream>>>(x_curh, WT + (size_t)(1 + i) * 16384,
                                           x_curh, NV);
  }
  gemm_out<<<gblocks, 256, 0, stream>>>(x_curh, Wout, bout, out, NV);
}

// Round 9
// 554.787 us; speedup vs baseline: 1.2648x; 1.0007x over previous
//
#include <hip/hip_runtime.h>

#define NV 100000
#define NE 50000
#define NNZ_C 800000
#define CAP_E 64        // slots per edge   (multiple of 16)
#define CAP_V 48        // slots per vertex (multiple of 8)
#define NB_E 391        // ceil(NE/128)
#define NB_V 782        // ceil(NV/128)
#define CAPB_E8 512     // per-XCD sub-stream cap
#define CAPB_V8 256
#define OVF_CAP 810000  // overflow covers worst case -> always correct
#define NCUR ((NB_E + NB_V) * 8)
#define OVCNT_E NCUR
#define OVCNT_V (NCUR + 1)

typedef unsigned int uint32;
typedef unsigned short u16;
typedef u16 u16x8 __attribute__((ext_vector_type(8)));
typedef short short8 __attribute__((ext_vector_type(8)));
typedef float floatx16 __attribute__((ext_vector_type(16)));

__device__ __forceinline__ float bf2f(u16 h) {
  return __uint_as_float(((uint32)h) << 16);
}
__device__ __forceinline__ u16 f2bf(float f) {
  uint32 u = __float_as_uint(f);
  u += 0x7FFF + ((u >> 16) & 1);   // RNE
  return (u16)(u >> 16);
}
__device__ __forceinline__ int xcc_id() {
  int x;
  asm("s_getreg_b32 %0, hwreg(HW_REG_XCC_ID)" : "=s"(x));
  return x & 7;
}
// XCD-local cursor bump: cursor is only ever touched from one XCD (we index by
// the hardware XCC_ID), so a workgroup-scope RMW -- which executes at the local
// L2, shared by all waves on this XCD -- is atomic for every accessor. Avoids
// the ~900-cyc cross-XCD coherence-point round-trip of device-scope atomicAdd.
__device__ __forceinline__ int l2_atomic_inc(int* p) {
  return __hip_atomic_fetch_add(p, 1, __ATOMIC_RELAXED, __HIP_MEMORY_SCOPE_WORKGROUP);
}

// ---------------- zero cursors + dummy gather rows ----------------

__global__ void zero_misc(int* __restrict__ bcur, int nb,
                          u16* __restrict__ dummyX, u16* __restrict__ dummyXe) {
  int i = blockIdx.x * blockDim.x + threadIdx.x;
  if (i < nb) bcur[i] = 0;
  if (i < 128) { dummyX[i] = 0; dummyXe[i] = 0; }
}

// ---------------- bucket scatter: XCD-local streams, L2-scope atomics ----------------

__global__ void bucket_scatter(const int* __restrict__ vertex, const int* __restrict__ edges,
                               int* __restrict__ bcur,
                               uint32* __restrict__ pairE, uint32* __restrict__ pairV,
                               uint2* __restrict__ ovfE, uint2* __restrict__ ovfV) {
  int xcd = xcc_id();
  int stride = gridDim.x * blockDim.x;
  const int half = NNZ_C / 2;
  for (int k = blockIdx.x * blockDim.x + threadIdx.x; k < half; k += stride) {
    uint32 e0 = (uint32)edges[k],        v0 = (uint32)vertex[k];
    uint32 e1 = (uint32)edges[k + half], v1 = (uint32)vertex[k + half];
    uint32 be0 = e0 >> 7, bv0 = v0 >> 7, be1 = e1 >> 7, bv1 = v1 >> 7;
    int se0 = (int)(be0 * 8) + xcd, sv0 = (int)(bv0 * 8) + xcd;
    int se1 = (int)(be1 * 8) + xcd, sv1 = (int)(bv1 * 8) + xcd;
    // 4 independent XCD-local atomic chains
    int pe0 = l2_atomic_inc(&bcur[se0 << 4]);
    int pv0 = l2_atomic_inc(&bcur[(NB_E * 8 + sv0) << 4]);
    int pe1 = l2_atomic_inc(&bcur[se1 << 4]);
    int pv1 = l2_atomic_inc(&bcur[(NB_E * 8 + sv1) << 4]);
    uint32 pkE0 = ((e0 & 127u) << 25) | v0, pkV0 = ((v0 & 127u) << 25) | e0;
    uint32 pkE1 = ((e1 & 127u) << 25) | v1, pkV1 = ((v1 & 127u) << 25) | e1;
    if (pe0 < CAPB_E8) pairE[(size_t)se0 * CAPB_E8 + pe0] = pkE0;
    else { int op = atomicAdd(&bcur[OVCNT_E << 4], 1); if (op < OVF_CAP) ovfE[op] = make_uint2(be0, pkE0); }
    if (pv0 < CAPB_V8) pairV[(size_t)sv0 * CAPB_V8 + pv0] = pkV0;
    else { int op = atomicAdd(&bcur[OVCNT_V << 4], 1); if (op < OVF_CAP) ovfV[op] = make_uint2(bv0, pkV0); }
    if (pe1 < CAPB_E8) pairE[(size_t)se1 * CAPB_E8 + pe1] = pkE1;
    else { int op = atomicAdd(&bcur[OVCNT_E << 4], 1); if (op < OVF_CAP) ovfE[op] = make_uint2(be1, pkE1); }
    if (pv1 < CAPB_V8) pairV[(size_t)sv1 * CAPB_V8 + pv1] = pkV1;
    else { int op = atomicAdd(&bcur[OVCNT_V << 4], 1); if (op < OVF_CAP) ovfV[op] = make_uint2(bv1, pkV1); }
  }
}

// one block per bucket: rank via LDS atomics; pad each key list to multiple of P
// with `dummy` index (points at an always-zero row -> exact under mean)
__global__ __launch_bounds__(256) void expand(const uint32* __restrict__ pairs,
                                              const int* __restrict__ bcur, int subOff,
                                              int capb, const uint2* __restrict__ ovf,
                                              int ovfIdx, int* __restrict__ items, int cap,
                                              int* __restrict__ cnt, int nKeys,
                                              int P, int dummy) {
  __shared__ int lcnt[128];
  int b = blockIdx.x, t = threadIdx.x;
  if (t < 128) lcnt[t] = 0;
  __syncthreads();
  #pragma unroll
  for (int x = 0; x < 8; x++) {
    int c = subOff + b * 8 + x;
    int n = min(bcur[c << 4], capb);
    const uint32* p = pairs + (size_t)(b * 8 + x) * capb;
    for (int i = t; i < n; i += 256) {
      uint32 w = p[i];
      int loc = w >> 25;
      int val = (int)(w & 0x1FFFFFFu);
      int r = atomicAdd(&lcnt[loc], 1);
      if (r < cap) items[(size_t)((b << 7) + loc) * cap + r] = val;
    }
  }
  int novf = min(bcur[ovfIdx << 4], OVF_CAP);
  for (int i = t; i < novf; i += 256) {
    uint2 w = ovf[i];
    if ((int)w.x == b) {
      int loc = w.y >> 25;
      int val = (int)(w.y & 0x1FFFFFFu);
      int r = atomicAdd(&lcnt[loc], 1);
      if (r < cap) items[(size_t)((b << 7) + loc) * cap + r] = val;
    }
  }
  __syncthreads();
  if (t < 128) {
    int key = (b << 7) + t;
    if (key < nKeys) {
      int c = lcnt[t];
      cnt[key] = c;
      int cc = min(c, cap);
      int padded = min((cc + P - 1) & ~(P - 1), cap);
      for (int r = cc; r < padded; r++)
        items[(size_t)key * cap + r] = dummy;
    }
  }
}

// ---------------- weight prep ----------------
// WT: [0,16384) = W0T[n][k]; then 4x WeffT[i][n][k], Weff=(1-b)I+b*Ws[i]

__global__ void prep_weights(const float* __restrict__ W0, const float* __restrict__ Ws,
                             u16* __restrict__ WT) {
  int idx = blockIdx.x * blockDim.x + threadIdx.x;
  if (idx >= 5 * 16384) return;
  const float betas[4] = {0.4054651081f, 0.2231435513f, 0.1541506798f, 0.1177830357f};
  int sec = idx >> 14;
  int rc = idx & 16383;
  int n = rc >> 7, k = rc & 127;
  float v;
  if (sec == 0) {
    v = W0[k * 128 + n];
  } else {
    int i = sec - 1;
    float b = betas[i];
    v = b * Ws[i * 16384 + k * 128 + n];
    if (k == n) v += 1.0f - b;
  }
  WT[idx] = f2bf(v);
}

// ---------------- aggregations (bf16, 16 lanes/row, guard-free batches) ----------------

__global__ __launch_bounds__(256) void edge_agg(const u16* __restrict__ Xh,
                                                const int* __restrict__ cntE,
                                                const int* __restrict__ itemsE,
                                                u16* __restrict__ Xeh) {
  int g = threadIdx.x >> 4;
  int lane = threadIdx.x & 15;
  int e = blockIdx.x * 16 + g;
  int cnt = cntE[e];
  int n16 = (min(cnt, CAP_E) + 15) & ~15;
  const int* it = itemsE + (size_t)e * CAP_E;
  float acc[8] = {0.f, 0.f, 0.f, 0.f, 0.f, 0.f, 0.f, 0.f};
  for (int j = 0; j < n16; j += 16) {
    int4 i0 = *(const int4*)(it + j);
    int4 i1 = *(const int4*)(it + j + 4);
    int4 i2 = *(const int4*)(it + j + 8);
    int4 i3 = *(const int4*)(it + j + 12);
    u16x8 r0 = *(const u16x8*)(Xh + (size_t)i0.x * 128 + lane * 8);
    u16x8 r1 = *(const u16x8*)(Xh + (size_t)i0.y * 128 + lane * 8);
    u16x8 r2 = *(const u16x8*)(Xh + (size_t)i0.z * 128 + lane * 8);
    u16x8 r3 = *(const u16x8*)(Xh + (size_t)i0.w * 128 + lane * 8);
    u16x8 r4 = *(const u16x8*)(Xh + (size_t)i1.x * 128 + lane * 8);
    u16x8 r5 = *(const u16x8*)(Xh + (size_t)i1.y * 128 + lane * 8);
    u16x8 r6 = *(const u16x8*)(Xh + (size_t)i1.z * 128 + lane * 8);
    u16x8 r7 = *(const u16x8*)(Xh + (size_t)i1.w * 128 + lane * 8);
    u16x8 r8 = *(const u16x8*)(Xh + (size_t)i2.x * 128 + lane * 8);
    u16x8 r9 = *(const u16x8*)(Xh + (size_t)i2.y * 128 + lane * 8);
    u16x8 rA = *(const u16x8*)(Xh + (size_t)i2.z * 128 + lane * 8);
    u16x8 rB = *(const u16x8*)(Xh + (size_t)i2.w * 128 + lane * 8);
    u16x8 rC = *(const u16x8*)(Xh + (size_t)i3.x * 128 + lane * 8);
    u16x8 rD = *(const u16x8*)(Xh + (size_t)i3.y * 128 + lane * 8);
    u16x8 rE = *(const u16x8*)(Xh + (size_t)i3.z * 128 + lane * 8);
    u16x8 rF = *(const u16x8*)(Xh + (size_t)i3.w * 128 + lane * 8);
    #pragma unroll
    for (int q = 0; q < 8; q++) {
      float s0 = (bf2f(r0[q]) + bf2f(r1[q])) + (bf2f(r2[q]) + bf2f(r3[q]));
      float s1 = (bf2f(r4[q]) + bf2f(r5[q])) + (bf2f(r6[q]) + bf2f(r7[q]));
      float s2 = (bf2f(r8[q]) + bf2f(r9[q])) + (bf2f(rA[q]) + bf2f(rB[q]));
      float s3 = (bf2f(rC[q]) + bf2f(rD[q])) + (bf2f(rE[q]) + bf2f(rF[q]));
      acc[q] += (s0 + s1) + (s2 + s3);
    }
  }
  float inv = 1.f / fmaxf((float)cnt, 1.f);
  u16x8 o;
  #pragma unroll
  for (int q = 0; q < 8; q++) o[q] = f2bf(acc[q] * inv);
  *(u16x8*)(Xeh + (size_t)e * 128 + lane * 8) = o;
}

__global__ __launch_bounds__(256) void vertex_agg(const u16* __restrict__ Xeh,
                                                  const int* __restrict__ cntV,
                                                  const int* __restrict__ itemsV,
                                                  const u16* __restrict__ x0h,
                                                  u16* __restrict__ Xih) {
  int g = threadIdx.x >> 4;
  int lane = threadIdx.x & 15;
  int v = blockIdx.x * 16 + g;
  int cnt = cntV[v];
  int n8 = (min(cnt, CAP_V) + 7) & ~7;
  const int* it = itemsV + (size_t)v * CAP_V;
  float acc[8] = {0.f, 0.f, 0.f, 0.f, 0.f, 0.f, 0.f, 0.f};
  for (int j = 0; j < n8; j += 8) {
    int4 e0 = *(const int4*)(it + j);
    int4 e1 = *(const int4*)(it + j + 4);
    u16x8 r0 = *(const u16x8*)(Xeh + (size_t)e0.x * 128 + lane * 8);
    u16x8 r1 = *(const u16x8*)(Xeh + (size_t)e0.y * 128 + lane * 8);
    u16x8 r2 = *(const u16x8*)(Xeh + (size_t)e0.z * 128 + lane * 8);
    u16x8 r3 = *(const u16x8*)(Xeh + (size_t)e0.w * 128 + lane * 8);
    u16x8 r4 = *(const u16x8*)(Xeh + (size_t)e1.x * 128 + lane * 8);
    u16x8 r5 = *(const u16x8*)(Xeh + (size_t)e1.y * 128 + lane * 8);
    u16x8 r6 = *(const u16x8*)(Xeh + (size_t)e1.z * 128 + lane * 8);
    u16x8 r7 = *(const u16x8*)(Xeh + (size_t)e1.w * 128 + lane * 8);
    #pragma unroll
    for (int q = 0; q < 8; q++)
      acc[q] += ((bf2f(r0[q]) + bf2f(r1[q])) + (bf2f(r2[q]) + bf2f(r3[q]))) +
                ((bf2f(r4[q]) + bf2f(r5[q])) + (bf2f(r6[q]) + bf2f(r7[q])));
  }
  float inv = 1.f / fmaxf((float)cnt, 1.f);
  float sq = 0.f;
  #pragma unroll
  for (int q = 0; q < 8; q++) { acc[q] *= inv; sq += acc[q] * acc[q]; }
  sq += __shfl_xor(sq, 1, 64);
  sq += __shfl_xor(sq, 2, 64);
  sq += __shfl_xor(sq, 4, 64);
  sq += __shfl_xor(sq, 8, 64);
  float scale = (sq > 0.f) ? rsqrtf(sq) : 0.f;
  u16x8 x0v = *(const u16x8*)(x0h + (size_t)v * 128 + lane * 8);
  u16x8 o;
  #pragma unroll
  for (int q = 0; q < 8; q++)
    o[q] = f2bf(0.9f * acc[q] * scale + 0.1f * bf2f(x0v[q]));
  *(u16x8*)(Xih + (size_t)v * 128 + lane * 8) = o;
}

// ---------------- MFMA GEMM (32x32x16, 2x2 wave grid, 2x2 reg tile) ----------------
// A frag: row = lane&31, k = (lane>>5)*8 + j.  C/D: col = lane&31,
// row = (reg&3) + 8*(reg>>2) + 4*(lane>>5)  [m74/m101-verified]

__global__ __launch_bounds__(256) void gemm_mfma(const u16* __restrict__ Ah,
                                                 const u16* __restrict__ WT,
                                                 u16* __restrict__ Yh, int nrows) {
  __shared__ u16 As[128 * 136];
  __shared__ u16 Bs[128 * 136];
  int t = threadIdx.x;
  int row0 = blockIdx.x * 128;
  #pragma unroll
  for (int i = 0; i < 8; i++) {
    int idx = t + 256 * i;
    int r = idx >> 4, c8 = idx & 15;
    u16x8 v = {0, 0, 0, 0, 0, 0, 0, 0};
    if (row0 + r < nrows) v = *(const u16x8*)(Ah + (size_t)(row0 + r) * 128 + c8 * 8);
    *(u16x8*)&As[r * 136 + c8 * 8] = v;
    *(u16x8*)&Bs[r * 136 + c8 * 8] = *(const u16x8*)(WT + (size_t)r * 128 + c8 * 8);
  }
  __syncthreads();

  int w = t >> 6, lane = t & 63;
  int l31 = lane & 31, kh = lane >> 5;
  int wr = w >> 1, wc = w & 1;
  floatx16 acc[2][2];
  #pragma unroll
  for (int rt = 0; rt < 2; rt++)
    #pragma unroll
    for (int ct = 0; ct < 2; ct++)
      #pragma unroll
      for (int q = 0; q < 16; q++) acc[rt][ct][q] = 0.f;

  #pragma unroll
  for (int ks = 0; ks < 8; ks++) {
    int koff = ks * 16 + kh * 8;
    short8 a0 = *(const short8*)&As[(wr * 64 + l31) * 136 + koff];
    short8 a1 = *(const short8*)&As[(wr * 64 + 32 + l31) * 136 + koff];
    short8 b0 = *(const short8*)&Bs[(wc * 64 + l31) * 136 + koff];
    short8 b1 = *(const short8*)&Bs[(wc * 64 + 32 + l31) * 136 + koff];
    acc[0][0] = __builtin_amdgcn_mfma_f32_32x32x16_bf16(a0, b0, acc[0][0], 0, 0, 0);
    acc[0][1] = __builtin_amdgcn_mfma_f32_32x32x16_bf16(a0, b1, acc[0][1], 0, 0, 0);
    acc[1][0] = __builtin_amdgcn_mfma_f32_32x32x16_bf16(a1, b0, acc[1][0], 0, 0, 0);
    acc[1][1] = __builtin_amdgcn_mfma_f32_32x32x16_bf16(a1, b1, acc[1][1], 0, 0, 0);
  }
  __syncthreads();

  #pragma unroll
  for (int rt = 0; rt < 2; rt++)
    #pragma unroll
    for (int ct = 0; ct < 2; ct++) {
      int col = wc * 64 + ct * 32 + l31;
      #pragma unroll
      for (int reg = 0; reg < 16; reg++) {
        int row = wr * 64 + rt * 32 + (reg & 3) + 8 * (reg >> 2) + 4 * kh;
        As[row * 136 + col] = f2bf(fmaxf(acc[rt][ct][reg], 0.f));
      }
    }
  __syncthreads();
  #pragma unroll
  for (int i = 0; i < 8; i++) {
    int idx = t + 256 * i;
    int r = idx >> 4, c8 = idx & 15;
    if (row0 + r < nrows)
      *(u16x8*)(Yh + (size_t)(row0 + r) * 128 + c8 * 8) =
          *(const u16x8*)&As[r * 136 + c8 * 8];
  }
}

// first GEMM: fp32 A in, +bias, relu, dual bf16 outputs
__global__ __launch_bounds__(256) void gemm_first(const float* __restrict__ A,
                                                  const u16* __restrict__ WT,
                                                  const float* __restrict__ bias,
                                                  u16* __restrict__ Yh,
                                                  u16* __restrict__ Y2h, int nrows) {
  __shared__ u16 As[128 * 136];
  __shared__ u16 Bs[128 * 136];
  int t = threadIdx.x;
  int row0 = blockIdx.x * 128;
  #pragma unroll
  for (int i = 0; i < 8; i++) {
    int idx = t + 256 * i;
    int r = idx >> 4, c8 = idx & 15;
    u16x8 v = {0, 0, 0, 0, 0, 0, 0, 0};
    if (row0 + r < nrows) {
      const float* p = A + (size_t)(row0 + r) * 128 + c8 * 8;
      float4 a = *(const float4*)p;
      float4 b = *(const float4*)(p + 4);
      v[0] = f2bf(a.x); v[1] = f2bf(a.y); v[2] = f2bf(a.z); v[3] = f2bf(a.w);
      v[4] = f2bf(b.x); v[5] = f2bf(b.y); v[6] = f2bf(b.z); v[7] = f2bf(b.w);
    }
    *(u16x8*)&As[r * 136 + c8 * 8] = v;
    *(u16x8*)&Bs[r * 136 + c8 * 8] = *(const u16x8*)(WT + (size_t)r * 128 + c8 * 8);
  }
  __syncthreads();

  int w = t >> 6, lane = t & 63;
  int l31 = lane & 31, kh = lane >> 5;
  int wr = w >> 1, wc = w & 1;
  floatx16 acc[2][2];
  #pragma unroll
  for (int rt = 0; rt < 2; rt++)
    #pragma unroll
    for (int ct = 0; ct < 2; ct++)
      #pragma unroll
      for (int q = 0; q < 16; q++) acc[rt][ct][q] = 0.f;

  #pragma unroll
  for (int ks = 0; ks < 8; ks++) {
    int koff = ks * 16 + kh * 8;
    short8 a0 = *(const short8*)&As[(wr * 64 + l31) * 136 + koff];
    short8 a1 = *(const short8*)&As[(wr * 64 + 32 + l31) * 136 + koff];
    short8 b0 = *(const short8*)&Bs[(wc * 64 + l31) * 136 + koff];
    short8 b1 = *(const short8*)&Bs[(wc * 64 + 32 + l31) * 136 + koff];
    acc[0][0] = __builtin_amdgcn_mfma_f32_32x32x16_bf16(a0, b0, acc[0][0], 0, 0, 0);
    acc[0][1] = __builtin_amdgcn_mfma_f32_32x32x16_bf16(a0, b1, acc[0][1], 0, 0, 0);
    acc[1][0] = __builtin_amdgcn_mfma_f32_32x32x16_bf16(a1, b0, acc[1][0], 0, 0, 0);
    acc[1][1] = __builtin_amdgcn_mfma_f32_32x32x16_bf16(a1, b1, acc[1][1], 0, 0, 0);
  }
  __syncthreads();

  #pragma unroll
  for (int rt = 0; rt < 2; rt++)
    #pragma unroll
    for (int ct = 0; ct < 2; ct++) {
      int col = wc * 64 + ct * 32 + l31;
      float bv = bias[col];
      #pragma unroll
      for (int reg = 0; reg < 16; reg++) {
        int row = wr * 64 + rt * 32 + (reg & 3) + 8 * (reg >> 2) + 4 * kh;
        As[row * 136 + col] = f2bf(fmaxf(acc[rt][ct][reg] + bv, 0.f));
      }
    }
  __syncthreads();
  #pragma unroll
  for (int i = 0; i < 8; i++) {
    int idx = t + 256 * i;
    int r = idx >> 4, c8 = idx & 15;
    if (row0 + r < nrows) {
      u16x8 v = *(const u16x8*)&As[r * 136 + c8 * 8];
      *(u16x8*)(Yh + (size_t)(row0 + r) * 128 + c8 * 8) = v;
      *(u16x8*)(Y2h + (size_t)(row0 + r) * 128 + c8 * 8) = v;
    }
  }
}

// ---------------- output GEMM: out[nrows,40] = Xh @ Wout + bout ----------------

__global__ __launch_bounds__(256) void gemm_out(const u16* __restrict__ Xh,
                                                const float* __restrict__ W,
                                                const float* __restrict__ bias,
                                                float* __restrict__ Y, int nrows) {
  __shared__ float xs[128][36];
  __shared__ float ws[32][44];
  int t = threadIdx.x;
  int tr = t >> 3;
  int tc = t & 7;
  int row0 = blockIdx.x * 128;
  float acc[4][5];
  #pragma unroll
  for (int i = 0; i < 4; i++)
    #pragma unroll
    for (int j = 0; j < 5; j++) acc[i][j] = 0.f;

  for (int k0 = 0; k0 < 128; k0 += 32) {
    #pragma unroll
    for (int i = 0; i < 2; i++) {
      int idx = t + 256 * i;
      int r = idx >> 2, c8 = idx & 3;
      int gr = row0 + r;
      u16x8 v = {0, 0, 0, 0, 0, 0, 0, 0};
      if (gr < nrows) v = *(const u16x8*)(Xh + (size_t)gr * 128 + k0 + c8 * 8);
      #pragma unroll
      for (int q = 0; q < 8; q++) xs[r][c8 * 8 + q] = bf2f(v[q]);
    }
    #pragma unroll
    for (int i = 0; i < 5; i++) {
      int idx = t + 256 * i;
      int r = idx / 40, c = idx % 40;
      ws[r][c] = W[(k0 + r) * 40 + c];
    }
    __syncthreads();
    #pragma unroll
    for (int kk4 = 0; kk4 < 8; kk4++) {
      float4 xv[4];
      #pragma unroll
      for (int i = 0; i < 4; i++) xv[i] = *(const float4*)&xs[tr + 32 * i][kk4 * 4];
      #pragma unroll
      for (int q = 0; q < 4; q++) {
        int kk = kk4 * 4 + q;
        float wv[5];
        #pragma unroll
        for (int j = 0; j < 5; j++) wv[j] = ws[kk][tc * 5 + j];
        #pragma unroll
        for (int i = 0; i < 4; i++) {
          float xq = ((const float*)&xv[i])[q];
          #pragma unroll
          for (int j = 0; j < 5; j++) acc[i][j] += xq * wv[j];
        }
      }
    }
    __syncthreads();
  }
  #pragma unroll
  for (int i = 0; i < 4; i++) {
    int gr = row0 + tr + 32 * i;
    if (gr >= nrows) continue;
    #pragma unroll
    for (int j = 0; j < 5; j++) {
      int c = tc * 5 + j;
      Y[(long)gr * 40 + c] = acc[i][j] + bias[c];
    }
  }
}

// ---------------- launch ----------------

extern "C" void kernel_launch(void* const* d_in, const int* in_sizes, int n_in,
                              void* d_out, int out_size, void* d_ws, size_t ws_size,
                              hipStream_t stream) {
  const float* x    = (const float*)d_in[0];
  const float* W0   = (const float*)d_in[1];
  const float* b0   = (const float*)d_in[2];
  const float* Ws   = (const float*)d_in[3];
  const float* Wout = (const float*)d_in[4];
  const float* bout = (const float*)d_in[5];
  const int* vertex = (const int*)d_in[6];
  const int* edges  = (const int*)d_in[7];
  float* out = (float*)d_out;

  char* base = (char*)d_ws;
  size_t o = 0;
  auto alloc = [&](size_t bytes) -> char* {
    char* r = base + o;
    o += (bytes + 255) & ~(size_t)255;
    return r;
  };
  u16* x_curh = (u16*)alloc((size_t)(NV + 1) * 128 * 2);  // +1 dummy zero row
  u16* x0h    = (u16*)alloc((size_t)NV * 128 * 2);
  u16* Xeh    = (u16*)alloc((size_t)(NE + 1) * 128 * 2);  // +1 dummy zero row
  u16* WT     = (u16*)alloc((size_t)5 * 16384 * 2);
  int* cntE   = (int*)alloc((size_t)NE * 4);
  int* cntV   = (int*)alloc((size_t)NV * 4);
  int* itemsE = (int*)alloc((size_t)NE * CAP_E * 4);
  int* itemsV = (int*)alloc((size_t)NV * CAP_V * 4);
  uint32* pairE = (uint32*)alloc((size_t)NB_E * 8 * CAPB_E8 * 4);
  uint32* pairV = (uint32*)alloc((size_t)NB_V * 8 * CAPB_V8 * 4);
  uint2* ovfE  = (uint2*)alloc((size_t)OVF_CAP * 8);
  uint2* ovfV  = (uint2*)alloc((size_t)OVF_CAP * 8);
  int* bcur   = (int*)alloc((size_t)(NCUR + 2) * 16 * 4);

  int nb = (NCUR + 2) * 16;
  zero_misc<<<(nb + 255) / 256, 256, 0, stream>>>(bcur, nb,
                                                  x_curh + (size_t)NV * 128,
                                                  Xeh + (size_t)NE * 128);
  bucket_scatter<<<1024, 256, 0, stream>>>(vertex, edges, bcur, pairE, pairV, ovfE, ovfV);
  expand<<<NB_E, 256, 0, stream>>>(pairE, bcur, 0, CAPB_E8, ovfE, OVCNT_E,
                                   itemsE, CAP_E, cntE, NE, 16, NV);
  expand<<<NB_V, 256, 0, stream>>>(pairV, bcur, NB_E * 8, CAPB_V8, ovfV, OVCNT_V,
                                   itemsV, CAP_V, cntV, NV, 8, NE);
  prep_weights<<<(5 * 16384 + 255) / 256, 256, 0, stream>>>(W0, Ws, WT);

  int gblocks = (NV + 127) / 128;
  gemm_first<<<gblocks, 256, 0, stream>>>(x, WT, b0, x_curh, x0h, NV);

  for (int i = 0; i < 4; i++) {
    edge_agg<<<NE / 16, 256, 0, stream>>>(x_curh, cntE, itemsE, Xeh);
    vertex_agg<<<NV / 16, 256, 0, stream>>>(Xeh, cntV, itemsV, x0h, x_curh);
    gemm_mfma<<<gblocks, 256, 0, stream>>>(x_curh, WT + (size_t)(1 + i) * 16384,
                                           x_curh, NV);
  }
  gemm_out<<<gblocks, 256, 0, stream>>>(x_curh, Wout, bout, out, NV);
}

// Round 10
// 503.362 us; speedup vs baseline: 1.3940x; 1.1022x over previous
//
#include <hip/hip_runtime.h>

#define NV 100000
#define NE 50000
#define NNZ_C 800000
#define CAP_E 64        // slots per edge   (multiple of 16)
#define CAP_V 48        // slots per vertex (multiple of 8)
#define NB_E 391        // ceil(NE/128)
#define NB_V 782        // ceil(NV/128)
#define CAPB_E 2560     // per-bucket stream cap (Poisson 2048, +11 sigma)
#define CAPB_V 1408     // per-bucket stream cap (Poisson 1024, +12 sigma)
#define OVF_CAP 810000  // overflow covers worst case -> always correct
#define T_ITEMS 4096
#define N_TILES ((NNZ_C + T_ITEMS - 1) / T_ITEMS)   // 196

typedef unsigned int uint32;
typedef unsigned short u16;
typedef u16 u16x8 __attribute__((ext_vector_type(8)));
typedef short short8 __attribute__((ext_vector_type(8)));
typedef float floatx16 __attribute__((ext_vector_type(16)));

__device__ __forceinline__ float bf2f(u16 h) {
  return __uint_as_float(((uint32)h) << 16);
}
__device__ __forceinline__ u16 f2bf(float f) {
  uint32 u = __float_as_uint(f);
  u += 0x7FFF + ((u >> 16) & 1);   // RNE
  return (u16)(u >> 16);
}

// ---------------- zero cursors + dummy gather rows ----------------

__global__ void zero_misc(int* __restrict__ cur, int n,
                          u16* __restrict__ dummyX, u16* __restrict__ dummyXe) {
  int i = blockIdx.x * blockDim.x + threadIdx.x;
  if (i < n) cur[i] = 0;
  if (i < 128) { dummyX[i] = 0; dummyXe[i] = 0; }
}

// ---------------- LDS-binned scatter: tile histogram -> 1 global atomic ----------------
// per touched bucket per tile (~230K global atomics vs 1.6M per-item), stores
// become dense runs so L2 assembles full lines.

__global__ __launch_bounds__(256) void scatter_binned(const int* __restrict__ vertex,
                                                      const int* __restrict__ edges,
                                                      int* __restrict__ curE,
                                                      int* __restrict__ curV,
                                                      int* __restrict__ ovfCnt,
                                                      uint32* __restrict__ pairE,
                                                      uint32* __restrict__ pairV,
                                                      uint2* __restrict__ ovfE,
                                                      uint2* __restrict__ ovfV) {
  __shared__ int histE[NB_E], baseE[NB_E];
  __shared__ int histV[NB_V], baseV[NB_V];
  int t = threadIdx.x;
  for (int tile = blockIdx.x; tile < N_TILES; tile += gridDim.x) {
    for (int b = t; b < NB_E; b += 256) histE[b] = 0;
    for (int b = t; b < NB_V; b += 256) histV[b] = 0;
    __syncthreads();
    int base = tile * T_ITEMS;
    int ev[16], vv[16], rE[16], rV[16];
    #pragma unroll
    for (int i = 0; i < 16; i++) {
      int k = base + t + i * 256;
      if (k < NNZ_C) {
        ev[i] = edges[k];
        vv[i] = vertex[k];
        rE[i] = atomicAdd(&histE[ev[i] >> 7], 1);
        rV[i] = atomicAdd(&histV[vv[i] >> 7], 1);
      }
    }
    __syncthreads();
    for (int b = t; b < NB_E; b += 256) {
      int h = histE[b];
      baseE[b] = h ? atomicAdd(&curE[b], h) : 0;
    }
    for (int b = t; b < NB_V; b += 256) {
      int h = histV[b];
      baseV[b] = h ? atomicAdd(&curV[b], h) : 0;
    }
    __syncthreads();
    #pragma unroll
    for (int i = 0; i < 16; i++) {
      int k = base + t + i * 256;
      if (k < NNZ_C) {
        uint32 e = (uint32)ev[i], v = (uint32)vv[i];
        uint32 pkE = ((e & 127u) << 25) | v;
        uint32 pkV = ((v & 127u) << 25) | e;
        int pE = baseE[e >> 7] + rE[i];
        if (pE < CAPB_E) pairE[(size_t)(e >> 7) * CAPB_E + pE] = pkE;
        else { int op = atomicAdd(&ovfCnt[0], 1); if (op < OVF_CAP) ovfE[op] = make_uint2(e >> 7, pkE); }
        int pV = baseV[v >> 7] + rV[i];
        if (pV < CAPB_V) pairV[(size_t)(v >> 7) * CAPB_V + pV] = pkV;
        else { int op = atomicAdd(&ovfCnt[1], 1); if (op < OVF_CAP) ovfV[op] = make_uint2(v >> 7, pkV); }
      }
    }
    __syncthreads();
  }
}

// one block per bucket: rank via LDS atomics; pad each key list to multiple of P
// with `dummy` index (points at an always-zero row -> exact under mean)
__global__ __launch_bounds__(256) void expand(const uint32* __restrict__ pairs,
                                              const int* __restrict__ cur, int capb,
                                              const uint2* __restrict__ ovf,
                                              const int* __restrict__ ovfCnt,
                                              int* __restrict__ items, int cap,
                                              int* __restrict__ cnt, int nKeys,
                                              int P, int dummy) {
  __shared__ int lcnt[128];
  int b = blockIdx.x, t = threadIdx.x;
  if (t < 128) lcnt[t] = 0;
  __syncthreads();
  int n = min(cur[b], capb);
  const uint32* p = pairs + (size_t)b * capb;
  for (int i = t; i < n; i += 256) {
    uint32 w = p[i];
    int loc = w >> 25;
    int val = (int)(w & 0x1FFFFFFu);
    int r = atomicAdd(&lcnt[loc], 1);
    if (r < cap) items[(size_t)((b << 7) + loc) * cap + r] = val;
  }
  int novf = min(*ovfCnt, OVF_CAP);
  for (int i = t; i < novf; i += 256) {
    uint2 w = ovf[i];
    if ((int)w.x == b) {
      int loc = w.y >> 25;
      int val = (int)(w.y & 0x1FFFFFFu);
      int r = atomicAdd(&lcnt[loc], 1);
      if (r < cap) items[(size_t)((b << 7) + loc) * cap + r] = val;
    }
  }
  __syncthreads();
  if (t < 128) {
    int key = (b << 7) + t;
    if (key < nKeys) {
      int c = lcnt[t];
      cnt[key] = c;
      int cc = min(c, cap);
      int padded = min((cc + P - 1) & ~(P - 1), cap);
      for (int r = cc; r < padded; r++)
        items[(size_t)key * cap + r] = dummy;
    }
  }
}

// ---------------- weight prep ----------------
// WT: [0,16384) = W0T[n][k]; then 4x WeffT[i][n][k], Weff=(1-b)I+b*Ws[i]

__global__ void prep_weights(const float* __restrict__ W0, const float* __restrict__ Ws,
                             u16* __restrict__ WT) {
  int idx = blockIdx.x * blockDim.x + threadIdx.x;
  if (idx >= 5 * 16384) return;
  const float betas[4] = {0.4054651081f, 0.2231435513f, 0.1541506798f, 0.1177830357f};
  int sec = idx >> 14;
  int rc = idx & 16383;
  int n = rc >> 7, k = rc & 127;
  float v;
  if (sec == 0) {
    v = W0[k * 128 + n];
  } else {
    int i = sec - 1;
    float b = betas[i];
    v = b * Ws[i * 16384 + k * 128 + n];
    if (k == n) v += 1.0f - b;
  }
  WT[idx] = f2bf(v);
}

// ---------------- aggregations (bf16, 16 lanes/row, guard-free batches) ----------------

__global__ __launch_bounds__(256) void edge_agg(const u16* __restrict__ Xh,
                                                const int* __restrict__ cntE,
                                                const int* __restrict__ itemsE,
                                                u16* __restrict__ Xeh) {
  int g = threadIdx.x >> 4;
  int lane = threadIdx.x & 15;
  int e = blockIdx.x * 16 + g;
  int cnt = cntE[e];
  int n16 = (min(cnt, CAP_E) + 15) & ~15;
  const int* it = itemsE + (size_t)e * CAP_E;
  float acc[8] = {0.f, 0.f, 0.f, 0.f, 0.f, 0.f, 0.f, 0.f};
  for (int j = 0; j < n16; j += 16) {
    int4 i0 = *(const int4*)(it + j);
    int4 i1 = *(const int4*)(it + j + 4);
    int4 i2 = *(const int4*)(it + j + 8);
    int4 i3 = *(const int4*)(it + j + 12);
    u16x8 r0 = *(const u16x8*)(Xh + (size_t)i0.x * 128 + lane * 8);
    u16x8 r1 = *(const u16x8*)(Xh + (size_t)i0.y * 128 + lane * 8);
    u16x8 r2 = *(const u16x8*)(Xh + (size_t)i0.z * 128 + lane * 8);
    u16x8 r3 = *(const u16x8*)(Xh + (size_t)i0.w * 128 + lane * 8);
    u16x8 r4 = *(const u16x8*)(Xh + (size_t)i1.x * 128 + lane * 8);
    u16x8 r5 = *(const u16x8*)(Xh + (size_t)i1.y * 128 + lane * 8);
    u16x8 r6 = *(const u16x8*)(Xh + (size_t)i1.z * 128 + lane * 8);
    u16x8 r7 = *(const u16x8*)(Xh + (size_t)i1.w * 128 + lane * 8);
    u16x8 r8 = *(const u16x8*)(Xh + (size_t)i2.x * 128 + lane * 8);
    u16x8 r9 = *(const u16x8*)(Xh + (size_t)i2.y * 128 + lane * 8);
    u16x8 rA = *(const u16x8*)(Xh + (size_t)i2.z * 128 + lane * 8);
    u16x8 rB = *(const u16x8*)(Xh + (size_t)i2.w * 128 + lane * 8);
    u16x8 rC = *(const u16x8*)(Xh + (size_t)i3.x * 128 + lane * 8);
    u16x8 rD = *(const u16x8*)(Xh + (size_t)i3.y * 128 + lane * 8);
    u16x8 rE = *(const u16x8*)(Xh + (size_t)i3.z * 128 + lane * 8);
    u16x8 rF = *(const u16x8*)(Xh + (size_t)i3.w * 128 + lane * 8);
    #pragma unroll
    for (int q = 0; q < 8; q++) {
      float s0 = (bf2f(r0[q]) + bf2f(r1[q])) + (bf2f(r2[q]) + bf2f(r3[q]));
      float s1 = (bf2f(r4[q]) + bf2f(r5[q])) + (bf2f(r6[q]) + bf2f(r7[q]));
      float s2 = (bf2f(r8[q]) + bf2f(r9[q])) + (bf2f(rA[q]) + bf2f(rB[q]));
      float s3 = (bf2f(rC[q]) + bf2f(rD[q])) + (bf2f(rE[q]) + bf2f(rF[q]));
      acc[q] += (s0 + s1) + (s2 + s3);
    }
  }
  float inv = 1.f / fmaxf((float)cnt, 1.f);
  u16x8 o;
  #pragma unroll
  for (int q = 0; q < 8; q++) o[q] = f2bf(acc[q] * inv);
  *(u16x8*)(Xeh + (size_t)e * 128 + lane * 8) = o;
}

__global__ __launch_bounds__(256) void vertex_agg(const u16* __restrict__ Xeh,
                                                  const int* __restrict__ cntV,
                                                  const int* __restrict__ itemsV,
                                                  const u16* __restrict__ x0h,
                                                  u16* __restrict__ Xih) {
  int g = threadIdx.x >> 4;
  int lane = threadIdx.x & 15;
  int v = blockIdx.x * 16 + g;
  int cnt = cntV[v];
  int n8 = (min(cnt, CAP_V) + 7) & ~7;
  const int* it = itemsV + (size_t)v * CAP_V;
  float acc[8] = {0.f, 0.f, 0.f, 0.f, 0.f, 0.f, 0.f, 0.f};
  for (int j = 0; j < n8; j += 8) {
    int4 e0 = *(const int4*)(it + j);
    int4 e1 = *(const int4*)(it + j + 4);
    u16x8 r0 = *(const u16x8*)(Xeh + (size_t)e0.x * 128 + lane * 8);
    u16x8 r1 = *(const u16x8*)(Xeh + (size_t)e0.y * 128 + lane * 8);
    u16x8 r2 = *(const u16x8*)(Xeh + (size_t)e0.z * 128 + lane * 8);
    u16x8 r3 = *(const u16x8*)(Xeh + (size_t)e0.w * 128 + lane * 8);
    u16x8 r4 = *(const u16x8*)(Xeh + (size_t)e1.x * 128 + lane * 8);
    u16x8 r5 = *(const u16x8*)(Xeh + (size_t)e1.y * 128 + lane * 8);
    u16x8 r6 = *(const u16x8*)(Xeh + (size_t)e1.z * 128 + lane * 8);
    u16x8 r7 = *(const u16x8*)(Xeh + (size_t)e1.w * 128 + lane * 8);
    #pragma unroll
    for (int q = 0; q < 8; q++)
      acc[q] += ((bf2f(r0[q]) + bf2f(r1[q])) + (bf2f(r2[q]) + bf2f(r3[q]))) +
                ((bf2f(r4[q]) + bf2f(r5[q])) + (bf2f(r6[q]) + bf2f(r7[q])));
  }
  float inv = 1.f / fmaxf((float)cnt, 1.f);
  float sq = 0.f;
  #pragma unroll
  for (int q = 0; q < 8; q++) { acc[q] *= inv; sq += acc[q] * acc[q]; }
  sq += __shfl_xor(sq, 1, 64);
  sq += __shfl_xor(sq, 2, 64);
  sq += __shfl_xor(sq, 4, 64);
  sq += __shfl_xor(sq, 8, 64);
  float scale = (sq > 0.f) ? rsqrtf(sq) : 0.f;
  u16x8 x0v = *(const u16x8*)(x0h + (size_t)v * 128 + lane * 8);
  u16x8 o;
  #pragma unroll
  for (int q = 0; q < 8; q++)
    o[q] = f2bf(0.9f * acc[q] * scale + 0.1f * bf2f(x0v[q]));
  *(u16x8*)(Xih + (size_t)v * 128 + lane * 8) = o;
}

// ---------------- MFMA GEMM (32x32x16, 2x2 wave grid, 2x2 reg tile) ----------------
// A frag: row = lane&31, k = (lane>>5)*8 + j.  C/D: col = lane&31,
// row = (reg&3) + 8*(reg>>2) + 4*(lane>>5)  [m74/m101-verified]

__global__ __launch_bounds__(256) void gemm_mfma(const u16* __restrict__ Ah,
                                                 const u16* __restrict__ WT,
                                                 u16* __restrict__ Yh, int nrows) {
  __shared__ u16 As[128 * 136];
  __shared__ u16 Bs[128 * 136];
  int t = threadIdx.x;
  int row0 = blockIdx.x * 128;
  #pragma unroll
  for (int i = 0; i < 8; i++) {
    int idx = t + 256 * i;
    int r = idx >> 4, c8 = idx & 15;
    u16x8 v = {0, 0, 0, 0, 0, 0, 0, 0};
    if (row0 + r < nrows) v = *(const u16x8*)(Ah + (size_t)(row0 + r) * 128 + c8 * 8);
    *(u16x8*)&As[r * 136 + c8 * 8] = v;
    *(u16x8*)&Bs[r * 136 + c8 * 8] = *(const u16x8*)(WT + (size_t)r * 128 + c8 * 8);
  }
  __syncthreads();

  int w = t >> 6, lane = t & 63;
  int l31 = lane & 31, kh = lane >> 5;
  int wr = w >> 1, wc = w & 1;
  floatx16 acc[2][2];
  #pragma unroll
  for (int rt = 0; rt < 2; rt++)
    #pragma unroll
    for (int ct = 0; ct < 2; ct++)
      #pragma unroll
      for (int q = 0; q < 16; q++) acc[rt][ct][q] = 0.f;

  #pragma unroll
  for (int ks = 0; ks < 8; ks++) {
    int koff = ks * 16 + kh * 8;
    short8 a0 = *(const short8*)&As[(wr * 64 + l31) * 136 + koff];
    short8 a1 = *(const short8*)&As[(wr * 64 + 32 + l31) * 136 + koff];
    short8 b0 = *(const short8*)&Bs[(wc * 64 + l31) * 136 + koff];
    short8 b1 = *(const short8*)&Bs[(wc * 64 + 32 + l31) * 136 + koff];
    acc[0][0] = __builtin_amdgcn_mfma_f32_32x32x16_bf16(a0, b0, acc[0][0], 0, 0, 0);
    acc[0][1] = __builtin_amdgcn_mfma_f32_32x32x16_bf16(a0, b1, acc[0][1], 0, 0, 0);
    acc[1][0] = __builtin_amdgcn_mfma_f32_32x32x16_bf16(a1, b0, acc[1][0], 0, 0, 0);
    acc[1][1] = __builtin_amdgcn_mfma_f32_32x32x16_bf16(a1, b1, acc[1][1], 0, 0, 0);
  }
  __syncthreads();

  #pragma unroll
  for (int rt = 0; rt < 2; rt++)
    #pragma unroll
    for (int ct = 0; ct < 2; ct++) {
      int col = wc * 64 + ct * 32 + l31;
      #pragma unroll
      for (int reg = 0; reg < 16; reg++) {
        int row = wr * 64 + rt * 32 + (reg & 3) + 8 * (reg >> 2) + 4 * kh;
        As[row * 136 + col] = f2bf(fmaxf(acc[rt][ct][reg], 0.f));
      }
    }
  __syncthreads();
  #pragma unroll
  for (int i = 0; i < 8; i++) {
    int idx = t + 256 * i;
    int r = idx >> 4, c8 = idx & 15;
    if (row0 + r < nrows)
      *(u16x8*)(Yh + (size_t)(row0 + r) * 128 + c8 * 8) =
          *(const u16x8*)&As[r * 136 + c8 * 8];
  }
}

// first GEMM: fp32 A in, +bias, relu, dual bf16 outputs
__global__ __launch_bounds__(256) void gemm_first(const float* __restrict__ A,
                                                  const u16* __restrict__ WT,
                                                  const float* __restrict__ bias,
                                                  u16* __restrict__ Yh,
                                                  u16* __restrict__ Y2h, int nrows) {
  __shared__ u16 As[128 * 136];
  __shared__ u16 Bs[128 * 136];
  int t = threadIdx.x;
  int row0 = blockIdx.x * 128;
  #pragma unroll
  for (int i = 0; i < 8; i++) {
    int idx = t + 256 * i;
    int r = idx >> 4, c8 = idx & 15;
    u16x8 v = {0, 0, 0, 0, 0, 0, 0, 0};
    if (row0 + r < nrows) {
      const float* p = A + (size_t)(row0 + r) * 128 + c8 * 8;
      float4 a = *(const float4*)p;
      float4 b = *(const float4*)(p + 4);
      v[0] = f2bf(a.x); v[1] = f2bf(a.y); v[2] = f2bf(a.z); v[3] = f2bf(a.w);
      v[4] = f2bf(b.x); v[5] = f2bf(b.y); v[6] = f2bf(b.z); v[7] = f2bf(b.w);
    }
    *(u16x8*)&As[r * 136 + c8 * 8] = v;
    *(u16x8*)&Bs[r * 136 + c8 * 8] = *(const u16x8*)(WT + (size_t)r * 128 + c8 * 8);
  }
  __syncthreads();

  int w = t >> 6, lane = t & 63;
  int l31 = lane & 31, kh = lane >> 5;
  int wr = w >> 1, wc = w & 1;
  floatx16 acc[2][2];
  #pragma unroll
  for (int rt = 0; rt < 2; rt++)
    #pragma unroll
    for (int ct = 0; ct < 2; ct++)
      #pragma unroll
      for (int q = 0; q < 16; q++) acc[rt][ct][q] = 0.f;

  #pragma unroll
  for (int ks = 0; ks < 8; ks++) {
    int koff = ks * 16 + kh * 8;
    short8 a0 = *(const short8*)&As[(wr * 64 + l31) * 136 + koff];
    short8 a1 = *(const short8*)&As[(wr * 64 + 32 + l31) * 136 + koff];
    short8 b0 = *(const short8*)&Bs[(wc * 64 + l31) * 136 + koff];
    short8 b1 = *(const short8*)&Bs[(wc * 64 + 32 + l31) * 136 + koff];
    acc[0][0] = __builtin_amdgcn_mfma_f32_32x32x16_bf16(a0, b0, acc[0][0], 0, 0, 0);
    acc[0][1] = __builtin_amdgcn_mfma_f32_32x32x16_bf16(a0, b1, acc[0][1], 0, 0, 0);
    acc[1][0] = __builtin_amdgcn_mfma_f32_32x32x16_bf16(a1, b0, acc[1][0], 0, 0, 0);
    acc[1][1] = __builtin_amdgcn_mfma_f32_32x32x16_bf16(a1, b1, acc[1][1], 0, 0, 0);
  }
  __syncthreads();

  #pragma unroll
  for (int rt = 0; rt < 2; rt++)
    #pragma unroll
    for (int ct = 0; ct < 2; ct++) {
      int col = wc * 64 + ct * 32 + l31;
      float bv = bias[col];
      #pragma unroll
      for (int reg = 0; reg < 16; reg++) {
        int row = wr * 64 + rt * 32 + (reg & 3) + 8 * (reg >> 2) + 4 * kh;
        As[row * 136 + col] = f2bf(fmaxf(acc[rt][ct][reg] + bv, 0.f));
      }
    }
  __syncthreads();
  #pragma unroll
  for (int i = 0; i < 8; i++) {
    int idx = t + 256 * i;
    int r = idx >> 4, c8 = idx & 15;
    if (row0 + r < nrows) {
      u16x8 v = *(const u16x8*)&As[r * 136 + c8 * 8];
      *(u16x8*)(Yh + (size_t)(row0 + r) * 128 + c8 * 8) = v;
      *(u16x8*)(Y2h + (size_t)(row0 + r) * 128 + c8 * 8) = v;
    }
  }
}

// ---------------- output GEMM: out[nrows,40] = Xh @ Wout + bout ----------------

__global__ __launch_bounds__(256) void gemm_out(const u16* __restrict__ Xh,
                                                const float* __restrict__ W,
                                                const float* __restrict__ bias,
                                                float* __restrict__ Y, int nrows) {
  __shared__ float xs[128][36];
  __shared__ float ws[32][44];
  int t = threadIdx.x;
  int tr = t >> 3;
  int tc = t & 7;
  int row0 = blockIdx.x * 128;
  float acc[4][5];
  #pragma unroll
  for (int i = 0; i < 4; i++)
    #pragma unroll
    for (int j = 0; j < 5; j++) acc[i][j] = 0.f;

  for (int k0 = 0; k0 < 128; k0 += 32) {
    #pragma unroll
    for (int i = 0; i < 2; i++) {
      int idx = t + 256 * i;
      int r = idx >> 2, c8 = idx & 3;
      int gr = row0 + r;
      u16x8 v = {0, 0, 0, 0, 0, 0, 0, 0};
      if (gr < nrows) v = *(const u16x8*)(Xh + (size_t)gr * 128 + k0 + c8 * 8);
      #pragma unroll
      for (int q = 0; q < 8; q++) xs[r][c8 * 8 + q] = bf2f(v[q]);
    }
    #pragma unroll
    for (int i = 0; i < 5; i++) {
      int idx = t + 256 * i;
      int r = idx / 40, c = idx % 40;
      ws[r][c] = W[(k0 + r) * 40 + c];
    }
    __syncthreads();
    #pragma unroll
    for (int kk4 = 0; kk4 < 8; kk4++) {
      float4 xv[4];
      #pragma unroll
      for (int i = 0; i < 4; i++) xv[i] = *(const float4*)&xs[tr + 32 * i][kk4 * 4];
      #pragma unroll
      for (int q = 0; q < 4; q++) {
        int kk = kk4 * 4 + q;
        float wv[5];
        #pragma unroll
        for (int j = 0; j < 5; j++) wv[j] = ws[kk][tc * 5 + j];
        #pragma unroll
        for (int i = 0; i < 4; i++) {
          float xq = ((const float*)&xv[i])[q];
          #pragma unroll
          for (int j = 0; j < 5; j++) acc[i][j] += xq * wv[j];
        }
      }
    }
    __syncthreads();
  }
  #pragma unroll
  for (int i = 0; i < 4; i++) {
    int gr = row0 + tr + 32 * i;
    if (gr >= nrows) continue;
    #pragma unroll
    for (int j = 0; j < 5; j++) {
      int c = tc * 5 + j;
      Y[(long)gr * 40 + c] = acc[i][j] + bias[c];
    }
  }
}

// ---------------- launch ----------------

extern "C" void kernel_launch(void* const* d_in, const int* in_sizes, int n_in,
                              void* d_out, int out_size, void* d_ws, size_t ws_size,
                              hipStream_t stream) {
  const float* x    = (const float*)d_in[0];
  const float* W0   = (const float*)d_in[1];
  const float* b0   = (const float*)d_in[2];
  const float* Ws   = (const float*)d_in[3];
  const float* Wout = (const float*)d_in[4];
  const float* bout = (const float*)d_in[5];
  const int* vertex = (const int*)d_in[6];
  const int* edges  = (const int*)d_in[7];
  float* out = (float*)d_out;

  char* base = (char*)d_ws;
  size_t o = 0;
  auto alloc = [&](size_t bytes) -> char* {
    char* r = base + o;
    o += (bytes + 255) & ~(size_t)255;
    return r;
  };
  u16* x_curh = (u16*)alloc((size_t)(NV + 1) * 128 * 2);  // +1 dummy zero row
  u16* x0h    = (u16*)alloc((size_t)NV * 128 * 2);
  u16* Xeh    = (u16*)alloc((size_t)(NE + 1) * 128 * 2);  // +1 dummy zero row
  u16* WT     = (u16*)alloc((size_t)5 * 16384 * 2);
  int* cntE   = (int*)alloc((size_t)NE * 4);
  int* cntV   = (int*)alloc((size_t)NV * 4);
  int* itemsE = (int*)alloc((size_t)NE * CAP_E * 4);
  int* itemsV = (int*)alloc((size_t)NV * CAP_V * 4);
  uint32* pairE = (uint32*)alloc((size_t)NB_E * CAPB_E * 4);
  uint32* pairV = (uint32*)alloc((size_t)NB_V * CAPB_V * 4);
  uint2* ovfE  = (uint2*)alloc((size_t)OVF_CAP * 8);
  uint2* ovfV  = (uint2*)alloc((size_t)OVF_CAP * 8);
  int* curAll = (int*)alloc((size_t)(NB_E + NB_V + 2) * 4);  // curE | curV | ovfCnt[2]
  int* curE = curAll;
  int* curV = curAll + NB_E;
  int* ovfCnt = curAll + NB_E + NB_V;

  int nzero = NB_E + NB_V + 2;
  zero_misc<<<(nzero + 255) / 256, 256, 0, stream>>>(curAll, nzero,
                                                     x_curh + (size_t)NV * 128,
                                                     Xeh + (size_t)NE * 128);
  scatter_binned<<<N_TILES, 256, 0, stream>>>(vertex, edges, curE, curV, ovfCnt,
                                              pairE, pairV, ovfE, ovfV);
  expand<<<NB_E, 256, 0, stream>>>(pairE, curE, CAPB_E, ovfE, ovfCnt,
                                   itemsE, CAP_E, cntE, NE, 16, NV);
  expand<<<NB_V, 256, 0, stream>>>(pairV, curV, CAPB_V, ovfV, ovfCnt + 1,
                                   itemsV, CAP_V, cntV, NV, 8, NE);
  prep_weights<<<(5 * 16384 + 255) / 256, 256, 0, stream>>>(W0, Ws, WT);

  int gblocks = (NV + 127) / 128;
  gemm_first<<<gblocks, 256, 0, stream>>>(x, WT, b0, x_curh, x0h, NV);

  for (int i = 0; i < 4; i++) {
    edge_agg<<<NE / 16, 256, 0, stream>>>(x_curh, cntE, itemsE, Xeh);
    vertex_agg<<<NV / 16, 256, 0, stream>>>(Xeh, cntV, itemsV, x0h, x_curh);
    gemm_mfma<<<gblocks, 256, 0, stream>>>(x_curh, WT + (size_t)(1 + i) * 16384,
                                           x_curh, NV);
  }
  gemm_out<<<gblocks, 256, 0, stream>>>(x_curh, Wout, bout, out, NV);
}

// Round 11
// 495.944 us; speedup vs baseline: 1.4149x; 1.0150x over previous
//
#include <hip/hip_runtime.h>

#define NV 100000
#define NE 50000
#define NNZ_C 800000
#define CAP_E 64        // slots per edge   (multiple of 16)
#define CAP_V 48        // slots per vertex (multiple of 8)
#define NB_E 391        // ceil(NE/128)
#define NB_V 782        // ceil(NV/128)
#define CAPB_E 2560     // per-bucket stream cap (Poisson 2048, +11 sigma)
#define CAPB_V 1408     // per-bucket stream cap (Poisson 1024, +12 sigma)
#define OVF_CAP 810000  // overflow covers worst case -> always correct
#define T_ITEMS 4096
#define N_TILES ((NNZ_C + T_ITEMS - 1) / T_ITEMS)   // 196

typedef unsigned int uint32;
typedef unsigned short u16;
typedef u16 u16x8 __attribute__((ext_vector_type(8)));
typedef short short8 __attribute__((ext_vector_type(8)));
typedef float floatx16 __attribute__((ext_vector_type(16)));

__device__ __forceinline__ float bf2f(u16 h) {
  return __uint_as_float(((uint32)h) << 16);
}
__device__ __forceinline__ u16 f2bf(float f) {
  uint32 u = __float_as_uint(f);
  u += 0x7FFF + ((u >> 16) & 1);   // RNE
  return (u16)(u >> 16);
}

// ---------------- zero cursors + dummy gather rows ----------------

__global__ void zero_misc(int* __restrict__ cur, int n,
                          u16* __restrict__ dummyX, u16* __restrict__ dummyXe) {
  int i = blockIdx.x * blockDim.x + threadIdx.x;
  if (i < n) cur[i] = 0;
  if (i < 128) { dummyX[i] = 0; dummyXe[i] = 0; }
}

// ---------------- LDS-binned scatter ----------------

__global__ __launch_bounds__(256) void scatter_binned(const int* __restrict__ vertex,
                                                      const int* __restrict__ edges,
                                                      int* __restrict__ curE,
                                                      int* __restrict__ curV,
                                                      int* __restrict__ ovfCnt,
                                                      uint32* __restrict__ pairE,
                                                      uint32* __restrict__ pairV,
                                                      uint2* __restrict__ ovfE,
                                                      uint2* __restrict__ ovfV) {
  __shared__ int histE[NB_E], baseE[NB_E];
  __shared__ int histV[NB_V], baseV[NB_V];
  int t = threadIdx.x;
  for (int tile = blockIdx.x; tile < N_TILES; tile += gridDim.x) {
    for (int b = t; b < NB_E; b += 256) histE[b] = 0;
    for (int b = t; b < NB_V; b += 256) histV[b] = 0;
    __syncthreads();
    int base = tile * T_ITEMS;
    int ev[16], vv[16], rE[16], rV[16];
    #pragma unroll
    for (int i = 0; i < 16; i++) {
      int k = base + t + i * 256;
      if (k < NNZ_C) {
        ev[i] = edges[k];
        vv[i] = vertex[k];
        rE[i] = atomicAdd(&histE[ev[i] >> 7], 1);
        rV[i] = atomicAdd(&histV[vv[i] >> 7], 1);
      }
    }
    __syncthreads();
    for (int b = t; b < NB_E; b += 256) {
      int h = histE[b];
      baseE[b] = h ? atomicAdd(&curE[b], h) : 0;
    }
    for (int b = t; b < NB_V; b += 256) {
      int h = histV[b];
      baseV[b] = h ? atomicAdd(&curV[b], h) : 0;
    }
    __syncthreads();
    #pragma unroll
    for (int i = 0; i < 16; i++) {
      int k = base + t + i * 256;
      if (k < NNZ_C) {
        uint32 e = (uint32)ev[i], v = (uint32)vv[i];
        uint32 pkE = ((e & 127u) << 25) | v;
        uint32 pkV = ((v & 127u) << 25) | e;
        int pE = baseE[e >> 7] + rE[i];
        if (pE < CAPB_E) pairE[(size_t)(e >> 7) * CAPB_E + pE] = pkE;
        else { int op = atomicAdd(&ovfCnt[0], 1); if (op < OVF_CAP) ovfE[op] = make_uint2(e >> 7, pkE); }
        int pV = baseV[v >> 7] + rV[i];
        if (pV < CAPB_V) pairV[(size_t)(v >> 7) * CAPB_V + pV] = pkV;
        else { int op = atomicAdd(&ovfCnt[1], 1); if (op < OVF_CAP) ovfV[op] = make_uint2(v >> 7, pkV); }
      }
    }
    __syncthreads();
  }
}

// one block per bucket: rank via LDS atomics; pad each key list to multiple of P
__global__ __launch_bounds__(256) void expand(const uint32* __restrict__ pairs,
                                              const int* __restrict__ cur, int capb,
                                              const uint2* __restrict__ ovf,
                                              const int* __restrict__ ovfCnt,
                                              int* __restrict__ items, int cap,
                                              int* __restrict__ cnt, int nKeys,
                                              int P, int dummy) {
  __shared__ int lcnt[128];
  int b = blockIdx.x, t = threadIdx.x;
  if (t < 128) lcnt[t] = 0;
  __syncthreads();
  int n = min(cur[b], capb);
  const uint32* p = pairs + (size_t)b * capb;
  for (int i = t; i < n; i += 256) {
    uint32 w = p[i];
    int loc = w >> 25;
    int val = (int)(w & 0x1FFFFFFu);
    int r = atomicAdd(&lcnt[loc], 1);
    if (r < cap) items[(size_t)((b << 7) + loc) * cap + r] = val;
  }
  int novf = min(*ovfCnt, OVF_CAP);
  for (int i = t; i < novf; i += 256) {
    uint2 w = ovf[i];
    if ((int)w.x == b) {
      int loc = w.y >> 25;
      int val = (int)(w.y & 0x1FFFFFFu);
      int r = atomicAdd(&lcnt[loc], 1);
      if (r < cap) items[(size_t)((b << 7) + loc) * cap + r] = val;
    }
  }
  __syncthreads();
  if (t < 128) {
    int key = (b << 7) + t;
    if (key < nKeys) {
      int c = lcnt[t];
      cnt[key] = c;
      int cc = min(c, cap);
      int padded = min((cc + P - 1) & ~(P - 1), cap);
      for (int r = cc; r < padded; r++)
        items[(size_t)key * cap + r] = dummy;
    }
  }
}

// ---------------- weight prep ----------------
// WT: [0,16384) = W0T[n][k]; then 4x WeffT[i][n][k], Weff=(1-b)I+b*Ws[i]

__global__ void prep_weights(const float* __restrict__ W0, const float* __restrict__ Ws,
                             u16* __restrict__ WT) {
  int idx = blockIdx.x * blockDim.x + threadIdx.x;
  if (idx >= 5 * 16384) return;
  const float betas[4] = {0.4054651081f, 0.2231435513f, 0.1541506798f, 0.1177830357f};
  int sec = idx >> 14;
  int rc = idx & 16383;
  int n = rc >> 7, k = rc & 127;
  float v;
  if (sec == 0) {
    v = W0[k * 128 + n];
  } else {
    int i = sec - 1;
    float b = betas[i];
    v = b * Ws[i * 16384 + k * 128 + n];
    if (k == n) v += 1.0f - b;
  }
  WT[idx] = f2bf(v);
}

// ---------------- aggregations (bf16, 16 lanes/row, guard-free batches) ----------------

__global__ __launch_bounds__(256) void edge_agg(const u16* __restrict__ Xh,
                                                const int* __restrict__ cntE,
                                                const int* __restrict__ itemsE,
                                                u16* __restrict__ Xeh) {
  int g = threadIdx.x >> 4;
  int lane = threadIdx.x & 15;
  int e = blockIdx.x * 16 + g;
  int cnt = cntE[e];
  int n16 = (min(cnt, CAP_E) + 15) & ~15;
  const int* it = itemsE + (size_t)e * CAP_E;
  float acc[8] = {0.f, 0.f, 0.f, 0.f, 0.f, 0.f, 0.f, 0.f};
  for (int j = 0; j < n16; j += 16) {
    int4 i0 = *(const int4*)(it + j);
    int4 i1 = *(const int4*)(it + j + 4);
    int4 i2 = *(const int4*)(it + j + 8);
    int4 i3 = *(const int4*)(it + j + 12);
    u16x8 r0 = *(const u16x8*)(Xh + (size_t)i0.x * 128 + lane * 8);
    u16x8 r1 = *(const u16x8*)(Xh + (size_t)i0.y * 128 + lane * 8);
    u16x8 r2 = *(const u16x8*)(Xh + (size_t)i0.z * 128 + lane * 8);
    u16x8 r3 = *(const u16x8*)(Xh + (size_t)i0.w * 128 + lane * 8);
    u16x8 r4 = *(const u16x8*)(Xh + (size_t)i1.x * 128 + lane * 8);
    u16x8 r5 = *(const u16x8*)(Xh + (size_t)i1.y * 128 + lane * 8);
    u16x8 r6 = *(const u16x8*)(Xh + (size_t)i1.z * 128 + lane * 8);
    u16x8 r7 = *(const u16x8*)(Xh + (size_t)i1.w * 128 + lane * 8);
    u16x8 r8 = *(const u16x8*)(Xh + (size_t)i2.x * 128 + lane * 8);
    u16x8 r9 = *(const u16x8*)(Xh + (size_t)i2.y * 128 + lane * 8);
    u16x8 rA = *(const u16x8*)(Xh + (size_t)i2.z * 128 + lane * 8);
    u16x8 rB = *(const u16x8*)(Xh + (size_t)i2.w * 128 + lane * 8);
    u16x8 rC = *(const u16x8*)(Xh + (size_t)i3.x * 128 + lane * 8);
    u16x8 rD = *(const u16x8*)(Xh + (size_t)i3.y * 128 + lane * 8);
    u16x8 rE = *(const u16x8*)(Xh + (size_t)i3.z * 128 + lane * 8);
    u16x8 rF = *(const u16x8*)(Xh + (size_t)i3.w * 128 + lane * 8);
    #pragma unroll
    for (int q = 0; q < 8; q++) {
      float s0 = (bf2f(r0[q]) + bf2f(r1[q])) + (bf2f(r2[q]) + bf2f(r3[q]));
      float s1 = (bf2f(r4[q]) + bf2f(r5[q])) + (bf2f(r6[q]) + bf2f(r7[q]));
      float s2 = (bf2f(r8[q]) + bf2f(r9[q])) + (bf2f(rA[q]) + bf2f(rB[q]));
      float s3 = (bf2f(rC[q]) + bf2f(rD[q])) + (bf2f(rE[q]) + bf2f(rF[q]));
      acc[q] += (s0 + s1) + (s2 + s3);
    }
  }
  float inv = 1.f / fmaxf((float)cnt, 1.f);
  u16x8 o;
  #pragma unroll
  for (int q = 0; q < 8; q++) o[q] = f2bf(acc[q] * inv);
  *(u16x8*)(Xeh + (size_t)e * 128 + lane * 8) = o;
}

__global__ __launch_bounds__(256) void vertex_agg(const u16* __restrict__ Xeh,
                                                  const int* __restrict__ cntV,
                                                  const int* __restrict__ itemsV,
                                                  const u16* __restrict__ x0h,
                                                  u16* __restrict__ Xih) {
  int g = threadIdx.x >> 4;
  int lane = threadIdx.x & 15;
  int v = blockIdx.x * 16 + g;
  int cnt = cntV[v];
  int n8 = (min(cnt, CAP_V) + 7) & ~7;
  const int* it = itemsV + (size_t)v * CAP_V;
  u16x8 x0v = *(const u16x8*)(x0h + (size_t)v * 128 + lane * 8);  // hoisted
  float acc[8] = {0.f, 0.f, 0.f, 0.f, 0.f, 0.f, 0.f, 0.f};
  for (int j = 0; j < n8; j += 8) {
    int4 e0 = *(const int4*)(it + j);
    int4 e1 = *(const int4*)(it + j + 4);
    u16x8 r0 = *(const u16x8*)(Xeh + (size_t)e0.x * 128 + lane * 8);
    u16x8 r1 = *(const u16x8*)(Xeh + (size_t)e0.y * 128 + lane * 8);
    u16x8 r2 = *(const u16x8*)(Xeh + (size_t)e0.z * 128 + lane * 8);
    u16x8 r3 = *(const u16x8*)(Xeh + (size_t)e0.w * 128 + lane * 8);
    u16x8 r4 = *(const u16x8*)(Xeh + (size_t)e1.x * 128 + lane * 8);
    u16x8 r5 = *(const u16x8*)(Xeh + (size_t)e1.y * 128 + lane * 8);
    u16x8 r6 = *(const u16x8*)(Xeh + (size_t)e1.z * 128 + lane * 8);
    u16x8 r7 = *(const u16x8*)(Xeh + (size_t)e1.w * 128 + lane * 8);
    #pragma unroll
    for (int q = 0; q < 8; q++)
      acc[q] += ((bf2f(r0[q]) + bf2f(r1[q])) + (bf2f(r2[q]) + bf2f(r3[q]))) +
                ((bf2f(r4[q]) + bf2f(r5[q])) + (bf2f(r6[q]) + bf2f(r7[q])));
  }
  float inv = 1.f / fmaxf((float)cnt, 1.f);
  float sq = 0.f;
  #pragma unroll
  for (int q = 0; q < 8; q++) { acc[q] *= inv; sq += acc[q] * acc[q]; }
  sq += __shfl_xor(sq, 1, 64);
  sq += __shfl_xor(sq, 2, 64);
  sq += __shfl_xor(sq, 4, 64);
  sq += __shfl_xor(sq, 8, 64);
  float scale = (sq > 0.f) ? rsqrtf(sq) : 0.f;
  u16x8 o;
  #pragma unroll
  for (int q = 0; q < 8; q++)
    o[q] = f2bf(0.9f * acc[q] * scale + 0.1f * bf2f(x0v[q]));
  *(u16x8*)(Xih + (size_t)v * 128 + lane * 8) = o;
}

// ---------------- MFMA GEMM (32x32x16, 2x2 wave grid, 2x2 reg tile) ----------------
// B fragments read directly from global WT (32 KB L2-resident broadcast) -- no
// Bs LDS tile. LDS 34.8 KB -> 4 blocks/CU (was 2 at 69.6 KB); __launch_bounds__
// (256,4) caps VGPR at 128 so the occupancy is realized.
// A frag: row = lane&31, k = (lane>>5)*8 + j.  C/D: col = lane&31,
// row = (reg&3) + 8*(reg>>2) + 4*(lane>>5)  [m74/m101-verified]

__global__ __launch_bounds__(256, 4) void gemm_mfma(const u16* __restrict__ Ah,
                                                    const u16* __restrict__ WT,
                                                    u16* __restrict__ Yh, int nrows) {
  __shared__ u16 As[128 * 136];
  int t = threadIdx.x;
  int row0 = blockIdx.x * 128;
  #pragma unroll
  for (int i = 0; i < 8; i++) {
    int idx = t + 256 * i;
    int r = idx >> 4, c8 = idx & 15;
    u16x8 v = {0, 0, 0, 0, 0, 0, 0, 0};
    if (row0 + r < nrows) v = *(const u16x8*)(Ah + (size_t)(row0 + r) * 128 + c8 * 8);
    *(u16x8*)&As[r * 136 + c8 * 8] = v;
  }
  __syncthreads();

  int w = t >> 6, lane = t & 63;
  int l31 = lane & 31, kh = lane >> 5;
  int wr = w >> 1, wc = w & 1;
  floatx16 acc[2][2];
  #pragma unroll
  for (int rt = 0; rt < 2; rt++)
    #pragma unroll
    for (int ct = 0; ct < 2; ct++)
      #pragma unroll
      for (int q = 0; q < 16; q++) acc[rt][ct][q] = 0.f;

  const u16* wtb0 = WT + (size_t)(wc * 64 + l31) * 128;
  const u16* wtb1 = WT + (size_t)(wc * 64 + 32 + l31) * 128;
  #pragma unroll
  for (int ks = 0; ks < 8; ks++) {
    int koff = ks * 16 + kh * 8;
    short8 b0 = *(const short8*)(wtb0 + koff);
    short8 b1 = *(const short8*)(wtb1 + koff);
    short8 a0 = *(const short8*)&As[(wr * 64 + l31) * 136 + koff];
    short8 a1 = *(const short8*)&As[(wr * 64 + 32 + l31) * 136 + koff];
    acc[0][0] = __builtin_amdgcn_mfma_f32_32x32x16_bf16(a0, b0, acc[0][0], 0, 0, 0);
    acc[0][1] = __builtin_amdgcn_mfma_f32_32x32x16_bf16(a0, b1, acc[0][1], 0, 0, 0);
    acc[1][0] = __builtin_amdgcn_mfma_f32_32x32x16_bf16(a1, b0, acc[1][0], 0, 0, 0);
    acc[1][1] = __builtin_amdgcn_mfma_f32_32x32x16_bf16(a1, b1, acc[1][1], 0, 0, 0);
  }
  __syncthreads();

  #pragma unroll
  for (int rt = 0; rt < 2; rt++)
    #pragma unroll
    for (int ct = 0; ct < 2; ct++) {
      int col = wc * 64 + ct * 32 + l31;
      #pragma unroll
      for (int reg = 0; reg < 16; reg++) {
        int row = wr * 64 + rt * 32 + (reg & 3) + 8 * (reg >> 2) + 4 * kh;
        As[row * 136 + col] = f2bf(fmaxf(acc[rt][ct][reg], 0.f));
      }
    }
  __syncthreads();
  #pragma unroll
  for (int i = 0; i < 8; i++) {
    int idx = t + 256 * i;
    int r = idx >> 4, c8 = idx & 15;
    if (row0 + r < nrows)
      *(u16x8*)(Yh + (size_t)(row0 + r) * 128 + c8 * 8) =
          *(const u16x8*)&As[r * 136 + c8 * 8];
  }
}

// first GEMM: fp32 A in, +bias, relu, dual bf16 outputs; B from global
__global__ __launch_bounds__(256, 4) void gemm_first(const float* __restrict__ A,
                                                     const u16* __restrict__ WT,
                                                     const float* __restrict__ bias,
                                                     u16* __restrict__ Yh,
                                                     u16* __restrict__ Y2h, int nrows) {
  __shared__ u16 As[128 * 136];
  int t = threadIdx.x;
  int row0 = blockIdx.x * 128;
  #pragma unroll
  for (int i = 0; i < 8; i++) {
    int idx = t + 256 * i;
    int r = idx >> 4, c8 = idx & 15;
    u16x8 v = {0, 0, 0, 0, 0, 0, 0, 0};
    if (row0 + r < nrows) {
      const float* p = A + (size_t)(row0 + r) * 128 + c8 * 8;
      float4 a = *(const float4*)p;
      float4 b = *(const float4*)(p + 4);
      v[0] = f2bf(a.x); v[1] = f2bf(a.y); v[2] = f2bf(a.z); v[3] = f2bf(a.w);
      v[4] = f2bf(b.x); v[5] = f2bf(b.y); v[6] = f2bf(b.z); v[7] = f2bf(b.w);
    }
    *(u16x8*)&As[r * 136 + c8 * 8] = v;
  }
  __syncthreads();

  int w = t >> 6, lane = t & 63;
  int l31 = lane & 31, kh = lane >> 5;
  int wr = w >> 1, wc = w & 1;
  floatx16 acc[2][2];
  #pragma unroll
  for (int rt = 0; rt < 2; rt++)
    #pragma unroll
    for (int ct = 0; ct < 2; ct++)
      #pragma unroll
      for (int q = 0; q < 16; q++) acc[rt][ct][q] = 0.f;

  const u16* wtb0 = WT + (size_t)(wc * 64 + l31) * 128;
  const u16* wtb1 = WT + (size_t)(wc * 64 + 32 + l31) * 128;
  #pragma unroll
  for (int ks = 0; ks < 8; ks++) {
    int koff = ks * 16 + kh * 8;
    short8 b0 = *(const short8*)(wtb0 + koff);
    short8 b1 = *(const short8*)(wtb1 + koff);
    short8 a0 = *(const short8*)&As[(wr * 64 + l31) * 136 + koff];
    short8 a1 = *(const short8*)&As[(wr * 64 + 32 + l31) * 136 + koff];
    acc[0][0] = __builtin_amdgcn_mfma_f32_32x32x16_bf16(a0, b0, acc[0][0], 0, 0, 0);
    acc[0][1] = __builtin_amdgcn_mfma_f32_32x32x16_bf16(a0, b1, acc[0][1], 0, 0, 0);
    acc[1][0] = __builtin_amdgcn_mfma_f32_32x32x16_bf16(a1, b0, acc[1][0], 0, 0, 0);
    acc[1][1] = __builtin_amdgcn_mfma_f32_32x32x16_bf16(a1, b1, acc[1][1], 0, 0, 0);
  }
  __syncthreads();

  #pragma unroll
  for (int rt = 0; rt < 2; rt++)
    #pragma unroll
    for (int ct = 0; ct < 2; ct++) {
      int col = wc * 64 + ct * 32 + l31;
      float bv = bias[col];
      #pragma unroll
      for (int reg = 0; reg < 16; reg++) {
        int row = wr * 64 + rt * 32 + (reg & 3) + 8 * (reg >> 2) + 4 * kh;
        As[row * 136 + col] = f2bf(fmaxf(acc[rt][ct][reg] + bv, 0.f));
      }
    }
  __syncthreads();
  #pragma unroll
  for (int i = 0; i < 8; i++) {
    int idx = t + 256 * i;
    int r = idx >> 4, c8 = idx & 15;
    if (row0 + r < nrows) {
      u16x8 v = *(const u16x8*)&As[r * 136 + c8 * 8];
      *(u16x8*)(Yh + (size_t)(row0 + r) * 128 + c8 * 8) = v;
      *(u16x8*)(Y2h + (size_t)(row0 + r) * 128 + c8 * 8) = v;
    }
  }
}

// ---------------- output GEMM: out[nrows,40] = Xh @ Wout + bout ----------------

__global__ __launch_bounds__(256) void gemm_out(const u16* __restrict__ Xh,
                                                const float* __restrict__ W,
                                                const float* __restrict__ bias,
                                                float* __restrict__ Y, int nrows) {
  __shared__ float xs[128][36];
  __shared__ float ws[32][44];
  int t = threadIdx.x;
  int tr = t >> 3;
  int tc = t & 7;
  int row0 = blockIdx.x * 128;
  float acc[4][5];
  #pragma unroll
  for (int i = 0; i < 4; i++)
    #pragma unroll
    for (int j = 0; j < 5; j++) acc[i][j] = 0.f;

  for (int k0 = 0; k0 < 128; k0 += 32) {
    #pragma unroll
    for (int i = 0; i < 2; i++) {
      int idx = t + 256 * i;
      int r = idx >> 2, c8 = idx & 3;
      int gr = row0 + r;
      u16x8 v = {0, 0, 0, 0, 0, 0, 0, 0};
      if (gr < nrows) v = *(const u16x8*)(Xh + (size_t)gr * 128 + k0 + c8 * 8);
      #pragma unroll
      for (int q = 0; q < 8; q++) xs[r][c8 * 8 + q] = bf2f(v[q]);
    }
    #pragma unroll
    for (int i = 0; i < 5; i++) {
      int idx = t + 256 * i;
      int r = idx / 40, c = idx % 40;
      ws[r][c] = W[(k0 + r) * 40 + c];
    }
    __syncthreads();
    #pragma unroll
    for (int kk4 = 0; kk4 < 8; kk4++) {
      float4 xv[4];
      #pragma unroll
      for (int i = 0; i < 4; i++) xv[i] = *(const float4*)&xs[tr + 32 * i][kk4 * 4];
      #pragma unroll
      for (int q = 0; q < 4; q++) {
        int kk = kk4 * 4 + q;
        float wv[5];
        #pragma unroll
        for (int j = 0; j < 5; j++) wv[j] = ws[kk][tc * 5 + j];
        #pragma unroll
        for (int i = 0; i < 4; i++) {
          float xq = ((const float*)&xv[i])[q];
          #pragma unroll
          for (int j = 0; j < 5; j++) acc[i][j] += xq * wv[j];
        }
      }
    }
    __syncthreads();
  }
  #pragma unroll
  for (int i = 0; i < 4; i++) {
    int gr = row0 + tr + 32 * i;
    if (gr >= nrows) continue;
    #pragma unroll
    for (int j = 0; j < 5; j++) {
      int c = tc * 5 + j;
      Y[(long)gr * 40 + c] = acc[i][j] + bias[c];
    }
  }
}

// ---------------- launch ----------------

extern "C" void kernel_launch(void* const* d_in, const int* in_sizes, int n_in,
                              void* d_out, int out_size, void* d_ws, size_t ws_size,
                              hipStream_t stream) {
  const float* x    = (const float*)d_in[0];
  const float* W0   = (const float*)d_in[1];
  const float* b0   = (const float*)d_in[2];
  const float* Ws   = (const float*)d_in[3];
  const float* Wout = (const float*)d_in[4];
  const float* bout = (const float*)d_in[5];
  const int* vertex = (const int*)d_in[6];
  const int* edges  = (const int*)d_in[7];
  float* out = (float*)d_out;

  char* base = (char*)d_ws;
  size_t o = 0;
  auto alloc = [&](size_t bytes) -> char* {
    char* r = base + o;
    o += (bytes + 255) & ~(size_t)255;
    return r;
  };
  u16* x_curh = (u16*)alloc((size_t)(NV + 1) * 128 * 2);  // +1 dummy zero row
  u16* x0h    = (u16*)alloc((size_t)NV * 128 * 2);
  u16* Xeh    = (u16*)alloc((size_t)(NE + 1) * 128 * 2);  // +1 dummy zero row
  u16* WT     = (u16*)alloc((size_t)5 * 16384 * 2);
  int* cntE   = (int*)alloc((size_t)NE * 4);
  int* cntV   = (int*)alloc((size_t)NV * 4);
  int* itemsE = (int*)alloc((size_t)NE * CAP_E * 4);
  int* itemsV = (int*)alloc((size_t)NV * CAP_V * 4);
  uint32* pairE = (uint32*)alloc((size_t)NB_E * CAPB_E * 4);
  uint32* pairV = (uint32*)alloc((size_t)NB_V * CAPB_V * 4);
  uint2* ovfE  = (uint2*)alloc((size_t)OVF_CAP * 8);
  uint2* ovfV  = (uint2*)alloc((size_t)OVF_CAP * 8);
  int* curAll = (int*)alloc((size_t)(NB_E + NB_V + 2) * 4);  // curE | curV | ovfCnt[2]
  int* curE = curAll;
  int* curV = curAll + NB_E;
  int* ovfCnt = curAll + NB_E + NB_V;

  int nzero = NB_E + NB_V + 2;
  zero_misc<<<(nzero + 255) / 256, 256, 0, stream>>>(curAll, nzero,
                                                     x_curh + (size_t)NV * 128,
                                                     Xeh + (size_t)NE * 128);
  scatter_binned<<<N_TILES, 256, 0, stream>>>(vertex, edges, curE, curV, ovfCnt,
                                              pairE, pairV, ovfE, ovfV);
  expand<<<NB_E, 256, 0, stream>>>(pairE, curE, CAPB_E, ovfE, ovfCnt,
                                   itemsE, CAP_E, cntE, NE, 16, NV);
  expand<<<NB_V, 256, 0, stream>>>(pairV, curV, CAPB_V, ovfV, ovfCnt + 1,
                                   itemsV, CAP_V, cntV, NV, 8, NE);
  prep_weights<<<(5 * 16384 + 255) / 256, 256, 0, stream>>>(W0, Ws, WT);

  int gblocks = (NV + 127) / 128;
  gemm_first<<<gblocks, 256, 0, stream>>>(x, WT, b0, x_curh, x0h, NV);

  for (int i = 0; i < 4; i++) {
    edge_agg<<<NE / 16, 256, 0, stream>>>(x_curh, cntE, itemsE, Xeh);
    vertex_agg<<<NV / 16, 256, 0, stream>>>(Xeh, cntV, itemsV, x0h, x_curh);
    gemm_mfma<<<gblocks, 256, 0, stream>>>(x_curh, WT + (size_t)(1 + i) * 16384,
                                           x_curh, NV);
  }
  gemm_out<<<gblocks, 256, 0, stream>>>(x_curh, Wout, bout, out, NV);
}

// Round 12
// 479.986 us; speedup vs baseline: 1.4619x; 1.0332x over previous
//
#include <hip/hip_runtime.h>

#define NV 100000
#define NE 50000
#define NNZ_C 800000
#define CAP_E 64        // slots per edge   (multiple of 16)
#define CAP_V 48        // slots per vertex (multiple of 8)
#define NB_E 391        // ceil(NE/128)
#define NB_V 782        // ceil(NV/128)
#define CAPB_E 2560     // per-bucket stream cap (Poisson 2048, +11 sigma)
#define CAPB_V 1408     // per-bucket stream cap (Poisson 1024, +12 sigma)
#define OVF_CAP 810000  // overflow covers worst case -> always correct
#define T_ITEMS 4096
#define N_TILES ((NNZ_C + T_ITEMS - 1) / T_ITEMS)   // 196

typedef unsigned int uint32;
typedef unsigned short u16;
typedef u16 u16x8 __attribute__((ext_vector_type(8)));
typedef short short8 __attribute__((ext_vector_type(8)));
typedef float floatx16 __attribute__((ext_vector_type(16)));

__device__ __forceinline__ float bf2f(u16 h) {
  return __uint_as_float(((uint32)h) << 16);
}
__device__ __forceinline__ u16 f2bf(float f) {
  uint32 u = __float_as_uint(f);
  u += 0x7FFF + ((u >> 16) & 1);   // RNE
  return (u16)(u >> 16);
}

// ---------------- zero cursors + dummy gather rows ----------------

__global__ void zero_misc(int* __restrict__ cur, int n,
                          u16* __restrict__ dummyX, u16* __restrict__ dummyXe) {
  int i = blockIdx.x * blockDim.x + threadIdx.x;
  if (i < n) cur[i] = 0;
  if (i < 128) { dummyX[i] = 0; dummyXe[i] = 0; }
}

// ---------------- LDS-binned scatter ----------------

__global__ __launch_bounds__(256) void scatter_binned(const int* __restrict__ vertex,
                                                      const int* __restrict__ edges,
                                                      int* __restrict__ curE,
                                                      int* __restrict__ curV,
                                                      int* __restrict__ ovfCnt,
                                                      uint32* __restrict__ pairE,
                                                      uint32* __restrict__ pairV,
                                                      uint2* __restrict__ ovfE,
                                                      uint2* __restrict__ ovfV) {
  __shared__ int histE[NB_E], baseE[NB_E];
  __shared__ int histV[NB_V], baseV[NB_V];
  int t = threadIdx.x;
  for (int tile = blockIdx.x; tile < N_TILES; tile += gridDim.x) {
    for (int b = t; b < NB_E; b += 256) histE[b] = 0;
    for (int b = t; b < NB_V; b += 256) histV[b] = 0;
    __syncthreads();
    int base = tile * T_ITEMS;
    int ev[16], vv[16], rE[16], rV[16];
    #pragma unroll
    for (int i = 0; i < 16; i++) {
      int k = base + t + i * 256;
      if (k < NNZ_C) {
        ev[i] = edges[k];
        vv[i] = vertex[k];
        rE[i] = atomicAdd(&histE[ev[i] >> 7], 1);
        rV[i] = atomicAdd(&histV[vv[i] >> 7], 1);
      }
    }
    __syncthreads();
    for (int b = t; b < NB_E; b += 256) {
      int h = histE[b];
      baseE[b] = h ? atomicAdd(&curE[b], h) : 0;
    }
    for (int b = t; b < NB_V; b += 256) {
      int h = histV[b];
      baseV[b] = h ? atomicAdd(&curV[b], h) : 0;
    }
    __syncthreads();
    #pragma unroll
    for (int i = 0; i < 16; i++) {
      int k = base + t + i * 256;
      if (k < NNZ_C) {
        uint32 e = (uint32)ev[i], v = (uint32)vv[i];
        uint32 pkE = ((e & 127u) << 25) | v;
        uint32 pkV = ((v & 127u) << 25) | e;
        int pE = baseE[e >> 7] + rE[i];
        if (pE < CAPB_E) pairE[(size_t)(e >> 7) * CAPB_E + pE] = pkE;
        else { int op = atomicAdd(&ovfCnt[0], 1); if (op < OVF_CAP) ovfE[op] = make_uint2(e >> 7, pkE); }
        int pV = baseV[v >> 7] + rV[i];
        if (pV < CAPB_V) pairV[(size_t)(v >> 7) * CAPB_V + pV] = pkV;
        else { int op = atomicAdd(&ovfCnt[1], 1); if (op < OVF_CAP) ovfV[op] = make_uint2(v >> 7, pkV); }
      }
    }
    __syncthreads();
  }
}

// one block per bucket: rank via LDS atomics; pad each key list to multiple of P
__global__ __launch_bounds__(256) void expand(const uint32* __restrict__ pairs,
                                              const int* __restrict__ cur, int capb,
                                              const uint2* __restrict__ ovf,
                                              const int* __restrict__ ovfCnt,
                                              int* __restrict__ items, int cap,
                                              int* __restrict__ cnt, int nKeys,
                                              int P, int dummy) {
  __shared__ int lcnt[128];
  int b = blockIdx.x, t = threadIdx.x;
  if (t < 128) lcnt[t] = 0;
  __syncthreads();
  int n = min(cur[b], capb);
  const uint32* p = pairs + (size_t)b * capb;
  for (int i = t; i < n; i += 256) {
    uint32 w = p[i];
    int loc = w >> 25;
    int val = (int)(w & 0x1FFFFFFu);
    int r = atomicAdd(&lcnt[loc], 1);
    if (r < cap) items[(size_t)((b << 7) + loc) * cap + r] = val;
  }
  int novf = min(*ovfCnt, OVF_CAP);
  for (int i = t; i < novf; i += 256) {
    uint2 w = ovf[i];
    if ((int)w.x == b) {
      int loc = w.y >> 25;
      int val = (int)(w.y & 0x1FFFFFFu);
      int r = atomicAdd(&lcnt[loc], 1);
      if (r < cap) items[(size_t)((b << 7) + loc) * cap + r] = val;
    }
  }
  __syncthreads();
  if (t < 128) {
    int key = (b << 7) + t;
    if (key < nKeys) {
      int c = lcnt[t];
      cnt[key] = c;
      int cc = min(c, cap);
      int padded = min((cc + P - 1) & ~(P - 1), cap);
      for (int r = cc; r < padded; r++)
        items[(size_t)key * cap + r] = dummy;
    }
  }
}

// ---------------- weight prep ----------------
// WT: [0,16384) = W0T[n][k]; then 4x WeffT[i][n][k], Weff=(1-b)I+b*Ws[i]

__global__ void prep_weights(const float* __restrict__ W0, const float* __restrict__ Ws,
                             u16* __restrict__ WT) {
  int idx = blockIdx.x * blockDim.x + threadIdx.x;
  if (idx >= 5 * 16384) return;
  const float betas[4] = {0.4054651081f, 0.2231435513f, 0.1541506798f, 0.1177830357f};
  int sec = idx >> 14;
  int rc = idx & 16383;
  int n = rc >> 7, k = rc & 127;
  float v;
  if (sec == 0) {
    v = W0[k * 128 + n];
  } else {
    int i = sec - 1;
    float b = betas[i];
    v = b * Ws[i * 16384 + k * 128 + n];
    if (k == n) v += 1.0f - b;
  }
  WT[idx] = f2bf(v);
}

// ---------------- edge aggregation (bf16, 16 lanes/row, guard-free) ----------------

__global__ __launch_bounds__(256) void edge_agg(const u16* __restrict__ Xh,
                                                const int* __restrict__ cntE,
                                                const int* __restrict__ itemsE,
                                                u16* __restrict__ Xeh) {
  int g = threadIdx.x >> 4;
  int lane = threadIdx.x & 15;
  int e = blockIdx.x * 16 + g;
  int cnt = cntE[e];
  int n16 = (min(cnt, CAP_E) + 15) & ~15;
  const int* it = itemsE + (size_t)e * CAP_E;
  float acc[8] = {0.f, 0.f, 0.f, 0.f, 0.f, 0.f, 0.f, 0.f};
  for (int j = 0; j < n16; j += 16) {
    int4 i0 = *(const int4*)(it + j);
    int4 i1 = *(const int4*)(it + j + 4);
    int4 i2 = *(const int4*)(it + j + 8);
    int4 i3 = *(const int4*)(it + j + 12);
    u16x8 r0 = *(const u16x8*)(Xh + (size_t)i0.x * 128 + lane * 8);
    u16x8 r1 = *(const u16x8*)(Xh + (size_t)i0.y * 128 + lane * 8);
    u16x8 r2 = *(const u16x8*)(Xh + (size_t)i0.z * 128 + lane * 8);
    u16x8 r3 = *(const u16x8*)(Xh + (size_t)i0.w * 128 + lane * 8);
    u16x8 r4 = *(const u16x8*)(Xh + (size_t)i1.x * 128 + lane * 8);
    u16x8 r5 = *(const u16x8*)(Xh + (size_t)i1.y * 128 + lane * 8);
    u16x8 r6 = *(const u16x8*)(Xh + (size_t)i1.z * 128 + lane * 8);
    u16x8 r7 = *(const u16x8*)(Xh + (size_t)i1.w * 128 + lane * 8);
    u16x8 r8 = *(const u16x8*)(Xh + (size_t)i2.x * 128 + lane * 8);
    u16x8 r9 = *(const u16x8*)(Xh + (size_t)i2.y * 128 + lane * 8);
    u16x8 rA = *(const u16x8*)(Xh + (size_t)i2.z * 128 + lane * 8);
    u16x8 rB = *(const u16x8*)(Xh + (size_t)i2.w * 128 + lane * 8);
    u16x8 rC = *(const u16x8*)(Xh + (size_t)i3.x * 128 + lane * 8);
    u16x8 rD = *(const u16x8*)(Xh + (size_t)i3.y * 128 + lane * 8);
    u16x8 rE = *(const u16x8*)(Xh + (size_t)i3.z * 128 + lane * 8);
    u16x8 rF = *(const u16x8*)(Xh + (size_t)i3.w * 128 + lane * 8);
    #pragma unroll
    for (int q = 0; q < 8; q++) {
      float s0 = (bf2f(r0[q]) + bf2f(r1[q])) + (bf2f(r2[q]) + bf2f(r3[q]));
      float s1 = (bf2f(r4[q]) + bf2f(r5[q])) + (bf2f(r6[q]) + bf2f(r7[q]));
      float s2 = (bf2f(r8[q]) + bf2f(r9[q])) + (bf2f(rA[q]) + bf2f(rB[q]));
      float s3 = (bf2f(rC[q]) + bf2f(rD[q])) + (bf2f(rE[q]) + bf2f(rF[q]));
      acc[q] += (s0 + s1) + (s2 + s3);
    }
  }
  float inv = 1.f / fmaxf((float)cnt, 1.f);
  u16x8 o;
  #pragma unroll
  for (int q = 0; q < 8; q++) o[q] = f2bf(acc[q] * inv);
  *(u16x8*)(Xeh + (size_t)e * 128 + lane * 8) = o;
}

// ---------------- fused vertex_agg + MFMA GEMM, 64-row tile ----------------
// Gather phase: 16 groups x 4 passes cover 64 rows; norm+blend; rows land in As.
// MFMA: 2x2 wave grid, M=64 N=128, B from global WT (L2 broadcast). LDS 17.4 KB
// -> ~6 blocks/CU (grid 1563), 20+ waves/CU for the latency-bound gathers
// (R5's fused attempt died at 2 blocks/CU with 68 KB LDS).

__global__ __launch_bounds__(256, 5) void gemm_fused(const u16* __restrict__ Xeh,
                                                     const int* __restrict__ cntV,
                                                     const int* __restrict__ itemsV,
                                                     const u16* __restrict__ x0h,
                                                     const u16* __restrict__ WT,
                                                     u16* __restrict__ Yh, int nrows) {
  __shared__ u16 As[64 * 136];
  int t = threadIdx.x;
  int row0 = blockIdx.x * 64;
  int g = t >> 4, lane = t & 15;
  #pragma unroll
  for (int pass = 0; pass < 4; pass++) {
    int r = pass * 16 + g;
    int v = row0 + r;
    float acc[8] = {0.f, 0.f, 0.f, 0.f, 0.f, 0.f, 0.f, 0.f};
    int cnt = 0;
    if (v < nrows) {
      cnt = cntV[v];
      int n8 = (min(cnt, CAP_V) + 7) & ~7;
      const int* it = itemsV + (size_t)v * CAP_V;
      for (int j = 0; j < n8; j += 8) {
        int4 e0 = *(const int4*)(it + j);
        int4 e1 = *(const int4*)(it + j + 4);
        u16x8 r0 = *(const u16x8*)(Xeh + (size_t)e0.x * 128 + lane * 8);
        u16x8 r1 = *(const u16x8*)(Xeh + (size_t)e0.y * 128 + lane * 8);
        u16x8 r2 = *(const u16x8*)(Xeh + (size_t)e0.z * 128 + lane * 8);
        u16x8 r3 = *(const u16x8*)(Xeh + (size_t)e0.w * 128 + lane * 8);
        u16x8 r4 = *(const u16x8*)(Xeh + (size_t)e1.x * 128 + lane * 8);
        u16x8 r5 = *(const u16x8*)(Xeh + (size_t)e1.y * 128 + lane * 8);
        u16x8 r6 = *(const u16x8*)(Xeh + (size_t)e1.z * 128 + lane * 8);
        u16x8 r7 = *(const u16x8*)(Xeh + (size_t)e1.w * 128 + lane * 8);
        #pragma unroll
        for (int q = 0; q < 8; q++)
          acc[q] += ((bf2f(r0[q]) + bf2f(r1[q])) + (bf2f(r2[q]) + bf2f(r3[q]))) +
                    ((bf2f(r4[q]) + bf2f(r5[q])) + (bf2f(r6[q]) + bf2f(r7[q])));
      }
    }
    float inv = 1.f / fmaxf((float)cnt, 1.f);
    float sq = 0.f;
    #pragma unroll
    for (int q = 0; q < 8; q++) { acc[q] *= inv; sq += acc[q] * acc[q]; }
    sq += __shfl_xor(sq, 1, 64);
    sq += __shfl_xor(sq, 2, 64);
    sq += __shfl_xor(sq, 4, 64);
    sq += __shfl_xor(sq, 8, 64);
    float scale = (sq > 0.f) ? rsqrtf(sq) : 0.f;
    u16x8 o = {0, 0, 0, 0, 0, 0, 0, 0};
    if (v < nrows) {
      u16x8 x0v = *(const u16x8*)(x0h + (size_t)v * 128 + lane * 8);
      #pragma unroll
      for (int q = 0; q < 8; q++)
        o[q] = f2bf(0.9f * acc[q] * scale + 0.1f * bf2f(x0v[q]));
    }
    *(u16x8*)&As[r * 136 + lane * 8] = o;
  }
  __syncthreads();

  int w = t >> 6, lane64 = t & 63;
  int l31 = lane64 & 31, kh = lane64 >> 5;
  int wr = w >> 1, wc = w & 1;
  floatx16 acc[2];
  #pragma unroll
  for (int ct = 0; ct < 2; ct++)
    #pragma unroll
    for (int q = 0; q < 16; q++) acc[ct][q] = 0.f;

  const u16* wtb0 = WT + (size_t)(wc * 64 + l31) * 128;
  const u16* wtb1 = WT + (size_t)(wc * 64 + 32 + l31) * 128;
  #pragma unroll
  for (int ks = 0; ks < 8; ks++) {
    int koff = ks * 16 + kh * 8;
    short8 b0 = *(const short8*)(wtb0 + koff);
    short8 b1 = *(const short8*)(wtb1 + koff);
    short8 a0 = *(const short8*)&As[(wr * 32 + l31) * 136 + koff];
    acc[0] = __builtin_amdgcn_mfma_f32_32x32x16_bf16(a0, b0, acc[0], 0, 0, 0);
    acc[1] = __builtin_amdgcn_mfma_f32_32x32x16_bf16(a0, b1, acc[1], 0, 0, 0);
  }
  __syncthreads();

  #pragma unroll
  for (int ct = 0; ct < 2; ct++) {
    int col = wc * 64 + ct * 32 + l31;
    #pragma unroll
    for (int reg = 0; reg < 16; reg++) {
      int row = wr * 32 + (reg & 3) + 8 * (reg >> 2) + 4 * kh;
      As[row * 136 + col] = f2bf(fmaxf(acc[ct][reg], 0.f));
    }
  }
  __syncthreads();
  #pragma unroll
  for (int i = 0; i < 4; i++) {
    int idx = t + 256 * i;
    int r = idx >> 4, c8 = idx & 15;
    if (row0 + r < nrows)
      *(u16x8*)(Yh + (size_t)(row0 + r) * 128 + c8 * 8) =
          *(const u16x8*)&As[r * 136 + c8 * 8];
  }
}

// first GEMM: fp32 A in, +bias, relu, dual bf16 outputs; B from global
__global__ __launch_bounds__(256, 4) void gemm_first(const float* __restrict__ A,
                                                     const u16* __restrict__ WT,
                                                     const float* __restrict__ bias,
                                                     u16* __restrict__ Yh,
                                                     u16* __restrict__ Y2h, int nrows) {
  __shared__ u16 As[128 * 136];
  int t = threadIdx.x;
  int row0 = blockIdx.x * 128;
  #pragma unroll
  for (int i = 0; i < 8; i++) {
    int idx = t + 256 * i;
    int r = idx >> 4, c8 = idx & 15;
    u16x8 v = {0, 0, 0, 0, 0, 0, 0, 0};
    if (row0 + r < nrows) {
      const float* p = A + (size_t)(row0 + r) * 128 + c8 * 8;
      float4 a = *(const float4*)p;
      float4 b = *(const float4*)(p + 4);
      v[0] = f2bf(a.x); v[1] = f2bf(a.y); v[2] = f2bf(a.z); v[3] = f2bf(a.w);
      v[4] = f2bf(b.x); v[5] = f2bf(b.y); v[6] = f2bf(b.z); v[7] = f2bf(b.w);
    }
    *(u16x8*)&As[r * 136 + c8 * 8] = v;
  }
  __syncthreads();

  int w = t >> 6, lane = t & 63;
  int l31 = lane & 31, kh = lane >> 5;
  int wr = w >> 1, wc = w & 1;
  floatx16 acc[2][2];
  #pragma unroll
  for (int rt = 0; rt < 2; rt++)
    #pragma unroll
    for (int ct = 0; ct < 2; ct++)
      #pragma unroll
      for (int q = 0; q < 16; q++) acc[rt][ct][q] = 0.f;

  const u16* wtb0 = WT + (size_t)(wc * 64 + l31) * 128;
  const u16* wtb1 = WT + (size_t)(wc * 64 + 32 + l31) * 128;
  #pragma unroll
  for (int ks = 0; ks < 8; ks++) {
    int koff = ks * 16 + kh * 8;
    short8 b0 = *(const short8*)(wtb0 + koff);
    short8 b1 = *(const short8*)(wtb1 + koff);
    short8 a0 = *(const short8*)&As[(wr * 64 + l31) * 136 + koff];
    short8 a1 = *(const short8*)&As[(wr * 64 + 32 + l31) * 136 + koff];
    acc[0][0] = __builtin_amdgcn_mfma_f32_32x32x16_bf16(a0, b0, acc[0][0], 0, 0, 0);
    acc[0][1] = __builtin_amdgcn_mfma_f32_32x32x16_bf16(a0, b1, acc[0][1], 0, 0, 0);
    acc[1][0] = __builtin_amdgcn_mfma_f32_32x32x16_bf16(a1, b0, acc[1][0], 0, 0, 0);
    acc[1][1] = __builtin_amdgcn_mfma_f32_32x32x16_bf16(a1, b1, acc[1][1], 0, 0, 0);
  }
  __syncthreads();

  #pragma unroll
  for (int rt = 0; rt < 2; rt++)
    #pragma unroll
    for (int ct = 0; ct < 2; ct++) {
      int col = wc * 64 + ct * 32 + l31;
      float bv = bias[col];
      #pragma unroll
      for (int reg = 0; reg < 16; reg++) {
        int row = wr * 64 + rt * 32 + (reg & 3) + 8 * (reg >> 2) + 4 * kh;
        As[row * 136 + col] = f2bf(fmaxf(acc[rt][ct][reg] + bv, 0.f));
      }
    }
  __syncthreads();
  #pragma unroll
  for (int i = 0; i < 8; i++) {
    int idx = t + 256 * i;
    int r = idx >> 4, c8 = idx & 15;
    if (row0 + r < nrows) {
      u16x8 v = *(const u16x8*)&As[r * 136 + c8 * 8];
      *(u16x8*)(Yh + (size_t)(row0 + r) * 128 + c8 * 8) = v;
      *(u16x8*)(Y2h + (size_t)(row0 + r) * 128 + c8 * 8) = v;
    }
  }
}

// ---------------- output GEMM: out[nrows,40] = Xh @ Wout + bout ----------------

__global__ __launch_bounds__(256) void gemm_out(const u16* __restrict__ Xh,
                                                const float* __restrict__ W,
                                                const float* __restrict__ bias,
                                                float* __restrict__ Y, int nrows) {
  __shared__ float xs[128][36];
  __shared__ float ws[32][44];
  int t = threadIdx.x;
  int tr = t >> 3;
  int tc = t & 7;
  int row0 = blockIdx.x * 128;
  float acc[4][5];
  #pragma unroll
  for (int i = 0; i < 4; i++)
    #pragma unroll
    for (int j = 0; j < 5; j++) acc[i][j] = 0.f;

  for (int k0 = 0; k0 < 128; k0 += 32) {
    #pragma unroll
    for (int i = 0; i < 2; i++) {
      int idx = t + 256 * i;
      int r = idx >> 2, c8 = idx & 3;
      int gr = row0 + r;
      u16x8 v = {0, 0, 0, 0, 0, 0, 0, 0};
      if (gr < nrows) v = *(const u16x8*)(Xh + (size_t)gr * 128 + k0 + c8 * 8);
      #pragma unroll
      for (int q = 0; q < 8; q++) xs[r][c8 * 8 + q] = bf2f(v[q]);
    }
    #pragma unroll
    for (int i = 0; i < 5; i++) {
      int idx = t + 256 * i;
      int r = idx / 40, c = idx % 40;
      ws[r][c] = W[(k0 + r) * 40 + c];
    }
    __syncthreads();
    #pragma unroll
    for (int kk4 = 0; kk4 < 8; kk4++) {
      float4 xv[4];
      #pragma unroll
      for (int i = 0; i < 4; i++) xv[i] = *(const float4*)&xs[tr + 32 * i][kk4 * 4];
      #pragma unroll
      for (int q = 0; q < 4; q++) {
        int kk = kk4 * 4 + q;
        float wv[5];
        #pragma unroll
        for (int j = 0; j < 5; j++) wv[j] = ws[kk][tc * 5 + j];
        #pragma unroll
        for (int i = 0; i < 4; i++) {
          float xq = ((const float*)&xv[i])[q];
          #pragma unroll
          for (int j = 0; j < 5; j++) acc[i][j] += xq * wv[j];
        }
      }
    }
    __syncthreads();
  }
  #pragma unroll
  for (int i = 0; i < 4; i++) {
    int gr = row0 + tr + 32 * i;
    if (gr >= nrows) continue;
    #pragma unroll
    for (int j = 0; j < 5; j++) {
      int c = tc * 5 + j;
      Y[(long)gr * 40 + c] = acc[i][j] + bias[c];
    }
  }
}

// ---------------- launch ----------------

extern "C" void kernel_launch(void* const* d_in, const int* in_sizes, int n_in,
                              void* d_out, int out_size, void* d_ws, size_t ws_size,
                              hipStream_t stream) {
  const float* x    = (const float*)d_in[0];
  const float* W0   = (const float*)d_in[1];
  const float* b0   = (const float*)d_in[2];
  const float* Ws   = (const float*)d_in[3];
  const float* Wout = (const float*)d_in[4];
  const float* bout = (const float*)d_in[5];
  const int* vertex = (const int*)d_in[6];
  const int* edges  = (const int*)d_in[7];
  float* out = (float*)d_out;

  char* base = (char*)d_ws;
  size_t o = 0;
  auto alloc = [&](size_t bytes) -> char* {
    char* r = base + o;
    o += (bytes + 255) & ~(size_t)255;
    return r;
  };
  u16* x_curh = (u16*)alloc((size_t)(NV + 1) * 128 * 2);  // +1 dummy zero row
  u16* x0h    = (u16*)alloc((size_t)NV * 128 * 2);
  u16* Xeh    = (u16*)alloc((size_t)(NE + 1) * 128 * 2);  // +1 dummy zero row
  u16* WT     = (u16*)alloc((size_t)5 * 16384 * 2);
  int* cntE   = (int*)alloc((size_t)NE * 4);
  int* cntV   = (int*)alloc((size_t)NV * 4);
  int* itemsE = (int*)alloc((size_t)NE * CAP_E * 4);
  int* itemsV = (int*)alloc((size_t)NV * CAP_V * 4);
  uint32* pairE = (uint32*)alloc((size_t)NB_E * CAPB_E * 4);
  uint32* pairV = (uint32*)alloc((size_t)NB_V * CAPB_V * 4);
  uint2* ovfE  = (uint2*)alloc((size_t)OVF_CAP * 8);
  uint2* ovfV  = (uint2*)alloc((size_t)OVF_CAP * 8);
  int* curAll = (int*)alloc((size_t)(NB_E + NB_V + 2) * 4);  // curE | curV | ovfCnt[2]
  int* curE = curAll;
  int* curV = curAll + NB_E;
  int* ovfCnt = curAll + NB_E + NB_V;

  int nzero = NB_E + NB_V + 2;
  zero_misc<<<(nzero + 255) / 256, 256, 0, stream>>>(curAll, nzero,
                                                     x_curh + (size_t)NV * 128,
                                                     Xeh + (size_t)NE * 128);
  scatter_binned<<<N_TILES, 256, 0, stream>>>(vertex, edges, curE, curV, ovfCnt,
                                              pairE, pairV, ovfE, ovfV);
  expand<<<NB_E, 256, 0, stream>>>(pairE, curE, CAPB_E, ovfE, ovfCnt,
                                   itemsE, CAP_E, cntE, NE, 16, NV);
  expand<<<NB_V, 256, 0, stream>>>(pairV, curV, CAPB_V, ovfV, ovfCnt + 1,
                                   itemsV, CAP_V, cntV, NV, 8, NE);
  prep_weights<<<(5 * 16384 + 255) / 256, 256, 0, stream>>>(W0, Ws, WT);

  int gblocks = (NV + 127) / 128;
  int fblocks = (NV + 63) / 64;
  gemm_first<<<gblocks, 256, 0, stream>>>(x, WT, b0, x_curh, x0h, NV);

  for (int i = 0; i < 4; i++) {
    edge_agg<<<NE / 16, 256, 0, stream>>>(x_curh, cntE, itemsE, Xeh);
    gemm_fused<<<fblocks, 256, 0, stream>>>(Xeh, cntV, itemsV, x0h,
                                            WT + (size_t)(1 + i) * 16384, x_curh, NV);
  }
  gemm_out<<<gblocks, 256, 0, stream>>>(x_curh, Wout, bout, out, NV);
}